// Round 2
// baseline (5848.989 us; speedup 1.0000x reference)
//
#include <hip/hip_runtime.h>
#include <hip/hip_bf16.h>
#include <cstdint>
#include <cstddef>

// ---- problem constants ----
#define NN     20000
#define FIN_D  64
#define H_D    128
#define M_D    16
#define EIA_D  256000
#define EIR_D  256000
#define EIT_D  100000
#define EIN_D  257
#define EHID_D 514
#define NIN_D  144
#define NHID_D 256
#define BPAD   520          // padded EHID for bf16 B rows (260 uint pairs)

__device__ __forceinline__ float siluf(float x) { return x / (1.f + __expf(-x)); }
__device__ __forceinline__ float reluf(float x) { return x > 0.f ? x : 0.f; }
__device__ __forceinline__ float bf_lo(unsigned u) { return __uint_as_float(u << 16); }
__device__ __forceinline__ float bf_hi(unsigned u) { return __uint_as_float(u & 0xFFFF0000u); }

// ---------------- CSR build ----------------
__global__ void k_filli(int* p, int v, int n) {
    int i = blockIdx.x * 256 + threadIdx.x; if (i < n) p[i] = v;
}
__global__ void k_hist(const int* __restrict__ si, int nE, int* __restrict__ cnt) {
    int e = blockIdx.x * 256 + threadIdx.x; if (e < nE) atomicAdd(&cnt[si[e]], 1);
}
// one block per CSR list: exclusive scan of cnt[n] -> rp[n+1]
__global__ void k_scan4(const int* __restrict__ cnt4, int n, int* __restrict__ rp4) {
    const int* cnt = cnt4 + (size_t)blockIdx.x * n;
    int* rp = rp4 + (size_t)blockIdx.x * (n + 1);
    __shared__ int tmp[256];
    __shared__ int carry;
    if (threadIdx.x == 0) { carry = 0; rp[0] = 0; }
    __syncthreads();
    for (int base = 0; base < n; base += 256) {
        int i = base + threadIdx.x;
        int v = (i < n) ? cnt[i] : 0;
        tmp[threadIdx.x] = v;
        __syncthreads();
        for (int off = 1; off < 256; off <<= 1) {
            int t = (threadIdx.x >= off) ? tmp[threadIdx.x - off] : 0;
            __syncthreads();
            tmp[threadIdx.x] += t;
            __syncthreads();
        }
        if (i < n) rp[i + 1] = carry + tmp[threadIdx.x];
        __syncthreads();
        if (threadIdx.x == 0) carry += tmp[255];
        __syncthreads();
    }
}
__global__ void k_scatter(const int* __restrict__ sj, const int* __restrict__ si, int nE,
                          const int* __restrict__ rp, int* __restrict__ cursor, int* __restrict__ colj) {
    int e = blockIdx.x * 256 + threadIdx.x;
    if (e >= nE) return;
    int i = si[e];
    int p = rp[i] + atomicAdd(&cursor[i], 1);
    colj[p] = sj[e];
}

// ---------------- generic fp32 tiled GEMM: C = act(A@W + bias) (+res) ----------------
template<int ACT, bool RES, bool OBF>
__global__ __launch_bounds__(256) void k_gemm(const float* __restrict__ A, const float* __restrict__ W,
                                              const float* __restrict__ bias, const float* __restrict__ res,
                                              float* __restrict__ C, int M, int Nc, int K, int ldc) {
    __shared__ __align__(16) float sA[16][68];
    __shared__ __align__(16) float sB[16][68];
    const int tid = threadIdx.x;
    const int bm = blockIdx.x * 64, bn = blockIdx.y * 64;
    const int tm = (tid >> 4) << 2, tn = (tid & 15) << 2;
    float acc[4][4] = {};
    for (int k0 = 0; k0 < K; k0 += 16) {
#pragma unroll
        for (int t = 0; t < 4; ++t) {
            int idx = tid + 256 * t;
            int m = idx >> 4, kk = idx & 15;
            int gm = bm + m, gk = k0 + kk;
            sA[kk][m] = (gm < M && gk < K) ? A[(size_t)gm * K + gk] : 0.f;
            int n2 = idx & 63, k2 = idx >> 6;
            int gn = bn + n2, gk2 = k0 + k2;
            sB[k2][n2] = (gn < Nc && gk2 < K) ? W[(size_t)gk2 * Nc + gn] : 0.f;
        }
        __syncthreads();
#pragma unroll
        for (int kk = 0; kk < 16; ++kk) {
            float4 av = *(const float4*)&sA[kk][tm];
            float4 bv = *(const float4*)&sB[kk][tn];
            float aa[4] = {av.x, av.y, av.z, av.w};
            float bb[4] = {bv.x, bv.y, bv.z, bv.w};
#pragma unroll
            for (int i = 0; i < 4; ++i)
#pragma unroll
                for (int j = 0; j < 4; ++j) acc[i][j] += aa[i] * bb[j];
        }
        __syncthreads();
    }
#pragma unroll
    for (int i = 0; i < 4; ++i) {
        int gm = bm + tm + i;
        if (gm >= M) continue;
#pragma unroll
        for (int j = 0; j < 4; ++j) {
            int gn = bn + tn + j;
            if (gn >= Nc) continue;
            float v = acc[i][j];
            if (bias) v += bias[gn];
            if (ACT == 1) v = reluf(v);
            if (ACT == 2) v = siluf(v);
            if (RES) v += res[(size_t)gm * Nc + gn];
            if (OBF) ((__hip_bfloat16*)C)[(size_t)gm * ldc + gn] = __float2bfloat16(v);
            else C[(size_t)gm * ldc + gn] = v;
        }
    }
}

// zero the bf16 pad columns (elements 514..519 of each padded row)
__global__ void k_padzero(unsigned short* __restrict__ B16, int n) {
    int i = blockIdx.x * 256 + threadIdx.x;
    if (i >= n * 6) return;
    int r = i / 6, c = 514 + i % 6;
    B16[(size_t)r * BPAD + c] = 0;
}

// ---------------- row dot (es/ed): wave per node, d fixed at 128 ----------------
__global__ void k_rowdot(const float* __restrict__ h, const float* __restrict__ a,
                         float* __restrict__ o, int n) {
    int w = (blockIdx.x * blockDim.x + threadIdx.x) >> 6;
    int lane = threadIdx.x & 63;
    if (w >= n) return;
    const float* r = h + (size_t)w * H_D;
    float s = r[lane] * a[lane] + r[lane + 64] * a[lane + 64];
#pragma unroll
    for (int off = 32; off; off >>= 1) s += __shfl_xor(s, off);
    if (lane == 0) o[w] = s;
}

__global__ void k_nodescore(const float* __restrict__ x, const float* __restrict__ wv,
                            const float* __restrict__ b, float* __restrict__ o, int n) {
    int w = (blockIdx.x * blockDim.x + threadIdx.x) >> 6;
    int lane = threadIdx.x & 63;
    if (w >= n) return;
    const float* r = x + (size_t)w * H_D;
    float s = r[lane] * wv[lane] + r[lane + 64] * wv[lane + 64];
#pragma unroll
    for (int off = 32; off; off >>= 1) s += __shfl_xor(s, off);
    if (lane == 0) o[w] = s + b[0];
}

// ---------------- fused GAT softmax-aggregate (CSR, wave per dest node) ----------------
__global__ __launch_bounds__(256) void k_gat_fused(
        const int* __restrict__ rp, const int* __restrict__ cj, int hasSelf,
        const float* __restrict__ es, const float* __restrict__ ed,
        const float* __restrict__ hs, const float* __restrict__ bias,
        float* __restrict__ out, int N) {
    int node = blockIdx.x * 4 + (threadIdx.x >> 6);
    int lane = threadIdx.x & 63;
    if (node >= N) return;
    int start = rp[node], end = rp[node + 1];
    float edi = ed[node];
    // pass 1: max over edges (lanes parallel over edges)
    float m = -INFINITY;
    for (int p = start + lane; p < end; p += 64) {
        float v = es[cj[p]] + edi;
        v = v < 0.f ? 0.2f * v : v;
        m = fmaxf(m, v);
    }
#pragma unroll
    for (int off = 32; off; off >>= 1) m = fmaxf(m, __shfl_xor(m, off));
    float vself = 0.f;
    if (hasSelf) {
        vself = es[node] + edi;
        vself = vself < 0.f ? 0.2f * vself : vself;
        m = fmaxf(m, vself);
    }
    // pass 2: serial over edges, lanes over channels
    float den = 0.f, a0 = 0.f, a1 = 0.f;
    for (int p = start; p < end; ++p) {
        int j = cj[p];
        float v = es[j] + edi;
        v = v < 0.f ? 0.2f * v : v;
        float ex = __expf(v - m);
        den += ex;
        const float* hr = hs + (size_t)j * H_D;
        a0 += ex * hr[lane];
        a1 += ex * hr[lane + 64];
    }
    if (hasSelf) {
        float ex = __expf(vself - m);
        den += ex;
        const float* hr = hs + (size_t)node * H_D;
        a0 += ex * hr[lane];
        a1 += ex * hr[lane + 64];
    }
    float inv = 1.f / (den + 1e-16f);
    out[(size_t)node * H_D + lane]      = reluf(a0 * inv + bias[lane]);
    out[(size_t)node * H_D + 64 + lane] = reluf(a1 * inv + bias[lane + 64]);
}

// ---------------- 16-channel x 64-lane split-butterfly reduce ----------------
// in: v[16] per-lane partials; out: full sum of channel (lane&15) on every lane
__device__ __forceinline__ float reduce16x64(float (&v)[16], int lane) {
#pragma unroll
    for (int q = 0; q < 8; ++q) {
        float send = (lane & 8) ? v[q] : v[q + 8];
        float r = __shfl_xor(send, 8);
        v[q] = ((lane & 8) ? v[q + 8] : v[q]) + r;
    }
#pragma unroll
    for (int q = 0; q < 4; ++q) {
        float send = (lane & 4) ? v[q] : v[q + 4];
        float r = __shfl_xor(send, 4);
        v[q] = ((lane & 4) ? v[q + 4] : v[q]) + r;
    }
#pragma unroll
    for (int q = 0; q < 2; ++q) {
        float send = (lane & 2) ? v[q] : v[q + 2];
        float r = __shfl_xor(send, 2);
        v[q] = ((lane & 2) ? v[q + 2] : v[q]) + r;
    }
    {
        float send = (lane & 1) ? v[0] : v[1];
        float r = __shfl_xor(send, 1);
        v[0] = ((lane & 1) ? v[1] : v[0]) + r;
    }
    float s = v[0];
    s += __shfl_xor(s, 16);
    s += __shfl_xor(s, 32);
    return s;
}

// ---------------- fused EGNN edge kernel (CSR, wave per dest node, edge pairs) ----------------
__global__ __launch_bounds__(256) void k_egnn_csr(
        const int* __restrict__ rp, const int* __restrict__ cj,
        const float* __restrict__ A, const unsigned* __restrict__ Bp,     // bf16 pairs, stride 260
        const float* __restrict__ coors,
        const float* __restrict__ w_rd, const float* __restrict__ eb1,    // [514]
        const float* __restrict__ ew2,                                    // [514][16]
        const float* __restrict__ eb2,                                    // [16]
        const float* __restrict__ cw1, const float* __restrict__ cb1,     // [16][64],[64]
        const float* __restrict__ cw2, const float* __restrict__ cb2,     // [64],[1]
        float* __restrict__ coorsOut, float* __restrict__ macc, int N) {
    __shared__ __align__(16) float s_ew2t[16 * BPAD];   // [c][k], stride 520
    __shared__ float s_cw1[16 * 64];
    __shared__ float s_cb1[64], s_cw2[64], s_eb2[16];
    for (int t = threadIdx.x; t < EHID_D * 16; t += 256) {
        int k = t >> 4, c = t & 15;
        s_ew2t[c * BPAD + k] = ew2[t];
    }
    for (int t = threadIdx.x; t < 16 * 6; t += 256) {
        int c = t / 6, k = EHID_D + t % 6;
        s_ew2t[c * BPAD + k] = 0.f;
    }
    for (int t = threadIdx.x; t < 1024; t += 256) s_cw1[t] = cw1[t];
    if (threadIdx.x < 64) { s_cb1[threadIdx.x] = cb1[threadIdx.x]; s_cw2[threadIdx.x] = cw2[threadIdx.x]; }
    if (threadIdx.x < 16) s_eb2[threadIdx.x] = eb2[threadIdx.x];
    __syncthreads();
    const int lane = threadIdx.x & 63;
    const int node = blockIdx.x * 4 + (threadIdx.x >> 6);
    if (node >= N) return;
    const float cb2v = cb2[0];
    // per-lane k strip: k0 = 2*lane + 128*t, t=0..4 (zero-padded beyond 514)
    float Af[10], wrdv[10], ebv[10];
#pragma unroll
    for (int t = 0; t < 5; ++t) {
        int k0 = 2 * lane + 128 * t;
        bool v = k0 < EHID_D;
        Af[2 * t]     = v ? A[(size_t)node * EHID_D + k0] : 0.f;
        Af[2 * t + 1] = v ? A[(size_t)node * EHID_D + k0 + 1] : 0.f;
        wrdv[2 * t]     = v ? w_rd[k0] : 0.f;
        wrdv[2 * t + 1] = v ? w_rd[k0 + 1] : 0.f;
        ebv[2 * t]      = v ? eb1[k0] : 0.f;
        ebv[2 * t + 1]  = v ? eb1[k0 + 1] : 0.f;
    }
    int start = rp[node], end = rp[node + 1];
    float ci0 = coors[(size_t)node * 3], ci1 = coors[(size_t)node * 3 + 1], ci2 = coors[(size_t)node * 3 + 2];
    float cacc0 = 0.f, cacc1 = 0.f, cacc2 = 0.f;
    float mi_acc = 0.f;   // channel (lane&15)
    for (int p = start; p < end; p += 2) {
        int j0 = cj[p];
        bool has1 = (p + 1 < end);
        int j1 = has1 ? cj[p + 1] : j0;
        float r00 = coors[(size_t)j0 * 3] - ci0, r01 = coors[(size_t)j0 * 3 + 1] - ci1, r02 = coors[(size_t)j0 * 3 + 2] - ci2;
        float r10 = coors[(size_t)j1 * 3] - ci0, r11 = coors[(size_t)j1 * 3 + 1] - ci1, r12 = coors[(size_t)j1 * 3 + 2] - ci2;
        float rd0 = r00 * r00 + r01 * r01 + r02 * r02;
        float rd1 = r10 * r10 + r11 * r11 + r12 * r12;
        const unsigned* B0 = Bp + (size_t)j0 * 260;
        const unsigned* B1 = Bp + (size_t)j1 * 260;
        float mc0[16] = {}, mc1[16] = {};
#pragma unroll
        for (int t = 0; t < 5; ++t) {
            unsigned b0 = B0[lane + 64 * t];
            unsigned b1 = B1[lane + 64 * t];
            float g00 = siluf(Af[2 * t]     + bf_lo(b0) + rd0 * wrdv[2 * t]     + ebv[2 * t]);
            float g01 = siluf(Af[2 * t + 1] + bf_hi(b0) + rd0 * wrdv[2 * t + 1] + ebv[2 * t + 1]);
            float g10 = siluf(Af[2 * t]     + bf_lo(b1) + rd1 * wrdv[2 * t]     + ebv[2 * t]);
            float g11 = siluf(Af[2 * t + 1] + bf_hi(b1) + rd1 * wrdv[2 * t + 1] + ebv[2 * t + 1]);
            const float* wp = &s_ew2t[2 * lane + 128 * t];
#pragma unroll
            for (int c = 0; c < 16; ++c) {
                float2 w = *(const float2*)(wp + c * BPAD);
                mc0[c] += g00 * w.x + g01 * w.y;
                mc1[c] += g10 * w.x + g11 * w.y;
            }
        }
        float M0 = reduce16x64(mc0, lane);
        float M1 = reduce16x64(mc1, lane);
        float m0 = siluf(M0 + s_eb2[lane & 15]);
        float m1 = siluf(M1 + s_eb2[lane & 15]);
        mi_acc += m0 + (has1 ? m1 : 0.f);
        // coordinate gates (both edges share cw1 reads)
        float a0 = s_cb1[lane], a1 = s_cb1[lane];
#pragma unroll
        for (int c = 0; c < 16; ++c) {
            float w = s_cw1[c * 64 + lane];
            a0 += __shfl(m0, c) * w;
            a1 += __shfl(m1, c) * w;
        }
        float p0 = siluf(a0) * s_cw2[lane];
        float p1 = siluf(a1) * s_cw2[lane];
#pragma unroll
        for (int off = 32; off; off >>= 1) { p0 += __shfl_xor(p0, off); p1 += __shfl_xor(p1, off); }
        float cw0 = p0 + cb2v;
        float cw1v = p1 + cb2v;
        cacc0 += cw0 * r00 + (has1 ? cw1v * r10 : 0.f);
        cacc1 += cw0 * r01 + (has1 ? cw1v * r11 : 0.f);
        cacc2 += cw0 * r02 + (has1 ? cw1v * r12 : 0.f);
    }
    if (lane < 16) macc[(size_t)node * M_D + lane] = mi_acc;
    if (lane == 0) {
        coorsOut[(size_t)node * 3]     = ci0 + cacc0;
        coorsOut[(size_t)node * 3 + 1] = ci1 + cacc1;
        coorsOut[(size_t)node * 3 + 2] = ci2 + cacc2;
    }
}

__global__ void k_concat(float* __restrict__ cat, const float* __restrict__ f,
                         const float* __restrict__ m, int n) {
    int i = blockIdx.x * 256 + threadIdx.x;
    if (i >= n * NIN_D) return;
    int r = i / NIN_D, c = i - r * NIN_D;
    cat[i] = (c < H_D) ? f[r * H_D + c] : m[r * M_D + (c - H_D)];
}

// ---------------- aux head: fused gather-concat GEMM + relu + matvec ----------------
__global__ __launch_bounds__(256) void k_aux(const float* __restrict__ x1, const float* __restrict__ x2,
                                             const int* __restrict__ i0, const int* __restrict__ i1,
                                             const float* __restrict__ w1, const float* __restrict__ b1,
                                             const float* __restrict__ w2, const float* __restrict__ b2,
                                             float* __restrict__ dist, int nE) {
    __shared__ __align__(16) float sX[32][33];
    __shared__ __align__(16) float sW[32][128];
    __shared__ __align__(16) float sH[32][129];
    const int tid = threadIdx.x;
    const int te = (tid >> 5) << 2;
    const int tn = (tid & 31) << 2;
    const int be = blockIdx.x * 32;
    float acc[4][4] = {};
    for (int k0 = 0; k0 < 256; k0 += 32) {
#pragma unroll
        for (int t = 0; t < 4; ++t) {
            int idx = tid + 256 * t;
            int m = idx >> 5, k = idx & 31;
            int ge = be + m, gk = k0 + k;
            float v = 0.f;
            if (ge < nE)
                v = (gk < 128) ? x1[(size_t)i0[ge] * H_D + gk]
                               : x2[(size_t)i1[ge] * H_D + (gk - 128)];
            sX[m][k] = v;
        }
#pragma unroll
        for (int t = 0; t < 16; ++t) {
            int idx = tid + 256 * t;
            int k = idx >> 7, n = idx & 127;
            sW[k][n] = w1[(size_t)(k0 + k) * 128 + n];
        }
        __syncthreads();
#pragma unroll
        for (int k = 0; k < 32; ++k) {
            float aa[4] = {sX[te][k], sX[te + 1][k], sX[te + 2][k], sX[te + 3][k]};
            float4 bv = *(const float4*)&sW[k][tn];
            float bb[4] = {bv.x, bv.y, bv.z, bv.w};
#pragma unroll
            for (int i = 0; i < 4; ++i)
#pragma unroll
                for (int j = 0; j < 4; ++j) acc[i][j] += aa[i] * bb[j];
        }
        __syncthreads();
    }
#pragma unroll
    for (int i = 0; i < 4; ++i)
#pragma unroll
        for (int j = 0; j < 4; ++j)
            sH[te + i][tn + j] = reluf(acc[i][j] + b1[tn + j]);
    __syncthreads();
    const int wv = tid >> 6, lane = tid & 63;
    for (int r = wv; r < 32; r += 4) {
        int ge = be + r;
        if (ge >= nE) continue;
        float s = sH[r][lane] * w2[lane] + sH[r][lane + 64] * w2[lane + 64];
#pragma unroll
        for (int off = 32; off; off >>= 1) s += __shfl_xor(s, off);
        if (lane == 0) dist[ge] = reluf(s + b2[0]);
    }
}

// ---------------- host ----------------
extern "C" void kernel_launch(void* const* d_in, const int* in_sizes, int n_in,
                              void* d_out, int out_size, void* d_ws, size_t ws_size,
                              hipStream_t stream) {
    const float* x1_in = (const float*)d_in[0];
    const float* x2_in = (const float*)d_in[1];
    const float* pos1  = (const float*)d_in[2];
    const float* pos2  = (const float*)d_in[3];
    const int* ei_intra1 = (const int*)d_in[4];
    const int* ei_intra2 = (const int*)d_in[5];
    const int* ei_12 = (const int*)d_in[6];
    const int* ei_21 = (const int*)d_in[7];
    const int* ei_int = (const int*)d_in[8];
    const float* g0_w  = (const float*)d_in[9];
    const float* g0_as = (const float*)d_in[10];
    const float* g0_ad = (const float*)d_in[11];
    const float* g0_b  = (const float*)d_in[12];
    const float* g1_w  = (const float*)d_in[13];
    const float* g1_as = (const float*)d_in[14];
    const float* g1_ad = (const float*)d_in[15];
    const float* g1_b  = (const float*)d_in[16];
    const float* it_ws = (const float*)d_in[17];
    const float* it_wd = (const float*)d_in[18];
    const float* it_as = (const float*)d_in[19];
    const float* it_ad = (const float*)d_in[20];
    const float* it_b  = (const float*)d_in[21];
    const float* eg_e_w1 = (const float*)d_in[22];
    const float* eg_e_b1 = (const float*)d_in[23];
    const float* eg_e_w2 = (const float*)d_in[24];
    const float* eg_e_b2 = (const float*)d_in[25];
    const float* eg_c_w1 = (const float*)d_in[26];
    const float* eg_c_b1 = (const float*)d_in[27];
    const float* eg_c_w2 = (const float*)d_in[28];
    const float* eg_c_b2 = (const float*)d_in[29];
    const float* eg_n_w1 = (const float*)d_in[30];
    const float* eg_n_b1 = (const float*)d_in[31];
    const float* eg_n_w2 = (const float*)d_in[32];
    const float* eg_n_b2 = (const float*)d_in[33];
    const float* lin_w = (const float*)d_in[34];
    const float* lin_b = (const float*)d_in[35];
    const float* aux_w1 = (const float*)d_in[36];
    const float* aux_b1 = (const float*)d_in[37];
    const float* aux_w2 = (const float*)d_in[38];
    const float* aux_b2 = (const float*)d_in[39];
    float* dout = (float*)d_out;

    // ---- workspace layout ----
    float* wsf = (float*)d_ws;
    size_t off = 0;
    auto alloc = [&](size_t nfl) { float* p = wsf + off; off += (nfl + 255) & ~(size_t)255; return p; };
    float* x1a = alloc((size_t)NN * H_D);
    float* x2a = alloc((size_t)NN * H_D);
    float* x1b = alloc((size_t)NN * H_D);
    float* x2b = alloc((size_t)NN * H_D);
    float* gatbuf = alloc((size_t)2 * NN * H_D);   // hs|hd; aliased as concat buf in EGNN
    float* hs = gatbuf;
    float* hd = gatbuf + (size_t)NN * H_D;
    float* esb = alloc(NN);
    float* edb = alloc(NN);
    float* co1a = alloc(NN * 3);
    float* co1b = alloc(NN * 3);
    float* co2a = alloc(NN * 3);
    float* co2b = alloc(NN * 3);
    float* macc = alloc((size_t)NN * M_D);
    float* Abuf = alloc((size_t)NN * EHID_D);
    unsigned* B16 = (unsigned*)alloc((size_t)NN * 260);       // bf16 pairs
    int* cnt4 = (int*)alloc(4 * NN);
    int* rp4 = (int*)alloc(4 * (NN + 1));
    int* cjI1 = (int*)alloc(EIA_D);
    int* cjI2 = (int*)alloc(EIA_D);
    int* cj12 = (int*)alloc(EIR_D);
    int* cj21 = (int*)alloc(EIR_D);
    float* catb = gatbuf;          // N*144
    float* nh   = Abuf;            // N*256 fits in N*514

    const int N = NN, H = H_D;
    dim3 grid_h((N + 63) / 64, (H + 63) / 64);
    dim3 grid_A((N + 63) / 64, (EHID_D + 63) / 64);
    dim3 grid_nh((N + 63) / 64, (NHID_D + 63) / 64);
    int gNW = (N + 3) / 4;         // 4 waves/block kernels
    int gEA = (EIA_D + 255) / 256;

    // ---- build 4 CSRs (dest-sorted) ----
    k_filli<<<(4 * N + 255) / 256, 256, 0, stream>>>(cnt4, 0, 4 * N);
    k_hist<<<gEA, 256, 0, stream>>>(ei_intra1 + EIA_D, EIA_D, cnt4);
    k_hist<<<gEA, 256, 0, stream>>>(ei_intra2 + EIA_D, EIA_D, cnt4 + N);
    k_hist<<<gEA, 256, 0, stream>>>(ei_12 + EIR_D, EIR_D, cnt4 + 2 * N);
    k_hist<<<gEA, 256, 0, stream>>>(ei_21 + EIR_D, EIR_D, cnt4 + 3 * N);
    k_scan4<<<4, 256, 0, stream>>>(cnt4, N, rp4);
    k_filli<<<(4 * N + 255) / 256, 256, 0, stream>>>(cnt4, 0, 4 * N);
    const int* rpI1 = rp4;
    const int* rpI2 = rp4 + (N + 1);
    const int* rp12 = rp4 + 2 * (N + 1);
    const int* rp21 = rp4 + 3 * (N + 1);
    k_scatter<<<gEA, 256, 0, stream>>>(ei_intra1, ei_intra1 + EIA_D, EIA_D, rpI1, cnt4, cjI1);
    k_scatter<<<gEA, 256, 0, stream>>>(ei_intra2, ei_intra2 + EIA_D, EIA_D, rpI2, cnt4 + N, cjI2);
    k_scatter<<<gEA, 256, 0, stream>>>(ei_12, ei_12 + EIR_D, EIR_D, rp12, cnt4 + 2 * N, cj12);
    k_scatter<<<gEA, 256, 0, stream>>>(ei_21, ei_21 + EIR_D, EIR_D, rp21, cnt4 + 3 * N, cj21);

    // ---- GAT stage ----
    auto gat = [&](const float* xsrc, const float* xdst, bool same,
                   const int* rp, const int* cjj, int hasSelf,
                   const float* wsrc, const float* wdst,
                   const float* as_, const float* ad_, const float* b_,
                   int K, float* outb) {
        k_gemm<0, false, false><<<grid_h, 256, 0, stream>>>(xsrc, wsrc, nullptr, nullptr, hs, N, H, K, H);
        const float* hdp = hs;
        if (!same) {
            k_gemm<0, false, false><<<grid_h, 256, 0, stream>>>(xdst, wdst, nullptr, nullptr, hd, N, H, K, H);
            hdp = hd;
        }
        k_rowdot<<<gNW, 256, 0, stream>>>(hs, as_, esb, N);
        k_rowdot<<<gNW, 256, 0, stream>>>(hdp, ad_, edb, N);
        k_gat_fused<<<gNW, 256, 0, stream>>>(rp, cjj, hasSelf, esb, edb, hs, b_, outb, N);
    };

    gat(x1_in, x1_in, true, rpI1, cjI1, 1, g0_w, g0_w, g0_as, g0_ad, g0_b, FIN_D, x1a);
    gat(x2_in, x2_in, true, rpI2, cjI2, 1, g0_w + FIN_D * H, g0_w + FIN_D * H,
        g0_as + H, g0_ad + H, g0_b + H, FIN_D, x2a);
    const float* cx1 = x1a;
    const float* cx2 = x2a;
    gat(cx1, cx1, true, rpI1, cjI1, 1, g1_w, g1_w, g1_as, g1_ad, g1_b, H, x1b);
    gat(cx2, cx2, true, rpI2, cjI2, 1, g1_w + H * H, g1_w + H * H,
        g1_as + H, g1_ad + H, g1_b + H, H, x2b);
    cx1 = x1b; cx2 = x2b;
    {
        float* outs1[2] = {x1a, x1b};
        float* outs2[2] = {x2a, x2b};
        for (int l = 0; l < 2; ++l) {
            int p0 = l * 2 + 0, p1 = l * 2 + 1;
            float* o2 = outs2[l == 0 ? 0 : 1];
            float* o1 = outs1[l == 0 ? 0 : 1];
            gat(cx1, cx2, false, rp12, cj12, 0,
                it_ws + (size_t)p0 * H * H, it_wd + (size_t)p0 * H * H,
                it_as + p0 * H, it_ad + p0 * H, it_b + p0 * H, H, o2);
            gat(cx2, cx1, false, rp21, cj21, 0,
                it_ws + (size_t)p1 * H * H, it_wd + (size_t)p1 * H * H,
                it_as + p1 * H, it_ad + p1 * H, it_b + p1 * H, H, o1);
            cx1 = o1; cx2 = o2;
        }
    }

    // ---- EGNN stage ----
    k_padzero<<<(N * 6 + 255) / 256, 256, 0, stream>>>((unsigned short*)B16, N);
    auto egnn = [&](const float* feats, const float* coors, const int* rp, const int* cjj, int pidx,
                    float* featsOut, float* coorsOut) {
        const float* ew1 = eg_e_w1 + (size_t)pidx * EIN_D * EHID_D;
        k_gemm<0, false, false><<<grid_A, 256, 0, stream>>>(feats, ew1, nullptr, nullptr, Abuf, N, EHID_D, H, EHID_D);
        k_gemm<0, false, true><<<grid_A, 256, 0, stream>>>(feats, ew1 + (size_t)H * EHID_D, nullptr, nullptr,
                                                           (float*)B16, N, EHID_D, H, BPAD);
        k_egnn_csr<<<gNW, 256, 0, stream>>>(rp, cjj, Abuf, B16, coors,
                                            ew1 + (size_t)256 * EHID_D, eg_e_b1 + pidx * EHID_D,
                                            eg_e_w2 + (size_t)pidx * EHID_D * M_D, eg_e_b2 + pidx * M_D,
                                            eg_c_w1 + pidx * M_D * 64, eg_c_b1 + pidx * 64,
                                            eg_c_w2 + pidx * 64, eg_c_b2 + pidx,
                                            coorsOut, macc, N);
        k_concat<<<(N * NIN_D + 255) / 256, 256, 0, stream>>>(catb, feats, macc, N);
        k_gemm<2, false, false><<<grid_nh, 256, 0, stream>>>(catb, eg_n_w1 + (size_t)pidx * NIN_D * NHID_D,
                                                             eg_n_b1 + pidx * NHID_D, nullptr, nh, N, NHID_D, NIN_D, NHID_D);
        k_gemm<0, true, false><<<grid_h, 256, 0, stream>>>(nh, eg_n_w2 + (size_t)pidx * NHID_D * H,
                                                           eg_n_b2 + pidx * H, feats, featsOut, N, H, NHID_D, H);
    };
    egnn(cx1, pos1, rpI1, cjI1, 0, x1a, co1a);
    egnn(cx2, pos2, rpI2, cjI2, 1, x2a, co2a);
    cx1 = x1a; cx2 = x2a;
    egnn(cx1, co1a, rpI1, cjI1, 2, x1b, co1b);
    egnn(cx2, co2a, rpI2, cjI2, 3, x2b, co2b);
    cx1 = x1b; cx2 = x2b;

    // ---- heads ----
    k_nodescore<<<gNW, 256, 0, stream>>>(cx1, lin_w, lin_b, dout, N);
    k_nodescore<<<gNW, 256, 0, stream>>>(cx2, lin_w, lin_b, dout + N, N);
    k_aux<<<(EIT_D + 31) / 32, 256, 0, stream>>>(cx1, cx2, ei_int, ei_int + EIT_D,
                                                 aux_w1, aux_b1, aux_w2, aux_b2,
                                                 dout + 2 * N, EIT_D);
}

// Round 4
// 5521.424 us; speedup vs baseline: 1.0593x; 1.0593x over previous
//
#include <hip/hip_runtime.h>
#include <cstdint>
#include <cstddef>

// ---- problem constants ----
#define NN     20000
#define FIN_D  64
#define H_D    128
#define M_D    16
#define EIA_D  256000
#define EIR_D  256000
#define EIT_D  100000
#define EIN_D  257
#define EHID_D 514
#define NIN_D  144
#define NHID_D 256
#define BPAD   520          // padded EHID for bf16 B rows (260 uint pairs)

typedef short bfrag __attribute__((ext_vector_type(8)));   // 8 bf16 (4 VGPRs)
typedef float ffrag __attribute__((ext_vector_type(4)));   // 4 fp32 acc

__device__ __forceinline__ float siluf(float x) { return x / (1.f + __expf(-x)); }
__device__ __forceinline__ float reluf(float x) { return x > 0.f ? x : 0.f; }
__device__ __forceinline__ unsigned short f2bf(float f) {  // RNE fp32->bf16
    unsigned u = __float_as_uint(f);
    return (unsigned short)((u + 0x7FFFu + ((u >> 16) & 1u)) >> 16);
}
__device__ __forceinline__ float bf2f(unsigned short h) { return __uint_as_float(((unsigned)h) << 16); }
__device__ __forceinline__ float bf_lo(unsigned u) { return __uint_as_float(u << 16); }
__device__ __forceinline__ float bf_hi(unsigned u) { return __uint_as_float(u & 0xFFFF0000u); }

// ---------------- CSR build ----------------
__global__ void k_filli(int* p, int v, int n) {
    int i = blockIdx.x * 256 + threadIdx.x; if (i < n) p[i] = v;
}
__global__ void k_hist(const int* __restrict__ si, int nE, int* __restrict__ cnt) {
    int e = blockIdx.x * 256 + threadIdx.x; if (e < nE) atomicAdd(&cnt[si[e]], 1);
}
__global__ void k_scan4(const int* __restrict__ cnt4, int n, int* __restrict__ rp4) {
    const int* cnt = cnt4 + (size_t)blockIdx.x * n;
    int* rp = rp4 + (size_t)blockIdx.x * (n + 1);
    __shared__ int tmp[256];
    __shared__ int carry;
    if (threadIdx.x == 0) { carry = 0; rp[0] = 0; }
    __syncthreads();
    for (int base = 0; base < n; base += 256) {
        int i = base + threadIdx.x;
        int v = (i < n) ? cnt[i] : 0;
        tmp[threadIdx.x] = v;
        __syncthreads();
        for (int off = 1; off < 256; off <<= 1) {
            int t = (threadIdx.x >= off) ? tmp[threadIdx.x - off] : 0;
            __syncthreads();
            tmp[threadIdx.x] += t;
            __syncthreads();
        }
        if (i < n) rp[i + 1] = carry + tmp[threadIdx.x];
        __syncthreads();
        if (threadIdx.x == 0) carry += tmp[255];
        __syncthreads();
    }
}
__global__ void k_scatter(const int* __restrict__ sj, const int* __restrict__ si, int nE,
                          const int* __restrict__ rp, int* __restrict__ cursor, int* __restrict__ colj) {
    int e = blockIdx.x * 256 + threadIdx.x;
    if (e >= nE) return;
    int i = si[e];
    int p = rp[i] + atomicAdd(&cursor[i], 1);
    colj[p] = sj[e];
}

// ---------------- weight prep: transpose + hi/lo bf16 split ----------------
struct PrepDesc { const float* src; unsigned dstOff; int K, N, Kpad, Npad; };
struct PrepArgs { PrepDesc d[29]; };
__global__ void k_prep(PrepArgs pa, unsigned short* __restrict__ Wt) {
    PrepDesc de = pa.d[blockIdx.x];
    int tot = de.Npad * de.Kpad;
    unsigned short* hi = Wt + de.dstOff;
    unsigned short* lo = hi + tot;
    for (int i = blockIdx.y * 256 + threadIdx.x; i < tot; i += gridDim.y * 256) {
        int n = i / de.Kpad, k = i - n * de.Kpad;
        float v = (n < de.N && k < de.K) ? de.src[(size_t)k * de.N + n] : 0.f;
        unsigned short h = f2bf(v);
        hi[i] = h;
        lo[i] = f2bf(v - bf2f(h));
    }
}

// ---------------- MFMA GEMM: C = act(A@W + bias) (+res), fp32 via bf16 hi/lo split ----------
// Block 256 (4 waves). Tile M=128, N=64. Wave w: rows [w*32,w*32+32), 2x4 mfma tiles.
// A fp32 from global (or gathered rows), split to bf16 hi/lo in LDS (fragment-order layout).
// W pre-split bf16 [Npad][Kpad] (transposed) read directly from global as B-frags.
template<int ACT, bool RES, bool OBF, bool GATHER>
__global__ __launch_bounds__(256) void k_mm(
        const float* __restrict__ A, const float* __restrict__ A2,
        const int* __restrict__ gi0, const int* __restrict__ gi1,
        const unsigned short* __restrict__ Wh, const unsigned short* __restrict__ Wl,
        const float* __restrict__ bias, const float* __restrict__ res,
        float* __restrict__ C, int M, int Nc, int K, int Kpad, int ldc) {
    __shared__ __align__(16) unsigned short sAh[128 * 32];   // frag-order: ((grp*4+q)*16+m) 16B units
    __shared__ __align__(16) unsigned short sAl[128 * 32];
    const int tid = threadIdx.x;
    const int bm = blockIdx.x * 128, bn = blockIdx.y * 64;
    const int wv = tid >> 6, lane = tid & 63;
    ffrag acc[2][4];
#pragma unroll
    for (int mt = 0; mt < 2; ++mt)
#pragma unroll
        for (int nt = 0; nt < 4; ++nt)
#pragma unroll
            for (int r = 0; r < 4; ++r) acc[mt][nt][r] = 0.f;
    // staging coords: thread -> (row, 16-wide k strip)
    const int sr = tid >> 1;
    const int sks = (tid & 1) * 16;
    const int gm_s = bm + sr;
    const int sgmt = sr >> 4, smm = sr & 15, qb = (tid & 1) * 2;
    int gidx0 = 0, gidx1 = 0;
    if (GATHER && gm_s < M) { gidx0 = gi0[gm_s]; gidx1 = gi1[gm_s]; }
    const int q = lane >> 4, mm = lane & 15;

    for (int k0 = 0; k0 < Kpad; k0 += 32) {
        float v[16];
        bool valid = (gm_s < M) && (k0 + sks < K);
        if (valid) {
            const float* src;
            int kk = k0 + sks;
            if (GATHER) src = (kk < 128) ? (A + (size_t)gidx0 * 128 + kk)
                                         : (A2 + (size_t)gidx1 * 128 + (kk - 128));
            else src = A + (size_t)gm_s * K + kk;
#pragma unroll
            for (int i = 0; i < 4; ++i) {
                float4 t4 = ((const float4*)src)[i];
                v[4 * i] = t4.x; v[4 * i + 1] = t4.y; v[4 * i + 2] = t4.z; v[4 * i + 3] = t4.w;
            }
        } else {
#pragma unroll
            for (int i = 0; i < 16; ++i) v[i] = 0.f;
        }
#pragma unroll
        for (int o = 0; o < 2; ++o) {
            unsigned hw[4], lw[4];
#pragma unroll
            for (int p = 0; p < 4; ++p) {
                float f0 = v[o * 8 + 2 * p], f1 = v[o * 8 + 2 * p + 1];
                unsigned short h0 = f2bf(f0), h1 = f2bf(f1);
                unsigned short l0 = f2bf(f0 - bf2f(h0)), l1 = f2bf(f1 - bf2f(h1));
                hw[p] = (unsigned)h0 | ((unsigned)h1 << 16);
                lw[p] = (unsigned)l0 | ((unsigned)l1 << 16);
            }
            int off16 = (sgmt * 4 + qb + o) * 16 + smm;
            ((uint4*)sAh)[off16] = make_uint4(hw[0], hw[1], hw[2], hw[3]);
            ((uint4*)sAl)[off16] = make_uint4(lw[0], lw[1], lw[2], lw[3]);
        }
        __syncthreads();
        // B-frags direct from global (L2-resident weight tables)
        bfrag bh[4], bl[4];
#pragma unroll
        for (int nt = 0; nt < 4; ++nt) {
            size_t woff = (size_t)(bn + nt * 16 + mm) * Kpad + k0 + q * 8;
            bh[nt] = *(const bfrag*)(Wh + woff);
            bl[nt] = *(const bfrag*)(Wl + woff);
        }
#pragma unroll
        for (int mt = 0; mt < 2; ++mt) {
            int off16 = ((wv * 2 + mt) * 4 + q) * 16 + mm;
            bfrag ah = ((const bfrag*)sAh)[off16];
            bfrag al = ((const bfrag*)sAl)[off16];
#pragma unroll
            for (int nt = 0; nt < 4; ++nt) {
                acc[mt][nt] = __builtin_amdgcn_mfma_f32_16x16x32_bf16(ah, bh[nt], acc[mt][nt], 0, 0, 0);
                acc[mt][nt] = __builtin_amdgcn_mfma_f32_16x16x32_bf16(ah, bl[nt], acc[mt][nt], 0, 0, 0);
                acc[mt][nt] = __builtin_amdgcn_mfma_f32_16x16x32_bf16(al, bh[nt], acc[mt][nt], 0, 0, 0);
            }
        }
        __syncthreads();
    }
    // epilogue: C/D layout col=lane&15, row=(lane>>4)*4+reg
#pragma unroll
    for (int mt = 0; mt < 2; ++mt) {
#pragma unroll
        for (int nt = 0; nt < 4; ++nt) {
            int gn = bn + nt * 16 + mm;
            if (gn >= Nc) continue;
#pragma unroll
            for (int r = 0; r < 4; ++r) {
                int gm = bm + wv * 32 + mt * 16 + q * 4 + r;
                if (gm >= M) continue;
                float vv = acc[mt][nt][r];
                if (bias) vv += bias[gn];
                if (ACT == 1) vv = reluf(vv);
                if (ACT == 2) vv = siluf(vv);
                if (RES) vv += res[(size_t)gm * Nc + gn];
                if (OBF) ((unsigned short*)C)[(size_t)gm * ldc + gn] = f2bf(vv);
                else C[(size_t)gm * ldc + gn] = vv;
            }
        }
    }
}

// zero the bf16 pad columns (elements 514..519 of each padded row)
__global__ void k_padzero(unsigned short* __restrict__ B16, int n) {
    int i = blockIdx.x * 256 + threadIdx.x;
    if (i >= n * 6) return;
    int r = i / 6, c = 514 + i % 6;
    B16[(size_t)r * BPAD + c] = 0;
}

// ---------------- paired row dots (es/ed): wave per node ----------------
__global__ void k_rowdot2(const float* __restrict__ hs, const float* __restrict__ hd,
                          const float* __restrict__ a_s, const float* __restrict__ a_d,
                          float* __restrict__ es, float* __restrict__ ed, int n) {
    int w = blockIdx.x * 4 + (threadIdx.x >> 6);
    int lane = threadIdx.x & 63;
    if (w >= n) return;
    const float* r1 = hs + (size_t)w * H_D;
    const float* r2 = hd + (size_t)w * H_D;
    float s1 = r1[lane] * a_s[lane] + r1[lane + 64] * a_s[lane + 64];
    float s2 = r2[lane] * a_d[lane] + r2[lane + 64] * a_d[lane + 64];
#pragma unroll
    for (int off = 32; off; off >>= 1) { s1 += __shfl_xor(s1, off); s2 += __shfl_xor(s2, off); }
    if (lane == 0) { es[w] = s1; ed[w] = s2; }
}

__global__ void k_nodescore(const float* __restrict__ x, const float* __restrict__ wv,
                            const float* __restrict__ b, float* __restrict__ o, int n) {
    int w = blockIdx.x * 4 + (threadIdx.x >> 6);
    int lane = threadIdx.x & 63;
    if (w >= n) return;
    const float* r = x + (size_t)w * H_D;
    float s = r[lane] * wv[lane] + r[lane + 64] * wv[lane + 64];
#pragma unroll
    for (int off = 32; off; off >>= 1) s += __shfl_xor(s, off);
    if (lane == 0) o[w] = s + b[0];
}

// ---------------- fused GAT softmax-aggregate (CSR, wave per dest node) ----------------
__global__ __launch_bounds__(256) void k_gat_fused(
        const int* __restrict__ rp, const int* __restrict__ cj, int hasSelf,
        const float* __restrict__ es, const float* __restrict__ ed,
        const float* __restrict__ hs, const float* __restrict__ bias,
        float* __restrict__ out, int N) {
    int node = blockIdx.x * 4 + (threadIdx.x >> 6);
    int lane = threadIdx.x & 63;
    if (node >= N) return;
    int start = rp[node], end = rp[node + 1];
    float edi = ed[node];
    float m = -INFINITY;
    for (int p = start + lane; p < end; p += 64) {
        float v = es[cj[p]] + edi;
        v = v < 0.f ? 0.2f * v : v;
        m = fmaxf(m, v);
    }
#pragma unroll
    for (int off = 32; off; off >>= 1) m = fmaxf(m, __shfl_xor(m, off));
    float vself = 0.f;
    if (hasSelf) {
        vself = es[node] + edi;
        vself = vself < 0.f ? 0.2f * vself : vself;
        m = fmaxf(m, vself);
    }
    float den = 0.f, a0 = 0.f, a1 = 0.f;
    for (int p = start; p < end; ++p) {
        int j = cj[p];
        float v = es[j] + edi;
        v = v < 0.f ? 0.2f * v : v;
        float ex = __expf(v - m);
        den += ex;
        const float* hr = hs + (size_t)j * H_D;
        a0 += ex * hr[lane];
        a1 += ex * hr[lane + 64];
    }
    if (hasSelf) {
        float ex = __expf(vself - m);
        den += ex;
        const float* hr = hs + (size_t)node * H_D;
        a0 += ex * hr[lane];
        a1 += ex * hr[lane + 64];
    }
    float inv = 1.f / (den + 1e-16f);
    out[(size_t)node * H_D + lane]      = reluf(a0 * inv + bias[lane]);
    out[(size_t)node * H_D + 64 + lane] = reluf(a1 * inv + bias[lane + 64]);
}

// ---------------- 16-channel x 64-lane split-butterfly reduce ----------------
__device__ __forceinline__ float reduce16x64(float (&v)[16], int lane) {
#pragma unroll
    for (int q = 0; q < 8; ++q) {
        float send = (lane & 8) ? v[q] : v[q + 8];
        float r = __shfl_xor(send, 8);
        v[q] = ((lane & 8) ? v[q + 8] : v[q]) + r;
    }
#pragma unroll
    for (int q = 0; q < 4; ++q) {
        float send = (lane & 4) ? v[q] : v[q + 4];
        float r = __shfl_xor(send, 4);
        v[q] = ((lane & 4) ? v[q + 4] : v[q]) + r;
    }
#pragma unroll
    for (int q = 0; q < 2; ++q) {
        float send = (lane & 2) ? v[q] : v[q + 2];
        float r = __shfl_xor(send, 2);
        v[q] = ((lane & 2) ? v[q + 2] : v[q]) + r;
    }
    {
        float send = (lane & 1) ? v[0] : v[1];
        float r = __shfl_xor(send, 1);
        v[0] = ((lane & 1) ? v[1] : v[0]) + r;
    }
    float s = v[0];
    s += __shfl_xor(s, 16);
    s += __shfl_xor(s, 32);
    return s;
}

// ---------------- fused EGNN edge kernel (CSR, wave/node, 4-edge blocking) ----------------
// ew2 deinterleaved into even/odd fp32 LDS arrays, stride 272 (bank=(16c+lane)%32 -> 2-way free)
__global__ __launch_bounds__(256) void k_egnn_csr(
        const int* __restrict__ rp, const int* __restrict__ cj,
        const float* __restrict__ A, const unsigned* __restrict__ Bp,
        const float* __restrict__ coors,
        const float* __restrict__ w_rd, const float* __restrict__ eb1,
        const float* __restrict__ ew2, const float* __restrict__ eb2,
        const float* __restrict__ cw1, const float* __restrict__ cb1,
        const float* __restrict__ cw2, const float* __restrict__ cb2,
        float* __restrict__ coorsOut, float* __restrict__ macc, int N) {
    __shared__ float s_we[16][272];
    __shared__ float s_wo[16][272];
    __shared__ float s_cw1[1024];
    __shared__ float s_cb1[64], s_cw2[64], s_eb2[16];
    for (int i = threadIdx.x; i < 16 * 272; i += 256) {
        int c = i / 272, kp = i - c * 272;
        s_we[c][kp] = (2 * kp < EHID_D) ? ew2[(size_t)(2 * kp) * 16 + c] : 0.f;
        s_wo[c][kp] = (2 * kp + 1 < EHID_D) ? ew2[(size_t)(2 * kp + 1) * 16 + c] : 0.f;
    }
    for (int t = threadIdx.x; t < 1024; t += 256) s_cw1[t] = cw1[t];
    if (threadIdx.x < 64) { s_cb1[threadIdx.x] = cb1[threadIdx.x]; s_cw2[threadIdx.x] = cw2[threadIdx.x]; }
    if (threadIdx.x < 16) s_eb2[threadIdx.x] = eb2[threadIdx.x];
    __syncthreads();
    const int lane = threadIdx.x & 63;
    const int node = blockIdx.x * 4 + (threadIdx.x >> 6);
    if (node >= N) return;
    const float cb2v = cb2[0];
    // hoist A row + weights: k = 2*(lane+64t), t<5
    float Af0[5], Af1[5], wr0[5], wr1[5], eb0[5], ebo[5];
#pragma unroll
    for (int t = 0; t < 5; ++t) {
        int k = 2 * (lane + 64 * t);
        bool v = k < EHID_D;
        if (v) {
            float2 ap = *(const float2*)(A + (size_t)node * EHID_D + k);
            float2 wp = *(const float2*)(w_rd + k);
            float2 bp = *(const float2*)(eb1 + k);
            Af0[t] = ap.x; Af1[t] = ap.y;
            wr0[t] = wp.x; wr1[t] = wp.y;
            eb0[t] = bp.x; ebo[t] = bp.y;
        } else {
            Af0[t] = Af1[t] = wr0[t] = wr1[t] = eb0[t] = ebo[t] = 0.f;
        }
    }
    int start = rp[node], end = rp[node + 1];
    float ci0 = coors[(size_t)node * 3], ci1 = coors[(size_t)node * 3 + 1], ci2 = coors[(size_t)node * 3 + 2];
    float cacc0 = 0.f, cacc1 = 0.f, cacc2 = 0.f;
    float mi_acc = 0.f;
    for (int p = start; p < end; p += 4) {
        int j[4]; bool hv[4];
#pragma unroll
        for (int x = 0; x < 4; ++x) { hv[x] = (p + x < end); j[x] = hv[x] ? cj[p + x] : cj[p]; }
        float rx[4], ry[4], rz[4], rd[4];
#pragma unroll
        for (int x = 0; x < 4; ++x) {
            rx[x] = coors[(size_t)j[x] * 3]     - ci0;
            ry[x] = coors[(size_t)j[x] * 3 + 1] - ci1;
            rz[x] = coors[(size_t)j[x] * 3 + 2] - ci2;
            rd[x] = rx[x] * rx[x] + ry[x] * ry[x] + rz[x] * rz[x];
        }
        float mc0[16] = {}, mc1[16] = {}, mc2[16] = {}, mc3[16] = {};
#pragma unroll
        for (int t = 0; t < 5; ++t) {
            int kp = lane + 64 * t;
            unsigned bb[4];
#pragma unroll
            for (int x = 0; x < 4; ++x) bb[x] = (kp < 260) ? Bp[(size_t)j[x] * 260 + kp] : 0u;
            float g0[4], g1[4];
#pragma unroll
            for (int x = 0; x < 4; ++x) {
                g0[x] = siluf(Af0[t] + bf_lo(bb[x]) + rd[x] * wr0[t] + eb0[t]);
                g1[x] = siluf(Af1[t] + bf_hi(bb[x]) + rd[x] * wr1[t] + ebo[t]);
            }
            int kpl = kp < 272 ? kp : 271;
#pragma unroll
            for (int c = 0; c < 16; ++c) {
                float we = s_we[c][kpl], wo = s_wo[c][kpl];
                mc0[c] += g0[0] * we + g1[0] * wo;
                mc1[c] += g0[1] * we + g1[1] * wo;
                mc2[c] += g0[2] * we + g1[2] * wo;
                mc3[c] += g0[3] * we + g1[3] * wo;
            }
        }
#pragma unroll
        for (int x = 0; x < 4; ++x) {
            float Mx;
            if (x == 0) Mx = reduce16x64(mc0, lane);
            else if (x == 1) Mx = reduce16x64(mc1, lane);
            else if (x == 2) Mx = reduce16x64(mc2, lane);
            else Mx = reduce16x64(mc3, lane);
            float mex = siluf(Mx + s_eb2[lane & 15]);
            float a = s_cb1[lane];
#pragma unroll
            for (int c = 0; c < 16; ++c) a += __shfl(mex, c) * s_cw1[c * 64 + lane];
            float pp = siluf(a) * s_cw2[lane];
#pragma unroll
            for (int off = 32; off; off >>= 1) pp += __shfl_xor(pp, off);
            float cwv = pp + cb2v;
            if (hv[x]) {
                mi_acc += mex;
                cacc0 += cwv * rx[x];
                cacc1 += cwv * ry[x];
                cacc2 += cwv * rz[x];
            }
        }
    }
    if (lane < 16) macc[(size_t)node * M_D + lane] = mi_acc;
    if (lane == 0) {
        coorsOut[(size_t)node * 3]     = ci0 + cacc0;
        coorsOut[(size_t)node * 3 + 1] = ci1 + cacc1;
        coorsOut[(size_t)node * 3 + 2] = ci2 + cacc2;
    }
}

__global__ void k_concat(float* __restrict__ cat, const float* __restrict__ f,
                         const float* __restrict__ m, int n) {
    int i = blockIdx.x * 256 + threadIdx.x;
    if (i >= n * NIN_D) return;
    int r = i / NIN_D, c = i - r * NIN_D;
    cat[i] = (c < H_D) ? f[r * H_D + c] : m[r * M_D + (c - H_D)];
}

// ---------------- dist head final matvec ----------------
__global__ void k_dist(const float* __restrict__ Hb, const float* __restrict__ w2,
                       const float* __restrict__ b2, float* __restrict__ dist, int nE) {
    int e = blockIdx.x * 4 + (threadIdx.x >> 6);
    int lane = threadIdx.x & 63;
    if (e >= nE) return;
    const float* r = Hb + (size_t)e * H_D;
    float s = r[lane] * w2[lane] + r[lane + 64] * w2[lane + 64];
#pragma unroll
    for (int off = 32; off; off >>= 1) s += __shfl_xor(s, off);
    if (lane == 0) dist[e] = reluf(s + b2[0]);
}

// ---------------- host ----------------
extern "C" void kernel_launch(void* const* d_in, const int* in_sizes, int n_in,
                              void* d_out, int out_size, void* d_ws, size_t ws_size,
                              hipStream_t stream) {
    const float* x1_in = (const float*)d_in[0];
    const float* x2_in = (const float*)d_in[1];
    const float* pos1  = (const float*)d_in[2];
    const float* pos2  = (const float*)d_in[3];
    const int* ei_intra1 = (const int*)d_in[4];
    const int* ei_intra2 = (const int*)d_in[5];
    const int* ei_12 = (const int*)d_in[6];
    const int* ei_21 = (const int*)d_in[7];
    const int* ei_int = (const int*)d_in[8];
    const float* g0_w  = (const float*)d_in[9];
    const float* g0_as = (const float*)d_in[10];
    const float* g0_ad = (const float*)d_in[11];
    const float* g0_b  = (const float*)d_in[12];
    const float* g1_w  = (const float*)d_in[13];
    const float* g1_as = (const float*)d_in[14];
    const float* g1_ad = (const float*)d_in[15];
    const float* g1_b  = (const float*)d_in[16];
    const float* it_ws = (const float*)d_in[17];
    const float* it_wd = (const float*)d_in[18];
    const float* it_as = (const float*)d_in[19];
    const float* it_ad = (const float*)d_in[20];
    const float* it_b  = (const float*)d_in[21];
    const float* eg_e_w1 = (const float*)d_in[22];
    const float* eg_e_b1 = (const float*)d_in[23];
    const float* eg_e_w2 = (const float*)d_in[24];
    const float* eg_e_b2 = (const float*)d_in[25];
    const float* eg_c_w1 = (const float*)d_in[26];
    const float* eg_c_b1 = (const float*)d_in[27];
    const float* eg_c_w2 = (const float*)d_in[28];
    const float* eg_c_b2 = (const float*)d_in[29];
    const float* eg_n_w1 = (const float*)d_in[30];
    const float* eg_n_b1 = (const float*)d_in[31];
    const float* eg_n_w2 = (const float*)d_in[32];
    const float* eg_n_b2 = (const float*)d_in[33];
    const float* lin_w = (const float*)d_in[34];
    const float* lin_b = (const float*)d_in[35];
    const float* aux_w1 = (const float*)d_in[36];
    const float* aux_b1 = (const float*)d_in[37];
    const float* aux_w2 = (const float*)d_in[38];
    const float* aux_b2 = (const float*)d_in[39];
    float* dout = (float*)d_out;

    // ---- workspace layout ----
    float* wsf = (float*)d_ws;
    size_t off = 0;
    auto alloc = [&](size_t nfl) { float* p = wsf + off; off += (nfl + 255) & ~(size_t)255; return p; };
    float* x1a = alloc((size_t)NN * H_D);
    float* x2a = alloc((size_t)NN * H_D);
    float* x1b = alloc((size_t)NN * H_D);
    float* x2b = alloc((size_t)NN * H_D);
    float* gatbuf = alloc((size_t)2 * NN * H_D);   // hs|hd; aliased as concat buf in EGNN
    float* hs = gatbuf;
    float* hd = gatbuf + (size_t)NN * H_D;
    float* esb = alloc(NN);
    float* edb = alloc(NN);
    float* co1a = alloc(NN * 3);
    float* co1b = alloc(NN * 3);
    float* co2a = alloc(NN * 3);
    float* co2b = alloc(NN * 3);
    float* macc = alloc((size_t)NN * M_D);
    float* Abuf = alloc((size_t)NN * EHID_D);                 // aliased by nh (post-edge) and Hb (aux)
    unsigned* B16 = (unsigned*)alloc((size_t)NN * 260);       // bf16 pairs, row 260 uints
    int* cnt4 = (int*)alloc(4 * NN);
    int* rp4 = (int*)alloc(4 * (NN + 1));
    int* cjI1 = (int*)alloc(EIA_D);
    int* cjI2 = (int*)alloc(EIA_D);
    int* cj12 = (int*)alloc(EIR_D);
    int* cj21 = (int*)alloc(EIR_D);
    unsigned short* Wt = (unsigned short*)alloc(1100000);     // 2.2M ushorts
    float* catb = gatbuf;          // N*144 < 2*N*128 ✓ (GAT hs/hd dead during EGNN)
    float* nh   = Abuf;            // N*256 fits in N*514; Abuf dead once k_egnn_csr finishes
                                   // (round-3 bug: nh=gatbuf+N*144 overran gatbuf into co*/macc)
    float* Hb   = Abuf;            // 100000*128 floats span Abuf+B16, both dead at aux time ✓

    const int N = NN, H = H_D;
    int gNW = (N + 3) / 4;
    int gEA = (EIA_D + 255) / 256;

    // ---- weight prep descriptors ----
    PrepArgs pa;
    unsigned woffs[29], wsz[29];
    unsigned wo = 0;
    int wi = 0;
    auto addw = [&](const float* src, int K, int Ncols) {
        int Kpad = (K + 31) & ~31;
        int Npad = (Ncols + 63) & ~63;
        pa.d[wi] = {src, wo, K, Ncols, Kpad, Npad};
        woffs[wi] = wo; wsz[wi] = (unsigned)(Npad * Kpad);
        wo += 2u * Npad * Kpad;
        ++wi;
    };
    addw(g0_w, FIN_D, H);                          // 0
    addw(g0_w + FIN_D * H, FIN_D, H);              // 1
    addw(g1_w, H, H);                              // 2
    addw(g1_w + H * H, H, H);                      // 3
    for (int p = 0; p < 4; ++p) addw(it_ws + (size_t)p * H * H, H, H);   // 4..7
    for (int p = 0; p < 4; ++p) addw(it_wd + (size_t)p * H * H, H, H);   // 8..11
    for (int p = 0; p < 4; ++p) {                  // 12..19
        const float* ew1 = eg_e_w1 + (size_t)p * EIN_D * EHID_D;
        addw(ew1, H, EHID_D);
        addw(ew1 + (size_t)H * EHID_D, H, EHID_D);
    }
    for (int p = 0; p < 4; ++p) addw(eg_n_w1 + (size_t)p * NIN_D * NHID_D, NIN_D, NHID_D);  // 20..23
    for (int p = 0; p < 4; ++p) addw(eg_n_w2 + (size_t)p * NHID_D * H, NHID_D, H);          // 24..27
    addw(aux_w1, 2 * H, H);                        // 28
    k_prep<<<dim3(29, 16), 256, 0, stream>>>(pa, Wt);
    auto WH = [&](int i) { return (const unsigned short*)(Wt + woffs[i]); };
    auto WL = [&](int i) { return (const unsigned short*)(Wt + woffs[i] + wsz[i]); };

    // ---- build 4 CSRs (dest-sorted) ----
    k_filli<<<(4 * N + 255) / 256, 256, 0, stream>>>(cnt4, 0, 4 * N);
    k_hist<<<gEA, 256, 0, stream>>>(ei_intra1 + EIA_D, EIA_D, cnt4);
    k_hist<<<gEA, 256, 0, stream>>>(ei_intra2 + EIA_D, EIA_D, cnt4 + N);
    k_hist<<<gEA, 256, 0, stream>>>(ei_12 + EIR_D, EIR_D, cnt4 + 2 * N);
    k_hist<<<gEA, 256, 0, stream>>>(ei_21 + EIR_D, EIR_D, cnt4 + 3 * N);
    k_scan4<<<4, 256, 0, stream>>>(cnt4, N, rp4);
    k_filli<<<(4 * N + 255) / 256, 256, 0, stream>>>(cnt4, 0, 4 * N);
    const int* rpI1 = rp4;
    const int* rpI2 = rp4 + (N + 1);
    const int* rp12 = rp4 + 2 * (N + 1);
    const int* rp21 = rp4 + 3 * (N + 1);
    k_scatter<<<gEA, 256, 0, stream>>>(ei_intra1, ei_intra1 + EIA_D, EIA_D, rpI1, cnt4, cjI1);
    k_scatter<<<gEA, 256, 0, stream>>>(ei_intra2, ei_intra2 + EIA_D, EIA_D, rpI2, cnt4 + N, cjI2);
    k_scatter<<<gEA, 256, 0, stream>>>(ei_12, ei_12 + EIR_D, EIR_D, rp12, cnt4 + 2 * N, cj12);
    k_scatter<<<gEA, 256, 0, stream>>>(ei_21, ei_21 + EIR_D, EIR_D, rp21, cnt4 + 3 * N, cj21);

    const int MB = (N + 127) / 128;   // 157
    dim3 grid_h(MB, 2);               // N=128 outputs
    dim3 grid_A(MB, 9);               // N=514 outputs (Npad 576)
    dim3 grid_nh(MB, 4);              // N=256 outputs

    // ---- GAT stage ----
    auto gat = [&](const float* xsrc, const float* xdst, bool same, int wsi, int wdi,
                   const int* rp, const int* cjj, int hasSelf,
                   const float* as_, const float* ad_, const float* b_,
                   int K, float* outb) {
        int Kpad = (K + 31) & ~31;
        k_mm<0, false, false, false><<<grid_h, 256, 0, stream>>>(
            xsrc, nullptr, nullptr, nullptr, WH(wsi), WL(wsi), nullptr, nullptr,
            hs, N, H, K, Kpad, H);
        const float* hdp = hs;
        if (!same) {
            k_mm<0, false, false, false><<<grid_h, 256, 0, stream>>>(
                xdst, nullptr, nullptr, nullptr, WH(wdi), WL(wdi), nullptr, nullptr,
                hd, N, H, K, Kpad, H);
            hdp = hd;
        }
        k_rowdot2<<<gNW, 256, 0, stream>>>(hs, hdp, as_, ad_, esb, edb, N);
        k_gat_fused<<<gNW, 256, 0, stream>>>(rp, cjj, hasSelf, esb, edb, hs, b_, outb, N);
    };

    gat(x1_in, x1_in, true, 0, 0, rpI1, cjI1, 1, g0_as, g0_ad, g0_b, FIN_D, x1a);
    gat(x2_in, x2_in, true, 1, 1, rpI2, cjI2, 1, g0_as + H, g0_ad + H, g0_b + H, FIN_D, x2a);
    const float* cx1 = x1a;
    const float* cx2 = x2a;
    gat(cx1, cx1, true, 2, 2, rpI1, cjI1, 1, g1_as, g1_ad, g1_b, H, x1b);
    gat(cx2, cx2, true, 3, 3, rpI2, cjI2, 1, g1_as + H, g1_ad + H, g1_b + H, H, x2b);
    cx1 = x1b; cx2 = x2b;
    {
        float* outs1[2] = {x1a, x1b};
        float* outs2[2] = {x2a, x2b};
        for (int l = 0; l < 2; ++l) {
            int p0 = l * 2 + 0, p1 = l * 2 + 1;
            float* o2 = outs2[l == 0 ? 0 : 1];
            float* o1 = outs1[l == 0 ? 0 : 1];
            gat(cx1, cx2, false, 4 + p0, 8 + p0, rp12, cj12, 0,
                it_as + p0 * H, it_ad + p0 * H, it_b + p0 * H, H, o2);
            gat(cx2, cx1, false, 4 + p1, 8 + p1, rp21, cj21, 0,
                it_as + p1 * H, it_ad + p1 * H, it_b + p1 * H, H, o1);
            cx1 = o1; cx2 = o2;
        }
    }

    // ---- EGNN stage ----
    k_padzero<<<(N * 6 + 255) / 256, 256, 0, stream>>>((unsigned short*)B16, N);
    auto egnn = [&](const float* feats, const float* coors, const int* rp, const int* cjj, int pidx,
                    float* featsOut, float* coorsOut) {
        const float* ew1 = eg_e_w1 + (size_t)pidx * EIN_D * EHID_D;
        k_mm<0, false, false, false><<<grid_A, 256, 0, stream>>>(
            feats, nullptr, nullptr, nullptr, WH(12 + 2 * pidx), WL(12 + 2 * pidx),
            nullptr, nullptr, Abuf, N, EHID_D, H, H, EHID_D);
        k_mm<0, false, true, false><<<grid_A, 256, 0, stream>>>(
            feats, nullptr, nullptr, nullptr, WH(13 + 2 * pidx), WL(13 + 2 * pidx),
            nullptr, nullptr, (float*)B16, N, EHID_D, H, H, BPAD);
        k_egnn_csr<<<gNW, 256, 0, stream>>>(rp, cjj, Abuf, B16, coors,
                                            ew1 + (size_t)256 * EHID_D, eg_e_b1 + pidx * EHID_D,
                                            eg_e_w2 + (size_t)pidx * EHID_D * M_D, eg_e_b2 + pidx * M_D,
                                            eg_c_w1 + pidx * M_D * 64, eg_c_b1 + pidx * 64,
                                            eg_c_w2 + pidx * 64, eg_c_b2 + pidx,
                                            coorsOut, macc, N);
        k_concat<<<(N * NIN_D + 255) / 256, 256, 0, stream>>>(catb, feats, macc, N);
        k_mm<2, false, false, false><<<grid_nh, 256, 0, stream>>>(
            catb, nullptr, nullptr, nullptr, WH(20 + pidx), WL(20 + pidx),
            eg_n_b1 + pidx * NHID_D, nullptr, nh, N, NHID_D, NIN_D, 160, NHID_D);
        k_mm<0, true, false, false><<<grid_h, 256, 0, stream>>>(
            nh, nullptr, nullptr, nullptr, WH(24 + pidx), WL(24 + pidx),
            eg_n_b2 + pidx * H, feats, featsOut, N, H, NHID_D, NHID_D, H);
    };
    egnn(cx1, pos1, rpI1, cjI1, 0, x1a, co1a);
    egnn(cx2, pos2, rpI2, cjI2, 1, x2a, co2a);
    cx1 = x1a; cx2 = x2a;
    egnn(cx1, co1a, rpI1, cjI1, 2, x1b, co1b);
    egnn(cx2, co2a, rpI2, cjI2, 3, x2b, co2b);
    cx1 = x1b; cx2 = x2b;

    // ---- heads ----
    k_nodescore<<<gNW, 256, 0, stream>>>(cx1, lin_w, lin_b, dout, N);
    k_nodescore<<<gNW, 256, 0, stream>>>(cx2, lin_w, lin_b, dout + N, N);
    k_mm<1, false, false, true><<<dim3((EIT_D + 127) / 128, 2), 256, 0, stream>>>(
        cx1, cx2, ei_int, ei_int + EIT_D, WH(28), WL(28),
        aux_b1, nullptr, Hb, EIT_D, H, 2 * H, 2 * H, H);
    k_dist<<<(EIT_D + 3) / 4, 256, 0, stream>>>(Hb, aux_w2, aux_b2, dout + 2 * N, EIT_D);
}

// Round 5
// 2181.280 us; speedup vs baseline: 2.6814x; 2.5313x over previous
//
#include <hip/hip_runtime.h>
#include <cstdint>
#include <cstddef>

// ---- problem constants ----
#define NN     20000
#define FIN_D  64
#define H_D    128
#define M_D    16
#define EIA_D  256000
#define EIR_D  256000
#define EIT_D  100000
#define EIN_D  257
#define EHID_D 514
#define NIN_D  144
#define NHID_D 256
#define APAD   544          // padded EHID for A rows (fp32) and B rows (bf16); 17 k-tiles of 32
#define BUPAD  272          // APAD/2 uints per bf16 B row

typedef short bfrag __attribute__((ext_vector_type(8)));   // 8 bf16 (4 VGPRs)
typedef float ffrag __attribute__((ext_vector_type(4)));   // 4 fp32 acc

__device__ __forceinline__ float siluf(float x) { return x / (1.f + __expf(-x)); }
__device__ __forceinline__ float reluf(float x) { return x > 0.f ? x : 0.f; }
__device__ __forceinline__ unsigned short f2bf(float f) {  // RNE fp32->bf16
    unsigned u = __float_as_uint(f);
    return (unsigned short)((u + 0x7FFFu + ((u >> 16) & 1u)) >> 16);
}
__device__ __forceinline__ float bf2f(unsigned short h) { return __uint_as_float(((unsigned)h) << 16); }
__device__ __forceinline__ float bf_lo(unsigned u) { return __uint_as_float(u << 16); }
__device__ __forceinline__ float bf_hi(unsigned u) { return __uint_as_float(u & 0xFFFF0000u); }

// ---------------- CSR build ----------------
__global__ void k_filli(int* p, int v, int n) {
    int i = blockIdx.x * 256 + threadIdx.x; if (i < n) p[i] = v;
}
__global__ void k_hist(const int* __restrict__ si, int nE, int* __restrict__ cnt) {
    int e = blockIdx.x * 256 + threadIdx.x; if (e < nE) atomicAdd(&cnt[si[e]], 1);
}
__global__ void k_scan4(const int* __restrict__ cnt4, int n, int* __restrict__ rp4) {
    const int* cnt = cnt4 + (size_t)blockIdx.x * n;
    int* rp = rp4 + (size_t)blockIdx.x * (n + 1);
    __shared__ int tmp[256];
    __shared__ int carry;
    if (threadIdx.x == 0) { carry = 0; rp[0] = 0; }
    __syncthreads();
    for (int base = 0; base < n; base += 256) {
        int i = base + threadIdx.x;
        int v = (i < n) ? cnt[i] : 0;
        tmp[threadIdx.x] = v;
        __syncthreads();
        for (int off = 1; off < 256; off <<= 1) {
            int t = (threadIdx.x >= off) ? tmp[threadIdx.x - off] : 0;
            __syncthreads();
            tmp[threadIdx.x] += t;
            __syncthreads();
        }
        if (i < n) rp[i + 1] = carry + tmp[threadIdx.x];
        __syncthreads();
        if (threadIdx.x == 0) carry += tmp[255];
        __syncthreads();
    }
}
// also emits dsti[p] = dest node when dsti != nullptr (needed by EGNN edge kernel)
__global__ void k_scatter(const int* __restrict__ sj, const int* __restrict__ si, int nE,
                          const int* __restrict__ rp, int* __restrict__ cursor,
                          int* __restrict__ colj, int* __restrict__ dsti) {
    int e = blockIdx.x * 256 + threadIdx.x;
    if (e >= nE) return;
    int i = si[e];
    int p = rp[i] + atomicAdd(&cursor[i], 1);
    colj[p] = sj[e];
    if (dsti) dsti[p] = i;
}

// ---------------- weight prep: transpose + hi/lo bf16 split ----------------
struct PrepDesc { const float* src; unsigned dstOff; int K, N, Kpad, Npad; };
struct PrepArgs { PrepDesc d[29]; };
__global__ void k_prep(PrepArgs pa, unsigned short* __restrict__ Wt) {
    PrepDesc de = pa.d[blockIdx.x];
    int tot = de.Npad * de.Kpad;
    unsigned short* hi = Wt + de.dstOff;
    unsigned short* lo = hi + tot;
    for (int i = blockIdx.y * 256 + threadIdx.x; i < tot; i += gridDim.y * 256) {
        int n = i / de.Kpad, k = i - n * de.Kpad;
        float v = (n < de.N && k < de.K) ? de.src[(size_t)k * de.N + n] : 0.f;
        unsigned short h = f2bf(v);
        hi[i] = h;
        lo[i] = f2bf(v - bf2f(h));
    }
}

// pack ew2 [514][16] into MFMA B-fragment order: Wf[pidx][t][lane][jj], k=t*32+(lane>>4)*8+jj,
// n=lane&15; zero beyond k>=514 (this zero is what makes A/B pad garbage harmless).
__global__ void k_prep_ew2(const float* __restrict__ eg_e_w2, unsigned short* __restrict__ Wf) {
    int pidx = blockIdx.x;
    const float* src = eg_e_w2 + (size_t)pidx * EHID_D * M_D;
    unsigned short* hi = Wf + (size_t)pidx * 8704;
    unsigned short* lo = Wf + 4 * 8704 + (size_t)pidx * 8704;
    for (int idx = threadIdx.x; idx < 8704; idx += 256) {
        int t = idx >> 9, rem = idx & 511;
        int lane = rem >> 3, j2 = rem & 7;
        int k = t * 32 + ((lane >> 4) << 3) + j2;
        int n = lane & 15;
        float v = (k < EHID_D) ? src[(size_t)k * 16 + n] : 0.f;
        unsigned short h = f2bf(v);
        hi[idx] = h;
        lo[idx] = f2bf(v - bf2f(h));
    }
}

// ---------------- MFMA GEMM: C = act(A@W + bias) (+res), fp32 via bf16 hi/lo split ----------
template<int ACT, bool RES, bool OBF, bool GATHER>
__global__ __launch_bounds__(256) void k_mm(
        const float* __restrict__ A, const float* __restrict__ A2,
        const int* __restrict__ gi0, const int* __restrict__ gi1,
        const unsigned short* __restrict__ Wh, const unsigned short* __restrict__ Wl,
        const float* __restrict__ bias, const float* __restrict__ res,
        float* __restrict__ C, int M, int Nc, int K, int Kpad, int ldc) {
    __shared__ __align__(16) unsigned short sAh[128 * 32];
    __shared__ __align__(16) unsigned short sAl[128 * 32];
    const int tid = threadIdx.x;
    const int bm = blockIdx.x * 128, bn = blockIdx.y * 64;
    const int wv = tid >> 6, lane = tid & 63;
    ffrag acc[2][4];
#pragma unroll
    for (int mt = 0; mt < 2; ++mt)
#pragma unroll
        for (int nt = 0; nt < 4; ++nt)
#pragma unroll
            for (int r = 0; r < 4; ++r) acc[mt][nt][r] = 0.f;
    const int sr = tid >> 1;
    const int sks = (tid & 1) * 16;
    const int gm_s = bm + sr;
    const int sgmt = sr >> 4, smm = sr & 15, qb = (tid & 1) * 2;
    int gidx0 = 0, gidx1 = 0;
    if (GATHER && gm_s < M) { gidx0 = gi0[gm_s]; gidx1 = gi1[gm_s]; }
    const int q = lane >> 4, mm = lane & 15;

    for (int k0 = 0; k0 < Kpad; k0 += 32) {
        float v[16];
        bool valid = (gm_s < M) && (k0 + sks < K);
        if (valid) {
            const float* src;
            int kk = k0 + sks;
            if (GATHER) src = (kk < 128) ? (A + (size_t)gidx0 * 128 + kk)
                                         : (A2 + (size_t)gidx1 * 128 + (kk - 128));
            else src = A + (size_t)gm_s * K + kk;
#pragma unroll
            for (int i = 0; i < 4; ++i) {
                float4 t4 = ((const float4*)src)[i];
                v[4 * i] = t4.x; v[4 * i + 1] = t4.y; v[4 * i + 2] = t4.z; v[4 * i + 3] = t4.w;
            }
        } else {
#pragma unroll
            for (int i = 0; i < 16; ++i) v[i] = 0.f;
        }
#pragma unroll
        for (int o = 0; o < 2; ++o) {
            unsigned hw[4], lw[4];
#pragma unroll
            for (int p = 0; p < 4; ++p) {
                float f0 = v[o * 8 + 2 * p], f1 = v[o * 8 + 2 * p + 1];
                unsigned short h0 = f2bf(f0), h1 = f2bf(f1);
                unsigned short l0 = f2bf(f0 - bf2f(h0)), l1 = f2bf(f1 - bf2f(h1));
                hw[p] = (unsigned)h0 | ((unsigned)h1 << 16);
                lw[p] = (unsigned)l0 | ((unsigned)l1 << 16);
            }
            int off16 = (sgmt * 4 + qb + o) * 16 + smm;
            ((uint4*)sAh)[off16] = make_uint4(hw[0], hw[1], hw[2], hw[3]);
            ((uint4*)sAl)[off16] = make_uint4(lw[0], lw[1], lw[2], lw[3]);
        }
        __syncthreads();
        bfrag bh[4], bl[4];
#pragma unroll
        for (int nt = 0; nt < 4; ++nt) {
            size_t woff = (size_t)(bn + nt * 16 + mm) * Kpad + k0 + q * 8;
            bh[nt] = *(const bfrag*)(Wh + woff);
            bl[nt] = *(const bfrag*)(Wl + woff);
        }
#pragma unroll
        for (int mt = 0; mt < 2; ++mt) {
            int off16 = ((wv * 2 + mt) * 4 + q) * 16 + mm;
            bfrag ah = ((const bfrag*)sAh)[off16];
            bfrag al = ((const bfrag*)sAl)[off16];
#pragma unroll
            for (int nt = 0; nt < 4; ++nt) {
                acc[mt][nt] = __builtin_amdgcn_mfma_f32_16x16x32_bf16(ah, bh[nt], acc[mt][nt], 0, 0, 0);
                acc[mt][nt] = __builtin_amdgcn_mfma_f32_16x16x32_bf16(ah, bl[nt], acc[mt][nt], 0, 0, 0);
                acc[mt][nt] = __builtin_amdgcn_mfma_f32_16x16x32_bf16(al, bh[nt], acc[mt][nt], 0, 0, 0);
            }
        }
        __syncthreads();
    }
#pragma unroll
    for (int mt = 0; mt < 2; ++mt) {
#pragma unroll
        for (int nt = 0; nt < 4; ++nt) {
            int gn = bn + nt * 16 + mm;
            if (gn >= Nc) continue;
#pragma unroll
            for (int r = 0; r < 4; ++r) {
                int gm = bm + wv * 32 + mt * 16 + q * 4 + r;
                if (gm >= M) continue;
                float vv = acc[mt][nt][r];
                if (bias) vv += bias[gn];
                if (ACT == 1) vv = reluf(vv);
                if (ACT == 2) vv = siluf(vv);
                if (RES) vv += res[(size_t)gm * Nc + gn];
                if (OBF) ((unsigned short*)C)[(size_t)gm * ldc + gn] = f2bf(vv);
                else C[(size_t)gm * ldc + gn] = vv;
            }
        }
    }
}

// ---------------- paired row dots (es/ed): wave per node ----------------
__global__ void k_rowdot2(const float* __restrict__ hs, const float* __restrict__ hd,
                          const float* __restrict__ a_s, const float* __restrict__ a_d,
                          float* __restrict__ es, float* __restrict__ ed, int n) {
    int w = blockIdx.x * 4 + (threadIdx.x >> 6);
    int lane = threadIdx.x & 63;
    if (w >= n) return;
    const float* r1 = hs + (size_t)w * H_D;
    const float* r2 = hd + (size_t)w * H_D;
    float s1 = r1[lane] * a_s[lane] + r1[lane + 64] * a_s[lane + 64];
    float s2 = r2[lane] * a_d[lane] + r2[lane + 64] * a_d[lane + 64];
#pragma unroll
    for (int off = 32; off; off >>= 1) { s1 += __shfl_xor(s1, off); s2 += __shfl_xor(s2, off); }
    if (lane == 0) { es[w] = s1; ed[w] = s2; }
}

__global__ void k_nodescore(const float* __restrict__ x, const float* __restrict__ wv,
                            const float* __restrict__ b, float* __restrict__ o, int n) {
    int w = blockIdx.x * 4 + (threadIdx.x >> 6);
    int lane = threadIdx.x & 63;
    if (w >= n) return;
    const float* r = x + (size_t)w * H_D;
    float s = r[lane] * wv[lane] + r[lane + 64] * wv[lane + 64];
#pragma unroll
    for (int off = 32; off; off >>= 1) s += __shfl_xor(s, off);
    if (lane == 0) o[w] = s + b[0];
}

// ---------------- fused GAT softmax-aggregate (CSR, wave per dest node) ----------------
__global__ __launch_bounds__(256) void k_gat_fused(
        const int* __restrict__ rp, const int* __restrict__ cj, int hasSelf,
        const float* __restrict__ es, const float* __restrict__ ed,
        const float* __restrict__ hs, const float* __restrict__ bias,
        float* __restrict__ out, int N) {
    int node = blockIdx.x * 4 + (threadIdx.x >> 6);
    int lane = threadIdx.x & 63;
    if (node >= N) return;
    int start = rp[node], end = rp[node + 1];
    float edi = ed[node];
    float m = -INFINITY;
    for (int p = start + lane; p < end; p += 64) {
        float v = es[cj[p]] + edi;
        v = v < 0.f ? 0.2f * v : v;
        m = fmaxf(m, v);
    }
#pragma unroll
    for (int off = 32; off; off >>= 1) m = fmaxf(m, __shfl_xor(m, off));
    float vself = 0.f;
    if (hasSelf) {
        vself = es[node] + edi;
        vself = vself < 0.f ? 0.2f * vself : vself;
        m = fmaxf(m, vself);
    }
    float den = 0.f, a0 = 0.f, a1 = 0.f;
    for (int p = start; p < end; ++p) {
        int j = cj[p];
        float v = es[j] + edi;
        v = v < 0.f ? 0.2f * v : v;
        float ex = __expf(v - m);
        den += ex;
        const float* hr = hs + (size_t)j * H_D;
        a0 += ex * hr[lane];
        a1 += ex * hr[lane + 64];
    }
    if (hasSelf) {
        float ex = __expf(vself - m);
        den += ex;
        const float* hr = hs + (size_t)node * H_D;
        a0 += ex * hr[lane];
        a1 += ex * hr[lane + 64];
    }
    float inv = 1.f / (den + 1e-16f);
    out[(size_t)node * H_D + lane]      = reluf(a0 * inv + bias[lane]);
    out[(size_t)node * H_D + 64 + lane] = reluf(a1 * inv + bias[lane + 64]);
}

// ---------------- EGNN edge kernel: fused gather + silu + MFMA edge-MLP-2 + coord gate ------
// Wave owns 16 edges. A-frag: lane(q=lane>>4, mm=lane&15) computes g for edge mm at
// k = t*32 + q*8 + [0..8). D rows = edges, cols = 16 channels. Pad K 514->544 is
// neutralized by zero ew2 frags (garbage A/B pad values are finite, x0 = 0).
__global__ __launch_bounds__(256) void k_edge_mfma(
        const int* __restrict__ dsti, const int* __restrict__ cj, int nE,
        const float* __restrict__ A,            // [N][APAD] fp32
        const unsigned* __restrict__ Bp,        // [N][BUPAD] bf16 pairs
        const float* __restrict__ coors,
        const float* __restrict__ w_rd, const float* __restrict__ eb1,   // [514]
        const unsigned short* __restrict__ Wfh, const unsigned short* __restrict__ Wfl,
        const float* __restrict__ eb2,
        const float* __restrict__ cw1, const float* __restrict__ cb1,
        const float* __restrict__ cw2, const float* __restrict__ cb2,
        float* __restrict__ me_buf, float* __restrict__ cw_buf) {
    __shared__ __align__(16) float s_w[APAD], s_b[APAD];
    __shared__ float s_cw1[1024];
    __shared__ float s_cb1[64], s_cw2[64], s_eb2[16];
    __shared__ float sM[4][16][17];
    for (int i = threadIdx.x; i < APAD; i += 256) {
        s_w[i] = (i < EHID_D) ? w_rd[i] : 0.f;
        s_b[i] = (i < EHID_D) ? eb1[i] : 0.f;
    }
    for (int i = threadIdx.x; i < 1024; i += 256) s_cw1[i] = cw1[i];
    if (threadIdx.x < 64) { s_cb1[threadIdx.x] = cb1[threadIdx.x]; s_cw2[threadIdx.x] = cw2[threadIdx.x]; }
    if (threadIdx.x < 16) s_eb2[threadIdx.x] = eb2[threadIdx.x];
    __syncthreads();
    const float cb2v = cb2[0];
    const int wv = threadIdx.x >> 6, lane = threadIdx.x & 63;
    const int q = lane >> 4, mm = lane & 15;
    const int ebase = blockIdx.x * 64 + wv * 16;
    const int e = ebase + mm;
    const bool ev = e < nE;
    int ii = ev ? dsti[e] : 0;
    int jj = ev ? cj[e] : 0;
    float dx = coors[(size_t)jj * 3]     - coors[(size_t)ii * 3];
    float dy = coors[(size_t)jj * 3 + 1] - coors[(size_t)ii * 3 + 1];
    float dz = coors[(size_t)jj * 3 + 2] - coors[(size_t)ii * 3 + 2];
    float rd = dx * dx + dy * dy + dz * dz;
    const float* Ar = A + (size_t)ii * APAD;
    const unsigned* Br = Bp + (size_t)jj * BUPAD;
    ffrag acc = {0.f, 0.f, 0.f, 0.f};
#pragma unroll 4
    for (int t = 0; t < 17; ++t) {
        int ks = t * 32 + q * 8;
        float4 a0 = *(const float4*)(Ar + ks);
        float4 a1 = *(const float4*)(Ar + ks + 4);
        uint4 bu = *(const uint4*)(Br + (ks >> 1));
        float4 w0 = *(const float4*)(s_w + ks);
        float4 w1 = *(const float4*)(s_w + ks + 4);
        float4 b0 = *(const float4*)(s_b + ks);
        float4 b1 = *(const float4*)(s_b + ks + 4);
        float g[8];
        g[0] = siluf(a0.x + bf_lo(bu.x) + rd * w0.x + b0.x);
        g[1] = siluf(a0.y + bf_hi(bu.x) + rd * w0.y + b0.y);
        g[2] = siluf(a0.z + bf_lo(bu.y) + rd * w0.z + b0.z);
        g[3] = siluf(a0.w + bf_hi(bu.y) + rd * w0.w + b0.w);
        g[4] = siluf(a1.x + bf_lo(bu.z) + rd * w1.x + b1.x);
        g[5] = siluf(a1.y + bf_hi(bu.z) + rd * w1.y + b1.y);
        g[6] = siluf(a1.z + bf_lo(bu.w) + rd * w1.z + b1.z);
        g[7] = siluf(a1.w + bf_hi(bu.w) + rd * w1.w + b1.w);
        bfrag ah, al;
#pragma unroll
        for (int z = 0; z < 8; ++z) {
            unsigned short h = f2bf(g[z]);
            ah[z] = (short)h;
            al[z] = (short)f2bf(g[z] - bf2f(h));
        }
        bfrag bh = *(const bfrag*)(Wfh + (size_t)(t * 64 + lane) * 8);
        bfrag bl = *(const bfrag*)(Wfl + (size_t)(t * 64 + lane) * 8);
        acc = __builtin_amdgcn_mfma_f32_16x16x32_bf16(ah, bh, acc, 0, 0, 0);
        acc = __builtin_amdgcn_mfma_f32_16x16x32_bf16(al, bh, acc, 0, 0, 0);
        acc = __builtin_amdgcn_mfma_f32_16x16x32_bf16(ah, bl, acc, 0, 0, 0);
    }
    // epilogue: D row=q*4+r (edge), col=mm (channel); m_e = silu(D + eb2)
#pragma unroll
    for (int r = 0; r < 4; ++r) {
        int erow = q * 4 + r;
        float me = siluf(acc[r] + s_eb2[mm]);
        sM[wv][erow][mm] = me;
        int e2 = ebase + erow;
        if (e2 < nE) me_buf[(size_t)e2 * 16 + mm] = me;
    }
    // coordinate gate MLP (16 -> 64 -> 1), lanes over hidden units
    for (int el = 0; el < 16; ++el) {
        int e3 = ebase + el;
        if (e3 >= nE) break;
        float a = s_cb1[lane];
#pragma unroll
        for (int c = 0; c < 16; ++c) a += sM[wv][el][c] * s_cw1[c * 64 + lane];
        float p = siluf(a) * s_cw2[lane];
#pragma unroll
        for (int off = 32; off; off >>= 1) p += __shfl_xor(p, off);
        if (lane == 0) cw_buf[e3] = p + cb2v;
    }
}

// ---------------- EGNN CSR segment-sum: macc + coorsOut ----------------
__global__ __launch_bounds__(256) void k_egnn_seg(
        const int* __restrict__ rp, const int* __restrict__ cj,
        const float* __restrict__ me_buf, const float* __restrict__ cw_buf,
        const float* __restrict__ coors,
        float* __restrict__ coorsOut, float* __restrict__ macc, int N) {
    int node = blockIdx.x * 4 + (threadIdx.x >> 6);
    int lane = threadIdx.x & 63;
    if (node >= N) return;
    int s = rp[node], en = rp[node + 1];
    int x = lane >> 4, c = lane & 15;
    float ci0 = coors[(size_t)node * 3], ci1 = coors[(size_t)node * 3 + 1], ci2 = coors[(size_t)node * 3 + 2];
    float msum = 0.f, c0 = 0.f, c1 = 0.f, c2 = 0.f;
    for (int p = s + x; p < en; p += 4) {
        msum += me_buf[(size_t)p * 16 + c];
        float cw = cw_buf[p];
        int j = cj[p];
        c0 += cw * (coors[(size_t)j * 3]     - ci0);
        c1 += cw * (coors[(size_t)j * 3 + 1] - ci1);
        c2 += cw * (coors[(size_t)j * 3 + 2] - ci2);
    }
    msum += __shfl_xor(msum, 16); msum += __shfl_xor(msum, 32);
    c0 += __shfl_xor(c0, 16); c0 += __shfl_xor(c0, 32);
    c1 += __shfl_xor(c1, 16); c1 += __shfl_xor(c1, 32);
    c2 += __shfl_xor(c2, 16); c2 += __shfl_xor(c2, 32);
    if (lane < 16) macc[(size_t)node * M_D + lane] = msum;
    if (lane == 0) {
        coorsOut[(size_t)node * 3]     = ci0 + c0;
        coorsOut[(size_t)node * 3 + 1] = ci1 + c1;
        coorsOut[(size_t)node * 3 + 2] = ci2 + c2;
    }
}

__global__ void k_concat(float* __restrict__ cat, const float* __restrict__ f,
                         const float* __restrict__ m, int n) {
    int i = blockIdx.x * 256 + threadIdx.x;
    if (i >= n * NIN_D) return;
    int r = i / NIN_D, c = i - r * NIN_D;
    cat[i] = (c < H_D) ? f[r * H_D + c] : m[r * M_D + (c - H_D)];
}

// ---------------- dist head final matvec ----------------
__global__ void k_dist(const float* __restrict__ Hb, const float* __restrict__ w2,
                       const float* __restrict__ b2, float* __restrict__ dist, int nE) {
    int e = blockIdx.x * 4 + (threadIdx.x >> 6);
    int lane = threadIdx.x & 63;
    if (e >= nE) return;
    const float* r = Hb + (size_t)e * H_D;
    float s = r[lane] * w2[lane] + r[lane + 64] * w2[lane + 64];
#pragma unroll
    for (int off = 32; off; off >>= 1) s += __shfl_xor(s, off);
    if (lane == 0) dist[e] = reluf(s + b2[0]);
}

// ---------------- host ----------------
extern "C" void kernel_launch(void* const* d_in, const int* in_sizes, int n_in,
                              void* d_out, int out_size, void* d_ws, size_t ws_size,
                              hipStream_t stream) {
    const float* x1_in = (const float*)d_in[0];
    const float* x2_in = (const float*)d_in[1];
    const float* pos1  = (const float*)d_in[2];
    const float* pos2  = (const float*)d_in[3];
    const int* ei_intra1 = (const int*)d_in[4];
    const int* ei_intra2 = (const int*)d_in[5];
    const int* ei_12 = (const int*)d_in[6];
    const int* ei_21 = (const int*)d_in[7];
    const int* ei_int = (const int*)d_in[8];
    const float* g0_w  = (const float*)d_in[9];
    const float* g0_as = (const float*)d_in[10];
    const float* g0_ad = (const float*)d_in[11];
    const float* g0_b  = (const float*)d_in[12];
    const float* g1_w  = (const float*)d_in[13];
    const float* g1_as = (const float*)d_in[14];
    const float* g1_ad = (const float*)d_in[15];
    const float* g1_b  = (const float*)d_in[16];
    const float* it_ws = (const float*)d_in[17];
    const float* it_wd = (const float*)d_in[18];
    const float* it_as = (const float*)d_in[19];
    const float* it_ad = (const float*)d_in[20];
    const float* it_b  = (const float*)d_in[21];
    const float* eg_e_w1 = (const float*)d_in[22];
    const float* eg_e_b1 = (const float*)d_in[23];
    const float* eg_e_w2 = (const float*)d_in[24];
    const float* eg_e_b2 = (const float*)d_in[25];
    const float* eg_c_w1 = (const float*)d_in[26];
    const float* eg_c_b1 = (const float*)d_in[27];
    const float* eg_c_w2 = (const float*)d_in[28];
    const float* eg_c_b2 = (const float*)d_in[29];
    const float* eg_n_w1 = (const float*)d_in[30];
    const float* eg_n_b1 = (const float*)d_in[31];
    const float* eg_n_w2 = (const float*)d_in[32];
    const float* eg_n_b2 = (const float*)d_in[33];
    const float* lin_w = (const float*)d_in[34];
    const float* lin_b = (const float*)d_in[35];
    const float* aux_w1 = (const float*)d_in[36];
    const float* aux_b1 = (const float*)d_in[37];
    const float* aux_w2 = (const float*)d_in[38];
    const float* aux_b2 = (const float*)d_in[39];
    float* dout = (float*)d_out;

    // ---- workspace layout ----
    float* wsf = (float*)d_ws;
    size_t off = 0;
    auto alloc = [&](size_t nfl) { float* p = wsf + off; off += (nfl + 255) & ~(size_t)255; return p; };
    float* x1a = alloc((size_t)NN * H_D);
    float* x2a = alloc((size_t)NN * H_D);
    float* x1b = alloc((size_t)NN * H_D);
    float* x2b = alloc((size_t)NN * H_D);
    float* gatbuf = alloc((size_t)2 * NN * H_D);   // hs|hd; aliased as concat buf in EGNN
    float* hs = gatbuf;
    float* hd = gatbuf + (size_t)NN * H_D;
    float* esb = alloc(NN);
    float* edb = alloc(NN);
    float* co1a = alloc(NN * 3);
    float* co1b = alloc(NN * 3);
    float* co2a = alloc(NN * 3);
    float* co2b = alloc(NN * 3);
    float* macc = alloc((size_t)NN * M_D);
    float* Abuf = alloc((size_t)NN * APAD);                   // [N][544] fp32
    unsigned* B16 = (unsigned*)alloc((size_t)NN * BUPAD);     // [N][272] uints (bf16 pairs)
    int* cnt4 = (int*)alloc(4 * NN);
    int* rp4 = (int*)alloc(4 * (NN + 1));
    int* cjI1 = (int*)alloc(EIA_D);
    int* cjI2 = (int*)alloc(EIA_D);
    int* cj12 = (int*)alloc(EIR_D);
    int* cj21 = (int*)alloc(EIR_D);
    int* dstI1 = (int*)alloc(EIA_D);
    int* dstI2 = (int*)alloc(EIA_D);
    unsigned short* Wt = (unsigned short*)alloc(1100000);     // 2.2M ushorts
    unsigned short* Wf = (unsigned short*)alloc(35000);       // ew2 frag tables (hi|lo x 4)
    float* me_buf = alloc((size_t)EIA_D * M_D);               // per-edge m_e
    float* cw_buf = alloc(EIA_D);                             // per-edge coord gate
    float* catb = gatbuf;          // N*144 < 2*N*128 (GAT hs/hd dead during EGNN)
    float* nh   = Abuf;            // N*256 fits; Abuf dead once k_edge_mfma finishes
    float* Hb   = Abuf;            // 100000*128 floats span Abuf+B16, both dead at aux time

    const int N = NN, H = H_D;
    int gNW = (N + 3) / 4;
    int gEA = (EIA_D + 255) / 256;

    // ---- weight prep descriptors ----
    PrepArgs pa;
    unsigned woffs[29], wsz[29];
    unsigned wo = 0;
    int wi = 0;
    auto addw = [&](const float* src, int K, int Ncols) {
        int Kpad = (K + 31) & ~31;
        int Npad = (Ncols + 63) & ~63;
        pa.d[wi] = {src, wo, K, Ncols, Kpad, Npad};
        woffs[wi] = wo; wsz[wi] = (unsigned)(Npad * Kpad);
        wo += 2u * Npad * Kpad;
        ++wi;
    };
    addw(g0_w, FIN_D, H);                          // 0
    addw(g0_w + FIN_D * H, FIN_D, H);              // 1
    addw(g1_w, H, H);                              // 2
    addw(g1_w + H * H, H, H);                      // 3
    for (int p = 0; p < 4; ++p) addw(it_ws + (size_t)p * H * H, H, H);   // 4..7
    for (int p = 0; p < 4; ++p) addw(it_wd + (size_t)p * H * H, H, H);   // 8..11
    for (int p = 0; p < 4; ++p) {                  // 12..19
        const float* ew1 = eg_e_w1 + (size_t)p * EIN_D * EHID_D;
        addw(ew1, H, EHID_D);
        addw(ew1 + (size_t)H * EHID_D, H, EHID_D);
    }
    for (int p = 0; p < 4; ++p) addw(eg_n_w1 + (size_t)p * NIN_D * NHID_D, NIN_D, NHID_D);  // 20..23
    for (int p = 0; p < 4; ++p) addw(eg_n_w2 + (size_t)p * NHID_D * H, NHID_D, H);          // 24..27
    addw(aux_w1, 2 * H, H);                        // 28
    k_prep<<<dim3(29, 16), 256, 0, stream>>>(pa, Wt);
    k_prep_ew2<<<4, 256, 0, stream>>>(eg_e_w2, Wf);
    auto WH = [&](int i) { return (const unsigned short*)(Wt + woffs[i]); };
    auto WL = [&](int i) { return (const unsigned short*)(Wt + woffs[i] + wsz[i]); };

    // ---- build 4 CSRs (dest-sorted) ----
    k_filli<<<(4 * N + 255) / 256, 256, 0, stream>>>(cnt4, 0, 4 * N);
    k_hist<<<gEA, 256, 0, stream>>>(ei_intra1 + EIA_D, EIA_D, cnt4);
    k_hist<<<gEA, 256, 0, stream>>>(ei_intra2 + EIA_D, EIA_D, cnt4 + N);
    k_hist<<<gEA, 256, 0, stream>>>(ei_12 + EIR_D, EIR_D, cnt4 + 2 * N);
    k_hist<<<gEA, 256, 0, stream>>>(ei_21 + EIR_D, EIR_D, cnt4 + 3 * N);
    k_scan4<<<4, 256, 0, stream>>>(cnt4, N, rp4);
    k_filli<<<(4 * N + 255) / 256, 256, 0, stream>>>(cnt4, 0, 4 * N);
    const int* rpI1 = rp4;
    const int* rpI2 = rp4 + (N + 1);
    const int* rp12 = rp4 + 2 * (N + 1);
    const int* rp21 = rp4 + 3 * (N + 1);
    k_scatter<<<gEA, 256, 0, stream>>>(ei_intra1, ei_intra1 + EIA_D, EIA_D, rpI1, cnt4, cjI1, dstI1);
    k_scatter<<<gEA, 256, 0, stream>>>(ei_intra2, ei_intra2 + EIA_D, EIA_D, rpI2, cnt4 + N, cjI2, dstI2);
    k_scatter<<<gEA, 256, 0, stream>>>(ei_12, ei_12 + EIR_D, EIR_D, rp12, cnt4 + 2 * N, cj12, nullptr);
    k_scatter<<<gEA, 256, 0, stream>>>(ei_21, ei_21 + EIR_D, EIR_D, rp21, cnt4 + 3 * N, cj21, nullptr);

    const int MB = (N + 127) / 128;   // 157
    dim3 grid_h(MB, 2);               // N=128 outputs
    dim3 grid_A(MB, 9);               // N=514 outputs (Npad 576)
    dim3 grid_nh(MB, 4);              // N=256 outputs

    // ---- GAT stage ----
    auto gat = [&](const float* xsrc, const float* xdst, bool same, int wsi, int wdi,
                   const int* rp, const int* cjj, int hasSelf,
                   const float* as_, const float* ad_, const float* b_,
                   int K, float* outb) {
        int Kpad = (K + 31) & ~31;
        k_mm<0, false, false, false><<<grid_h, 256, 0, stream>>>(
            xsrc, nullptr, nullptr, nullptr, WH(wsi), WL(wsi), nullptr, nullptr,
            hs, N, H, K, Kpad, H);
        const float* hdp = hs;
        if (!same) {
            k_mm<0, false, false, false><<<grid_h, 256, 0, stream>>>(
                xdst, nullptr, nullptr, nullptr, WH(wdi), WL(wdi), nullptr, nullptr,
                hd, N, H, K, Kpad, H);
            hdp = hd;
        }
        k_rowdot2<<<gNW, 256, 0, stream>>>(hs, hdp, as_, ad_, esb, edb, N);
        k_gat_fused<<<gNW, 256, 0, stream>>>(rp, cjj, hasSelf, esb, edb, hs, b_, outb, N);
    };

    gat(x1_in, x1_in, true, 0, 0, rpI1, cjI1, 1, g0_as, g0_ad, g0_b, FIN_D, x1a);
    gat(x2_in, x2_in, true, 1, 1, rpI2, cjI2, 1, g0_as + H, g0_ad + H, g0_b + H, FIN_D, x2a);
    const float* cx1 = x1a;
    const float* cx2 = x2a;
    gat(cx1, cx1, true, 2, 2, rpI1, cjI1, 1, g1_as, g1_ad, g1_b, H, x1b);
    gat(cx2, cx2, true, 3, 3, rpI2, cjI2, 1, g1_as + H, g1_ad + H, g1_b + H, H, x2b);
    cx1 = x1b; cx2 = x2b;
    {
        float* outs1[2] = {x1a, x1b};
        float* outs2[2] = {x2a, x2b};
        for (int l = 0; l < 2; ++l) {
            int p0 = l * 2 + 0, p1 = l * 2 + 1;
            float* o2 = outs2[l == 0 ? 0 : 1];
            float* o1 = outs1[l == 0 ? 0 : 1];
            gat(cx1, cx2, false, 4 + p0, 8 + p0, rp12, cj12, 0,
                it_as + p0 * H, it_ad + p0 * H, it_b + p0 * H, H, o2);
            gat(cx2, cx1, false, 4 + p1, 8 + p1, rp21, cj21, 0,
                it_as + p1 * H, it_ad + p1 * H, it_b + p1 * H, H, o1);
            cx1 = o1; cx2 = o2;
        }
    }

    // ---- EGNN stage ----
    auto egnn = [&](const float* feats, const float* coors, const int* rp, const int* cjj,
                    const int* dsti, int pidx, float* featsOut, float* coorsOut) {
        const float* ew1 = eg_e_w1 + (size_t)pidx * EIN_D * EHID_D;
        k_mm<0, false, false, false><<<grid_A, 256, 0, stream>>>(
            feats, nullptr, nullptr, nullptr, WH(12 + 2 * pidx), WL(12 + 2 * pidx),
            nullptr, nullptr, Abuf, N, EHID_D, H, H, APAD);
        k_mm<0, false, true, false><<<grid_A, 256, 0, stream>>>(
            feats, nullptr, nullptr, nullptr, WH(13 + 2 * pidx), WL(13 + 2 * pidx),
            nullptr, nullptr, (float*)B16, N, EHID_D, H, H, APAD);
        k_edge_mfma<<<(EIA_D + 63) / 64, 256, 0, stream>>>(
            dsti, cjj, EIA_D, Abuf, B16, coors,
            ew1 + (size_t)256 * EHID_D, eg_e_b1 + pidx * EHID_D,
            Wf + (size_t)pidx * 8704, Wf + 4 * 8704 + (size_t)pidx * 8704,
            eg_e_b2 + pidx * M_D,
            eg_c_w1 + pidx * M_D * 64, eg_c_b1 + pidx * 64,
            eg_c_w2 + pidx * 64, eg_c_b2 + pidx,
            me_buf, cw_buf);
        k_egnn_seg<<<gNW, 256, 0, stream>>>(rp, cjj, me_buf, cw_buf, coors, coorsOut, macc, N);
        k_concat<<<(N * NIN_D + 255) / 256, 256, 0, stream>>>(catb, feats, macc, N);
        k_mm<2, false, false, false><<<grid_nh, 256, 0, stream>>>(
            catb, nullptr, nullptr, nullptr, WH(20 + pidx), WL(20 + pidx),
            eg_n_b1 + pidx * NHID_D, nullptr, nh, N, NHID_D, NIN_D, 160, NHID_D);
        k_mm<0, true, false, false><<<grid_h, 256, 0, stream>>>(
            nh, nullptr, nullptr, nullptr, WH(24 + pidx), WL(24 + pidx),
            eg_n_b2 + pidx * H, feats, featsOut, N, H, NHID_D, NHID_D, H);
    };
    egnn(cx1, pos1, rpI1, cjI1, dstI1, 0, x1a, co1a);
    egnn(cx2, pos2, rpI2, cjI2, dstI2, 1, x2a, co2a);
    cx1 = x1a; cx2 = x2a;
    egnn(cx1, co1a, rpI1, cjI1, dstI1, 2, x1b, co1b);
    egnn(cx2, co2a, rpI2, cjI2, dstI2, 3, x2b, co2b);
    cx1 = x1b; cx2 = x2b;

    // ---- heads ----
    k_nodescore<<<gNW, 256, 0, stream>>>(cx1, lin_w, lin_b, dout, N);
    k_nodescore<<<gNW, 256, 0, stream>>>(cx2, lin_w, lin_b, dout + N, N);
    k_mm<1, false, false, true><<<dim3((EIT_D + 127) / 128, 2), 256, 0, stream>>>(
        cx1, cx2, ei_int, ei_int + EIT_D, WH(28), WL(28),
        aux_b1, nullptr, Hb, EIT_D, H, 2 * H, 2 * H, H);
    k_dist<<<(EIT_D + 3) / 4, 256, 0, stream>>>(Hb, aux_w2, aux_b2, dout + 2 * N, EIT_D);
}

// Round 6
// 2135.673 us; speedup vs baseline: 2.7387x; 1.0214x over previous
//
#include <hip/hip_runtime.h>
#include <cstdint>
#include <cstddef>

// ---- problem constants ----
#define NN     20000
#define FIN_D  64
#define H_D    128
#define M_D    16
#define EIA_D  256000
#define EIR_D  256000
#define EIT_D  100000
#define EIN_D  257
#define EHID_D 514
#define NIN_D  144
#define NHID_D 256
#define APAD   544          // padded EHID; 17 k-tiles of 32
#define BUPAD  272          // APAD/2 uints per bf16 row (A and B tables)

typedef short bfrag __attribute__((ext_vector_type(8)));   // 8 bf16 (4 VGPRs)
typedef float ffrag __attribute__((ext_vector_type(4)));   // 4 fp32 acc

__device__ __forceinline__ float siluf(float x) { return x / (1.f + __expf(-x)); }
__device__ __forceinline__ float reluf(float x) { return x > 0.f ? x : 0.f; }
__device__ __forceinline__ unsigned short f2bf(float f) {  // RNE fp32->bf16
    unsigned u = __float_as_uint(f);
    return (unsigned short)((u + 0x7FFFu + ((u >> 16) & 1u)) >> 16);
}
__device__ __forceinline__ float bf2f(unsigned short h) { return __uint_as_float(((unsigned)h) << 16); }
__device__ __forceinline__ float bf_lo(unsigned u) { return __uint_as_float(u << 16); }
__device__ __forceinline__ float bf_hi(unsigned u) { return __uint_as_float(u & 0xFFFF0000u); }

// ---------------- CSR build ----------------
__global__ void k_filli(int* p, int v, int n) {
    int i = blockIdx.x * 256 + threadIdx.x; if (i < n) p[i] = v;
}
__global__ void k_hist(const int* __restrict__ si, int nE, int* __restrict__ cnt) {
    int e = blockIdx.x * 256 + threadIdx.x; if (e < nE) atomicAdd(&cnt[si[e]], 1);
}
__global__ void k_scan4(const int* __restrict__ cnt4, int n, int* __restrict__ rp4) {
    const int* cnt = cnt4 + (size_t)blockIdx.x * n;
    int* rp = rp4 + (size_t)blockIdx.x * (n + 1);
    __shared__ int tmp[256];
    __shared__ int carry;
    if (threadIdx.x == 0) { carry = 0; rp[0] = 0; }
    __syncthreads();
    for (int base = 0; base < n; base += 256) {
        int i = base + threadIdx.x;
        int v = (i < n) ? cnt[i] : 0;
        tmp[threadIdx.x] = v;
        __syncthreads();
        for (int off = 1; off < 256; off <<= 1) {
            int t = (threadIdx.x >= off) ? tmp[threadIdx.x - off] : 0;
            __syncthreads();
            tmp[threadIdx.x] += t;
            __syncthreads();
        }
        if (i < n) rp[i + 1] = carry + tmp[threadIdx.x];
        __syncthreads();
        if (threadIdx.x == 0) carry += tmp[255];
        __syncthreads();
    }
}
__global__ void k_scatter(const int* __restrict__ sj, const int* __restrict__ si, int nE,
                          const int* __restrict__ rp, int* __restrict__ cursor,
                          int* __restrict__ colj, int* __restrict__ dsti) {
    int e = blockIdx.x * 256 + threadIdx.x;
    if (e >= nE) return;
    int i = si[e];
    int p = rp[i] + atomicAdd(&cursor[i], 1);
    colj[p] = sj[e];
    if (dsti) dsti[p] = i;
}

// ---------------- weight prep: transpose + hi/lo bf16 split ----------------
struct PrepDesc { const float* src; unsigned dstOff; int K, N, Kpad, Npad; };
struct PrepArgs { PrepDesc d[29]; };
__global__ void k_prep(PrepArgs pa, unsigned short* __restrict__ Wt) {
    PrepDesc de = pa.d[blockIdx.x];
    int tot = de.Npad * de.Kpad;
    unsigned short* hi = Wt + de.dstOff;
    unsigned short* lo = hi + tot;
    for (int i = blockIdx.y * 256 + threadIdx.x; i < tot; i += gridDim.y * 256) {
        int n = i / de.Kpad, k = i - n * de.Kpad;
        float v = (n < de.N && k < de.K) ? de.src[(size_t)k * de.N + n] : 0.f;
        unsigned short h = f2bf(v);
        hi[i] = h;
        lo[i] = f2bf(v - bf2f(h));
    }
}

// pack ew2 [514][16] into MFMA B-fragment order; zero beyond k>=514 (neutralizes pad garbage)
__global__ void k_prep_ew2(const float* __restrict__ eg_e_w2, unsigned short* __restrict__ Wf) {
    int pidx = blockIdx.x;
    const float* src = eg_e_w2 + (size_t)pidx * EHID_D * M_D;
    unsigned short* hi = Wf + (size_t)pidx * 8704;
    unsigned short* lo = Wf + 4 * 8704 + (size_t)pidx * 8704;
    for (int idx = threadIdx.x; idx < 8704; idx += 256) {
        int t = idx >> 9, rem = idx & 511;
        int lane = rem >> 3, j2 = rem & 7;
        int k = t * 32 + ((lane >> 4) << 3) + j2;
        int n = lane & 15;
        float v = (k < EHID_D) ? src[(size_t)k * 16 + n] : 0.f;
        unsigned short h = f2bf(v);
        hi[idx] = h;
        lo[idx] = f2bf(v - bf2f(h));
    }
}

// ---------------- MFMA GEMM: C = act(A@W + bias) (+res), fp32 via bf16 hi/lo split ----------
// DUAL additionally writes a bf16 copy of the (post-act) output to C2 [M][ldc] shorts.
template<int ACT, bool RES, bool OBF, bool GATHER, bool DUAL>
__global__ __launch_bounds__(256) void k_mm(
        const float* __restrict__ A, const float* __restrict__ A2,
        const int* __restrict__ gi0, const int* __restrict__ gi1,
        const unsigned short* __restrict__ Wh, const unsigned short* __restrict__ Wl,
        const float* __restrict__ bias, const float* __restrict__ res,
        float* __restrict__ C, unsigned short* __restrict__ C2,
        int M, int Nc, int K, int Kpad, int ldc) {
    __shared__ __align__(16) unsigned short sAh[128 * 32];
    __shared__ __align__(16) unsigned short sAl[128 * 32];
    const int tid = threadIdx.x;
    const int bm = blockIdx.x * 128, bn = blockIdx.y * 64;
    const int wv = tid >> 6, lane = tid & 63;
    ffrag acc[2][4];
#pragma unroll
    for (int mt = 0; mt < 2; ++mt)
#pragma unroll
        for (int nt = 0; nt < 4; ++nt)
#pragma unroll
            for (int r = 0; r < 4; ++r) acc[mt][nt][r] = 0.f;
    const int sr = tid >> 1;
    const int sks = (tid & 1) * 16;
    const int gm_s = bm + sr;
    const int sgmt = sr >> 4, smm = sr & 15, qb = (tid & 1) * 2;
    int gidx0 = 0, gidx1 = 0;
    if (GATHER && gm_s < M) { gidx0 = gi0[gm_s]; gidx1 = gi1[gm_s]; }
    const int q = lane >> 4, mm = lane & 15;

    for (int k0 = 0; k0 < Kpad; k0 += 32) {
        float v[16];
        bool valid = (gm_s < M) && (k0 + sks < K);
        if (valid) {
            const float* src;
            int kk = k0 + sks;
            if (GATHER) src = (kk < 128) ? (A + (size_t)gidx0 * 128 + kk)
                                         : (A2 + (size_t)gidx1 * 128 + (kk - 128));
            else src = A + (size_t)gm_s * K + kk;
#pragma unroll
            for (int i = 0; i < 4; ++i) {
                float4 t4 = ((const float4*)src)[i];
                v[4 * i] = t4.x; v[4 * i + 1] = t4.y; v[4 * i + 2] = t4.z; v[4 * i + 3] = t4.w;
            }
        } else {
#pragma unroll
            for (int i = 0; i < 16; ++i) v[i] = 0.f;
        }
#pragma unroll
        for (int o = 0; o < 2; ++o) {
            unsigned hw[4], lw[4];
#pragma unroll
            for (int p = 0; p < 4; ++p) {
                float f0 = v[o * 8 + 2 * p], f1 = v[o * 8 + 2 * p + 1];
                unsigned short h0 = f2bf(f0), h1 = f2bf(f1);
                unsigned short l0 = f2bf(f0 - bf2f(h0)), l1 = f2bf(f1 - bf2f(h1));
                hw[p] = (unsigned)h0 | ((unsigned)h1 << 16);
                lw[p] = (unsigned)l0 | ((unsigned)l1 << 16);
            }
            int off16 = (sgmt * 4 + qb + o) * 16 + smm;
            ((uint4*)sAh)[off16] = make_uint4(hw[0], hw[1], hw[2], hw[3]);
            ((uint4*)sAl)[off16] = make_uint4(lw[0], lw[1], lw[2], lw[3]);
        }
        __syncthreads();
        bfrag bh[4], bl[4];
#pragma unroll
        for (int nt = 0; nt < 4; ++nt) {
            size_t woff = (size_t)(bn + nt * 16 + mm) * Kpad + k0 + q * 8;
            bh[nt] = *(const bfrag*)(Wh + woff);
            bl[nt] = *(const bfrag*)(Wl + woff);
        }
#pragma unroll
        for (int mt = 0; mt < 2; ++mt) {
            int off16 = ((wv * 2 + mt) * 4 + q) * 16 + mm;
            bfrag ah = ((const bfrag*)sAh)[off16];
            bfrag al = ((const bfrag*)sAl)[off16];
#pragma unroll
            for (int nt = 0; nt < 4; ++nt) {
                acc[mt][nt] = __builtin_amdgcn_mfma_f32_16x16x32_bf16(ah, bh[nt], acc[mt][nt], 0, 0, 0);
                acc[mt][nt] = __builtin_amdgcn_mfma_f32_16x16x32_bf16(ah, bl[nt], acc[mt][nt], 0, 0, 0);
                acc[mt][nt] = __builtin_amdgcn_mfma_f32_16x16x32_bf16(al, bh[nt], acc[mt][nt], 0, 0, 0);
            }
        }
        __syncthreads();
    }
#pragma unroll
    for (int mt = 0; mt < 2; ++mt) {
#pragma unroll
        for (int nt = 0; nt < 4; ++nt) {
            int gn = bn + nt * 16 + mm;
            if (gn >= Nc) continue;
#pragma unroll
            for (int r = 0; r < 4; ++r) {
                int gm = bm + wv * 32 + mt * 16 + q * 4 + r;
                if (gm >= M) continue;
                float vv = acc[mt][nt][r];
                if (bias) vv += bias[gn];
                if (ACT == 1) vv = reluf(vv);
                if (ACT == 2) vv = siluf(vv);
                if (RES) vv += res[(size_t)gm * Nc + gn];
                if (OBF) ((unsigned short*)C)[(size_t)gm * ldc + gn] = f2bf(vv);
                else C[(size_t)gm * ldc + gn] = vv;
                if (DUAL) C2[(size_t)gm * ldc + gn] = f2bf(vv);
            }
        }
    }
}

// ---------------- paired row dots (es/ed): wave per node ----------------
__global__ void k_rowdot2(const float* __restrict__ hs, const float* __restrict__ hd,
                          const float* __restrict__ a_s, const float* __restrict__ a_d,
                          float* __restrict__ es, float* __restrict__ ed, int n) {
    int w = blockIdx.x * 4 + (threadIdx.x >> 6);
    int lane = threadIdx.x & 63;
    if (w >= n) return;
    const float* r1 = hs + (size_t)w * H_D;
    const float* r2 = hd + (size_t)w * H_D;
    float s1 = r1[lane] * a_s[lane] + r1[lane + 64] * a_s[lane + 64];
    float s2 = r2[lane] * a_d[lane] + r2[lane + 64] * a_d[lane + 64];
#pragma unroll
    for (int off = 32; off; off >>= 1) { s1 += __shfl_xor(s1, off); s2 += __shfl_xor(s2, off); }
    if (lane == 0) { es[w] = s1; ed[w] = s2; }
}

__global__ void k_nodescore(const float* __restrict__ x, const float* __restrict__ wv,
                            const float* __restrict__ b, float* __restrict__ o, int n) {
    int w = blockIdx.x * 4 + (threadIdx.x >> 6);
    int lane = threadIdx.x & 63;
    if (w >= n) return;
    const float* r = x + (size_t)w * H_D;
    float s = r[lane] * wv[lane] + r[lane + 64] * wv[lane + 64];
#pragma unroll
    for (int off = 32; off; off >>= 1) s += __shfl_xor(s, off);
    if (lane == 0) o[w] = s + b[0];
}

// ---------------- fused GAT softmax-aggregate (single pass; softmax shift-invariance) -------
// h16: bf16 h rows, lane holds channels (2*lane, 2*lane+1) per uint.
__global__ __launch_bounds__(256) void k_gat_fused(
        const int* __restrict__ rp, const int* __restrict__ cj, int hasSelf,
        const float* __restrict__ es, const float* __restrict__ ed,
        const unsigned* __restrict__ h16, const float* __restrict__ bias,
        float* __restrict__ out, int N) {
    int node = blockIdx.x * 4 + (threadIdx.x >> 6);
    int lane = threadIdx.x & 63;
    if (node >= N) return;
    int start = rp[node], end = rp[node + 1];
    float edi = ed[node];
    float den = 0.f, a0 = 0.f, a1 = 0.f;
    for (int p = start; p < end; ++p) {
        int j = cj[p];
        float v = es[j] + edi;
        v = v < 0.f ? 0.2f * v : v;
        float ex = __expf(v);           // no max-sub: e is O(few), fp32 exp safe to ~88
        den += ex;
        unsigned u = h16[(size_t)j * 64 + lane];
        a0 += ex * bf_lo(u);
        a1 += ex * bf_hi(u);
    }
    if (hasSelf) {
        float v = es[node] + edi;
        v = v < 0.f ? 0.2f * v : v;
        float ex = __expf(v);
        den += ex;
        unsigned u = h16[(size_t)node * 64 + lane];
        a0 += ex * bf_lo(u);
        a1 += ex * bf_hi(u);
    }
    float inv = 1.f / (den + 1e-16f);
    float2 o;
    o.x = reluf(a0 * inv + bias[2 * lane]);
    o.y = reluf(a1 * inv + bias[2 * lane + 1]);
    ((float2*)(out + (size_t)node * H_D))[lane] = o;
}

// ---------------- EGNN edge kernel: gather(bf16 A,B) + silu + MFMA + coord gate -------------
__global__ __launch_bounds__(256) void k_edge_mfma(
        const int* __restrict__ dsti, const int* __restrict__ cj, int nE,
        const unsigned* __restrict__ A16,       // [N][BUPAD] bf16 pairs
        const unsigned* __restrict__ Bp,        // [N][BUPAD] bf16 pairs
        const float* __restrict__ coors,
        const float* __restrict__ w_rd, const float* __restrict__ eb1,   // [514]
        const unsigned short* __restrict__ Wfh, const unsigned short* __restrict__ Wfl,
        const float* __restrict__ eb2,
        const float* __restrict__ cw1, const float* __restrict__ cb1,
        const float* __restrict__ cw2, const float* __restrict__ cb2,
        unsigned short* __restrict__ me16, float* __restrict__ cvec) {
    __shared__ __align__(16) float s_w[APAD], s_b[APAD];
    __shared__ float s_cw1[1024];
    __shared__ float s_cb1[64], s_cw2[64], s_eb2[16];
    __shared__ float sM[4][16][17];
    for (int i = threadIdx.x; i < APAD; i += 256) {
        s_w[i] = (i < EHID_D) ? w_rd[i] : 0.f;
        s_b[i] = (i < EHID_D) ? eb1[i] : 0.f;
    }
    for (int i = threadIdx.x; i < 1024; i += 256) s_cw1[i] = cw1[i];
    if (threadIdx.x < 64) { s_cb1[threadIdx.x] = cb1[threadIdx.x]; s_cw2[threadIdx.x] = cw2[threadIdx.x]; }
    if (threadIdx.x < 16) s_eb2[threadIdx.x] = eb2[threadIdx.x];
    __syncthreads();
    const float cb2v = cb2[0];
    const int wv = threadIdx.x >> 6, lane = threadIdx.x & 63;
    const int q = lane >> 4, mm = lane & 15;
    const int ebase = blockIdx.x * 64 + wv * 16;
    const int e = ebase + mm;
    const bool ev = e < nE;
    int ii = ev ? dsti[e] : 0;
    int jj = ev ? cj[e] : 0;
    float dx = coors[(size_t)jj * 3]     - coors[(size_t)ii * 3];
    float dy = coors[(size_t)jj * 3 + 1] - coors[(size_t)ii * 3 + 1];
    float dz = coors[(size_t)jj * 3 + 2] - coors[(size_t)ii * 3 + 2];
    float rd = dx * dx + dy * dy + dz * dz;
    const unsigned* Ar = A16 + (size_t)ii * BUPAD;
    const unsigned* Br = Bp + (size_t)jj * BUPAD;
    ffrag acc = {0.f, 0.f, 0.f, 0.f};
#pragma unroll 4
    for (int t = 0; t < 17; ++t) {
        int ks = t * 32 + q * 8;
        int ku = ks >> 1;
        uint4 au = *(const uint4*)(Ar + ku);
        uint4 bu = *(const uint4*)(Br + ku);
        float4 w0 = *(const float4*)(s_w + ks);
        float4 w1 = *(const float4*)(s_w + ks + 4);
        float4 b0 = *(const float4*)(s_b + ks);
        float4 b1 = *(const float4*)(s_b + ks + 4);
        float g[8];
        g[0] = siluf(bf_lo(au.x) + bf_lo(bu.x) + rd * w0.x + b0.x);
        g[1] = siluf(bf_hi(au.x) + bf_hi(bu.x) + rd * w0.y + b0.y);
        g[2] = siluf(bf_lo(au.y) + bf_lo(bu.y) + rd * w0.z + b0.z);
        g[3] = siluf(bf_hi(au.y) + bf_hi(bu.y) + rd * w0.w + b0.w);
        g[4] = siluf(bf_lo(au.z) + bf_lo(bu.z) + rd * w1.x + b1.x);
        g[5] = siluf(bf_hi(au.z) + bf_hi(bu.z) + rd * w1.y + b1.y);
        g[6] = siluf(bf_lo(au.w) + bf_lo(bu.w) + rd * w1.z + b1.z);
        g[7] = siluf(bf_hi(au.w) + bf_hi(bu.w) + rd * w1.w + b1.w);
        bfrag ah, al;
#pragma unroll
        for (int z = 0; z < 8; ++z) {
            unsigned short h = f2bf(g[z]);
            ah[z] = (short)h;
            al[z] = (short)f2bf(g[z] - bf2f(h));
        }
        bfrag bh = *(const bfrag*)(Wfh + (size_t)(t * 64 + lane) * 8);
        bfrag bl = *(const bfrag*)(Wfl + (size_t)(t * 64 + lane) * 8);
        acc = __builtin_amdgcn_mfma_f32_16x16x32_bf16(ah, bh, acc, 0, 0, 0);
        acc = __builtin_amdgcn_mfma_f32_16x16x32_bf16(al, bh, acc, 0, 0, 0);
        acc = __builtin_amdgcn_mfma_f32_16x16x32_bf16(ah, bl, acc, 0, 0, 0);
    }
    // D row=q*4+r (edge), col=mm (channel); m_e = silu(D + eb2)
#pragma unroll
    for (int r = 0; r < 4; ++r) {
        int erow = q * 4 + r;
        float me = siluf(acc[r] + s_eb2[mm]);
        sM[wv][erow][mm] = me;
        int e2 = ebase + erow;
        if (e2 < nE) me16[(size_t)e2 * 16 + mm] = f2bf(me);
    }
    // coordinate gate MLP (16 -> 64 -> 1); lane==el owns edge el's (dx,dy,dz)
    for (int el = 0; el < 16; ++el) {
        int e3 = ebase + el;
        if (e3 >= nE) break;
        float a = s_cb1[lane];
#pragma unroll
        for (int c = 0; c < 16; ++c) a += sM[wv][el][c] * s_cw1[c * 64 + lane];
        float p = siluf(a) * s_cw2[lane];
#pragma unroll
        for (int off = 32; off; off >>= 1) p += __shfl_xor(p, off);
        float cwv = p + cb2v;
        if (lane == el) {
            cvec[(size_t)e3 * 3]     = cwv * dx;
            cvec[(size_t)e3 * 3 + 1] = cwv * dy;
            cvec[(size_t)e3 * 3 + 2] = cwv * dz;
        }
    }
}

// ---------------- EGNN CSR segment-sum: linear reads only ----------------
__global__ __launch_bounds__(256) void k_egnn_seg(
        const int* __restrict__ rp,
        const unsigned short* __restrict__ me16, const float* __restrict__ cvec,
        const float* __restrict__ coors,
        float* __restrict__ coorsOut, float* __restrict__ macc, int N) {
    int node = blockIdx.x * 4 + (threadIdx.x >> 6);
    int lane = threadIdx.x & 63;
    if (node >= N) return;
    int s = rp[node], en = rp[node + 1];
    int x = lane >> 4, c = lane & 15;
    float msum = 0.f, csum = 0.f;
    for (int p = s + x; p < en; p += 4) {
        msum += bf2f(me16[(size_t)p * 16 + c]);
        if (c < 3) csum += cvec[(size_t)p * 3 + c];
    }
    msum += __shfl_xor(msum, 16); msum += __shfl_xor(msum, 32);
    csum += __shfl_xor(csum, 16); csum += __shfl_xor(csum, 32);
    if (lane < 16) macc[(size_t)node * M_D + lane] = msum;
    if (lane < 3) coorsOut[(size_t)node * 3 + lane] = coors[(size_t)node * 3 + lane] + csum;
}

__global__ void k_concat(float* __restrict__ cat, const float* __restrict__ f,
                         const float* __restrict__ m, int n) {
    int i = blockIdx.x * 256 + threadIdx.x;
    if (i >= n * NIN_D) return;
    int r = i / NIN_D, c = i - r * NIN_D;
    cat[i] = (c < H_D) ? f[r * H_D + c] : m[r * M_D + (c - H_D)];
}

// ---------------- dist head final matvec ----------------
__global__ void k_dist(const float* __restrict__ Hb, const float* __restrict__ w2,
                       const float* __restrict__ b2, float* __restrict__ dist, int nE) {
    int e = blockIdx.x * 4 + (threadIdx.x >> 6);
    int lane = threadIdx.x & 63;
    if (e >= nE) return;
    const float* r = Hb + (size_t)e * H_D;
    float s = r[lane] * w2[lane] + r[lane + 64] * w2[lane + 64];
#pragma unroll
    for (int off = 32; off; off >>= 1) s += __shfl_xor(s, off);
    if (lane == 0) dist[e] = reluf(s + b2[0]);
}

// ---------------- host ----------------
extern "C" void kernel_launch(void* const* d_in, const int* in_sizes, int n_in,
                              void* d_out, int out_size, void* d_ws, size_t ws_size,
                              hipStream_t stream) {
    const float* x1_in = (const float*)d_in[0];
    const float* x2_in = (const float*)d_in[1];
    const float* pos1  = (const float*)d_in[2];
    const float* pos2  = (const float*)d_in[3];
    const int* ei_intra1 = (const int*)d_in[4];
    const int* ei_intra2 = (const int*)d_in[5];
    const int* ei_12 = (const int*)d_in[6];
    const int* ei_21 = (const int*)d_in[7];
    const int* ei_int = (const int*)d_in[8];
    const float* g0_w  = (const float*)d_in[9];
    const float* g0_as = (const float*)d_in[10];
    const float* g0_ad = (const float*)d_in[11];
    const float* g0_b  = (const float*)d_in[12];
    const float* g1_w  = (const float*)d_in[13];
    const float* g1_as = (const float*)d_in[14];
    const float* g1_ad = (const float*)d_in[15];
    const float* g1_b  = (const float*)d_in[16];
    const float* it_ws = (const float*)d_in[17];
    const float* it_wd = (const float*)d_in[18];
    const float* it_as = (const float*)d_in[19];
    const float* it_ad = (const float*)d_in[20];
    const float* it_b  = (const float*)d_in[21];
    const float* eg_e_w1 = (const float*)d_in[22];
    const float* eg_e_b1 = (const float*)d_in[23];
    const float* eg_e_w2 = (const float*)d_in[24];
    const float* eg_e_b2 = (const float*)d_in[25];
    const float* eg_c_w1 = (const float*)d_in[26];
    const float* eg_c_b1 = (const float*)d_in[27];
    const float* eg_c_w2 = (const float*)d_in[28];
    const float* eg_c_b2 = (const float*)d_in[29];
    const float* eg_n_w1 = (const float*)d_in[30];
    const float* eg_n_b1 = (const float*)d_in[31];
    const float* eg_n_w2 = (const float*)d_in[32];
    const float* eg_n_b2 = (const float*)d_in[33];
    const float* lin_w = (const float*)d_in[34];
    const float* lin_b = (const float*)d_in[35];
    const float* aux_w1 = (const float*)d_in[36];
    const float* aux_b1 = (const float*)d_in[37];
    const float* aux_w2 = (const float*)d_in[38];
    const float* aux_b2 = (const float*)d_in[39];
    float* dout = (float*)d_out;

    // ---- workspace layout (~227 MB of 256 MiB) ----
    float* wsf = (float*)d_ws;
    size_t off = 0;
    auto alloc = [&](size_t nfl) { float* p = wsf + off; off += (nfl + 255) & ~(size_t)255; return p; };
    float* x1a = alloc((size_t)NN * H_D);
    float* x2a = alloc((size_t)NN * H_D);
    float* x1b = alloc((size_t)NN * H_D);
    float* x2b = alloc((size_t)NN * H_D);
    float* gatbuf = alloc((size_t)2 * NN * H_D);   // hs|hd; aliased as concat buf in EGNN
    float* hs = gatbuf;
    float* hd = gatbuf + (size_t)NN * H_D;
    float* esb = alloc(NN);
    float* edb = alloc(NN);
    float* co1a = alloc(NN * 3);
    float* co1b = alloc(NN * 3);
    float* co2a = alloc(NN * 3);
    float* co2b = alloc(NN * 3);
    float* macc = alloc((size_t)NN * M_D);
    unsigned* A16 = (unsigned*)alloc((size_t)NN * BUPAD);     // [N][272] uints (bf16 pairs)
    unsigned* B16 = (unsigned*)alloc((size_t)NN * BUPAD);
    unsigned* h16 = (unsigned*)alloc((size_t)NN * 64);        // bf16 h table for GAT aggregate
    int* cnt4 = (int*)alloc(4 * NN);
    int* rp4 = (int*)alloc(4 * (NN + 1));
    int* cjI1 = (int*)alloc(EIA_D);
    int* cjI2 = (int*)alloc(EIA_D);
    int* cj12 = (int*)alloc(EIR_D);
    int* cj21 = (int*)alloc(EIR_D);
    int* dstI1 = (int*)alloc(EIA_D);
    int* dstI2 = (int*)alloc(EIA_D);
    unsigned short* Wt = (unsigned short*)alloc(1100000);     // 2.2M ushorts
    unsigned short* Wf = (unsigned short*)alloc(35000);       // ew2 frag tables (hi|lo x 4)
    unsigned short* me16 = (unsigned short*)alloc((size_t)EIA_D * 8);   // bf16 m_e [E][16]
    float* cvec = alloc((size_t)EIA_D * 3);                   // per-edge cw*(rel)
    float* nh   = alloc((size_t)NN * NHID_D);                 // fresh (no aliasing risk)
    float* Hb   = alloc((size_t)EIT_D * H_D);                 // fresh, 51.2 MB
    float* catb = gatbuf;          // N*144 < 2*N*128 (GAT hs/hd dead during EGNN)

    const int N = NN, H = H_D;
    int gNW = (N + 3) / 4;
    int gEA = (EIA_D + 255) / 256;

    // ---- weight prep descriptors ----
    PrepArgs pa;
    unsigned woffs[29], wsz[29];
    unsigned wo = 0;
    int wi = 0;
    auto addw = [&](const float* src, int K, int Ncols) {
        int Kpad = (K + 31) & ~31;
        int Npad = (Ncols + 63) & ~63;
        pa.d[wi] = {src, wo, K, Ncols, Kpad, Npad};
        woffs[wi] = wo; wsz[wi] = (unsigned)(Npad * Kpad);
        wo += 2u * Npad * Kpad;
        ++wi;
    };
    addw(g0_w, FIN_D, H);                          // 0
    addw(g0_w + FIN_D * H, FIN_D, H);              // 1
    addw(g1_w, H, H);                              // 2
    addw(g1_w + H * H, H, H);                      // 3
    for (int p = 0; p < 4; ++p) addw(it_ws + (size_t)p * H * H, H, H);   // 4..7
    for (int p = 0; p < 4; ++p) addw(it_wd + (size_t)p * H * H, H, H);   // 8..11
    for (int p = 0; p < 4; ++p) {                  // 12..19
        const float* ew1 = eg_e_w1 + (size_t)p * EIN_D * EHID_D;
        addw(ew1, H, EHID_D);
        addw(ew1 + (size_t)H * EHID_D, H, EHID_D);
    }
    for (int p = 0; p < 4; ++p) addw(eg_n_w1 + (size_t)p * NIN_D * NHID_D, NIN_D, NHID_D);  // 20..23
    for (int p = 0; p < 4; ++p) addw(eg_n_w2 + (size_t)p * NHID_D * H, NHID_D, H);          // 24..27
    addw(aux_w1, 2 * H, H);                        // 28
    k_prep<<<dim3(29, 16), 256, 0, stream>>>(pa, Wt);
    k_prep_ew2<<<4, 256, 0, stream>>>(eg_e_w2, Wf);
    auto WH = [&](int i) { return (const unsigned short*)(Wt + woffs[i]); };
    auto WL = [&](int i) { return (const unsigned short*)(Wt + woffs[i] + wsz[i]); };

    // ---- build 4 CSRs (dest-sorted) ----
    k_filli<<<(4 * N + 255) / 256, 256, 0, stream>>>(cnt4, 0, 4 * N);
    k_hist<<<gEA, 256, 0, stream>>>(ei_intra1 + EIA_D, EIA_D, cnt4);
    k_hist<<<gEA, 256, 0, stream>>>(ei_intra2 + EIA_D, EIA_D, cnt4 + N);
    k_hist<<<gEA, 256, 0, stream>>>(ei_12 + EIR_D, EIR_D, cnt4 + 2 * N);
    k_hist<<<gEA, 256, 0, stream>>>(ei_21 + EIR_D, EIR_D, cnt4 + 3 * N);
    k_scan4<<<4, 256, 0, stream>>>(cnt4, N, rp4);
    k_filli<<<(4 * N + 255) / 256, 256, 0, stream>>>(cnt4, 0, 4 * N);
    const int* rpI1 = rp4;
    const int* rpI2 = rp4 + (N + 1);
    const int* rp12 = rp4 + 2 * (N + 1);
    const int* rp21 = rp4 + 3 * (N + 1);
    k_scatter<<<gEA, 256, 0, stream>>>(ei_intra1, ei_intra1 + EIA_D, EIA_D, rpI1, cnt4, cjI1, dstI1);
    k_scatter<<<gEA, 256, 0, stream>>>(ei_intra2, ei_intra2 + EIA_D, EIA_D, rpI2, cnt4 + N, cjI2, dstI2);
    k_scatter<<<gEA, 256, 0, stream>>>(ei_12, ei_12 + EIR_D, EIR_D, rp12, cnt4 + 2 * N, cj12, nullptr);
    k_scatter<<<gEA, 256, 0, stream>>>(ei_21, ei_21 + EIR_D, EIR_D, rp21, cnt4 + 3 * N, cj21, nullptr);

    const int MB = (N + 127) / 128;   // 157
    dim3 grid_h(MB, 2);               // N=128 outputs
    dim3 grid_A(MB, 9);               // N=514 outputs (Npad 576)
    dim3 grid_nh(MB, 4);              // N=256 outputs

    // ---- GAT stage ----
    auto gat = [&](const float* xsrc, const float* xdst, bool same, int wsi, int wdi,
                   const int* rp, const int* cjj, int hasSelf,
                   const float* as_, const float* ad_, const float* b_,
                   int K, float* outb) {
        int Kpad = (K + 31) & ~31;
        k_mm<0, false, false, false, true><<<grid_h, 256, 0, stream>>>(
            xsrc, nullptr, nullptr, nullptr, WH(wsi), WL(wsi), nullptr, nullptr,
            hs, (unsigned short*)h16, N, H, K, Kpad, H);
        const float* hdp = hs;
        if (!same) {
            k_mm<0, false, false, false, false><<<grid_h, 256, 0, stream>>>(
                xdst, nullptr, nullptr, nullptr, WH(wdi), WL(wdi), nullptr, nullptr,
                hd, nullptr, N, H, K, Kpad, H);
            hdp = hd;
        }
        k_rowdot2<<<gNW, 256, 0, stream>>>(hs, hdp, as_, ad_, esb, edb, N);
        k_gat_fused<<<gNW, 256, 0, stream>>>(rp, cjj, hasSelf, esb, edb, h16, b_, outb, N);
    };

    gat(x1_in, x1_in, true, 0, 0, rpI1, cjI1, 1, g0_as, g0_ad, g0_b, FIN_D, x1a);
    gat(x2_in, x2_in, true, 1, 1, rpI2, cjI2, 1, g0_as + H, g0_ad + H, g0_b + H, FIN_D, x2a);
    const float* cx1 = x1a;
    const float* cx2 = x2a;
    gat(cx1, cx1, true, 2, 2, rpI1, cjI1, 1, g1_as, g1_ad, g1_b, H, x1b);
    gat(cx2, cx2, true, 3, 3, rpI2, cjI2, 1, g1_as + H, g1_ad + H, g1_b + H, H, x2b);
    cx1 = x1b; cx2 = x2b;
    {
        float* outs1[2] = {x1a, x1b};
        float* outs2[2] = {x2a, x2b};
        for (int l = 0; l < 2; ++l) {
            int p0 = l * 2 + 0, p1 = l * 2 + 1;
            float* o2 = outs2[l == 0 ? 0 : 1];
            float* o1 = outs1[l == 0 ? 0 : 1];
            gat(cx1, cx2, false, 4 + p0, 8 + p0, rp12, cj12, 0,
                it_as + p0 * H, it_ad + p0 * H, it_b + p0 * H, H, o2);
            gat(cx2, cx1, false, 4 + p1, 8 + p1, rp21, cj21, 0,
                it_as + p1 * H, it_ad + p1 * H, it_b + p1 * H, H, o1);
            cx1 = o1; cx2 = o2;
        }
    }

    // ---- EGNN stage ----
    auto egnn = [&](const float* feats, const float* coors, const int* rp, const int* cjj,
                    const int* dsti, int pidx, float* featsOut, float* coorsOut) {
        k_mm<0, false, true, false, false><<<grid_A, 256, 0, stream>>>(
            feats, nullptr, nullptr, nullptr, WH(12 + 2 * pidx), WL(12 + 2 * pidx),
            nullptr, nullptr, (float*)A16, nullptr, N, EHID_D, H, H, APAD);
        k_mm<0, false, true, false, false><<<grid_A, 256, 0, stream>>>(
            feats, nullptr, nullptr, nullptr, WH(13 + 2 * pidx), WL(13 + 2 * pidx),
            nullptr, nullptr, (float*)B16, nullptr, N, EHID_D, H, H, APAD);
        const float* ew1 = eg_e_w1 + (size_t)pidx * EIN_D * EHID_D;
        k_edge_mfma<<<(EIA_D + 63) / 64, 256, 0, stream>>>(
            dsti, cjj, EIA_D, A16, B16, coors,
            ew1 + (size_t)256 * EHID_D, eg_e_b1 + pidx * EHID_D,
            Wf + (size_t)pidx * 8704, Wf + 4 * 8704 + (size_t)pidx * 8704,
            eg_e_b2 + pidx * M_D,
            eg_c_w1 + pidx * M_D * 64, eg_c_b1 + pidx * 64,
            eg_c_w2 + pidx * 64, eg_c_b2 + pidx,
            me16, cvec);
        k_egnn_seg<<<gNW, 256, 0, stream>>>(rp, me16, cvec, coors, coorsOut, macc, N);
        k_concat<<<(N * NIN_D + 255) / 256, 256, 0, stream>>>(catb, feats, macc, N);
        k_mm<2, false, false, false, false><<<grid_nh, 256, 0, stream>>>(
            catb, nullptr, nullptr, nullptr, WH(20 + pidx), WL(20 + pidx),
            eg_n_b1 + pidx * NHID_D, nullptr, nh, nullptr, N, NHID_D, NIN_D, 160, NHID_D);
        k_mm<0, true, false, false, false><<<grid_h, 256, 0, stream>>>(
            nh, nullptr, nullptr, nullptr, WH(24 + pidx), WL(24 + pidx),
            eg_n_b2 + pidx * H, feats, featsOut, nullptr, N, H, NHID_D, NHID_D, H);
    };
    egnn(cx1, pos1, rpI1, cjI1, dstI1, 0, x1a, co1a);
    egnn(cx2, pos2, rpI2, cjI2, dstI2, 1, x2a, co2a);
    cx1 = x1a; cx2 = x2a;
    egnn(cx1, co1a, rpI1, cjI1, dstI1, 2, x1b, co1b);
    egnn(cx2, co2a, rpI2, cjI2, dstI2, 3, x2b, co2b);
    cx1 = x1b; cx2 = x2b;

    // ---- heads ----
    k_nodescore<<<gNW, 256, 0, stream>>>(cx1, lin_w, lin_b, dout, N);
    k_nodescore<<<gNW, 256, 0, stream>>>(cx2, lin_w, lin_b, dout + N, N);
    k_mm<1, false, false, true, false><<<dim3((EIT_D + 127) / 128, 2), 256, 0, stream>>>(
        cx1, cx2, ei_int, ei_int + EIT_D, WH(28), WL(28),
        aux_b1, nullptr, Hb, nullptr, EIT_D, H, 2 * H, 2 * H, H);
    k_dist<<<(EIT_D + 3) / 4, 256, 0, stream>>>(Hb, aux_w2, aux_b2, dout + 2 * N, EIT_D);
}

// Round 7
// 2032.186 us; speedup vs baseline: 2.8782x; 1.0509x over previous
//
#include <hip/hip_runtime.h>
#include <hip/hip_bf16.h>
#include <cstdint>
#include <cstddef>

// ---- problem constants ----
#define NN     20000
#define FIN_D  64
#define H_D    128
#define M_D    16
#define EIA_D  256000
#define EIR_D  256000
#define EIT_D  100000
#define EIN_D  257
#define EHID_D 514
#define NIN_D  144
#define NHID_D 256
#define APAD   544          // padded EHID; 17 k-tiles of 32
#define BUPAD  272          // APAD/2 uints per bf16 row (A and B tables)

typedef short bfrag __attribute__((ext_vector_type(8)));   // 8 bf16 (4 VGPRs)
typedef float ffrag __attribute__((ext_vector_type(4)));   // 4 fp32 acc

__device__ __forceinline__ float siluf(float x) { return x / (1.f + __expf(-x)); }
__device__ __forceinline__ float reluf(float x) { return x > 0.f ? x : 0.f; }
__device__ __forceinline__ unsigned short f2bf(float f) {  // RNE fp32->bf16
    unsigned u = __float_as_uint(f);
    return (unsigned short)((u + 0x7FFFu + ((u >> 16) & 1u)) >> 16);
}
__device__ __forceinline__ float bf2f(unsigned short h) { return __uint_as_float(((unsigned)h) << 16); }
__device__ __forceinline__ float bf_lo(unsigned u) { return __uint_as_float(u << 16); }
__device__ __forceinline__ float bf_hi(unsigned u) { return __uint_as_float(u & 0xFFFF0000u); }
// packed RNE cvt: f0 -> low 16, f1 -> high 16 (v_cvt_pk_bf16_f32 on gfx950)
__device__ __forceinline__ unsigned pkbf(float f0, float f1) {
    __hip_bfloat162 h = __float22bfloat162_rn(make_float2(f0, f1));
    return *(unsigned*)&h;
}

// ---------------- CSR build ----------------
__global__ void k_filli(int* p, int v, int n) {
    int i = blockIdx.x * 256 + threadIdx.x; if (i < n) p[i] = v;
}
__global__ void k_iota(int* p, int n) {
    int i = blockIdx.x * 256 + threadIdx.x; if (i < n) p[i] = i;
}
__global__ void k_hist(const int* __restrict__ si, int nE, int* __restrict__ cnt) {
    int e = blockIdx.x * 256 + threadIdx.x; if (e < nE) atomicAdd(&cnt[si[e]], 1);
}
__global__ void k_scan4(const int* __restrict__ cnt4, int n, int* __restrict__ rp4) {
    const int* cnt = cnt4 + (size_t)blockIdx.x * n;
    int* rp = rp4 + (size_t)blockIdx.x * (n + 1);
    __shared__ int tmp[256];
    __shared__ int carry;
    if (threadIdx.x == 0) { carry = 0; rp[0] = 0; }
    __syncthreads();
    for (int base = 0; base < n; base += 256) {
        int i = base + threadIdx.x;
        int v = (i < n) ? cnt[i] : 0;
        tmp[threadIdx.x] = v;
        __syncthreads();
        for (int off = 1; off < 256; off <<= 1) {
            int t = (threadIdx.x >= off) ? tmp[threadIdx.x - off] : 0;
            __syncthreads();
            tmp[threadIdx.x] += t;
            __syncthreads();
        }
        if (i < n) rp[i + 1] = carry + tmp[threadIdx.x];
        __syncthreads();
        if (threadIdx.x == 0) carry += tmp[255];
        __syncthreads();
    }
}
__global__ void k_scatter(const int* __restrict__ sj, const int* __restrict__ si, int nE,
                          const int* __restrict__ rp, int* __restrict__ cursor,
                          int* __restrict__ colj, int* __restrict__ dsti) {
    int e = blockIdx.x * 256 + threadIdx.x;
    if (e >= nE) return;
    int i = si[e];
    int p = rp[i] + atomicAdd(&cursor[i], 1);
    colj[p] = sj[e];
    if (dsti) dsti[p] = i;
}

// ---------------- weight prep: transpose + hi/lo bf16 split ----------------
struct PrepDesc { const float* src; unsigned dstOff; int K, N, Kpad, Npad; };
struct PrepArgs { PrepDesc d[29]; };
__global__ void k_prep(PrepArgs pa, unsigned short* __restrict__ Wt) {
    PrepDesc de = pa.d[blockIdx.x];
    int tot = de.Npad * de.Kpad;
    unsigned short* hi = Wt + de.dstOff;
    unsigned short* lo = hi + tot;
    for (int i = blockIdx.y * 256 + threadIdx.x; i < tot; i += gridDim.y * 256) {
        int n = i / de.Kpad, k = i - n * de.Kpad;
        float v = (n < de.N && k < de.K) ? de.src[(size_t)k * de.N + n] : 0.f;
        unsigned short h = f2bf(v);
        hi[i] = h;
        lo[i] = f2bf(v - bf2f(h));
    }
}

// pack ew2 [514][16] into MFMA B-fragment order; zero beyond k>=514 (neutralizes pad garbage)
__global__ void k_prep_ew2(const float* __restrict__ eg_e_w2, unsigned short* __restrict__ Wf) {
    int pidx = blockIdx.x;
    const float* src = eg_e_w2 + (size_t)pidx * EHID_D * M_D;
    unsigned short* hi = Wf + (size_t)pidx * 8704;
    unsigned short* lo = Wf + 4 * 8704 + (size_t)pidx * 8704;
    for (int idx = threadIdx.x; idx < 8704; idx += 256) {
        int t = idx >> 9, rem = idx & 511;
        int lane = rem >> 3, j2 = rem & 7;
        int k = t * 32 + ((lane >> 4) << 3) + j2;
        int n = lane & 15;
        float v = (k < EHID_D) ? src[(size_t)k * 16 + n] : 0.f;
        unsigned short h = f2bf(v);
        hi[idx] = h;
        lo[idx] = f2bf(v - bf2f(h));
    }
}

// ---------------- MFMA GEMM: C = act(A@W + bias) (+res) --------------------------------
// AMODE=2: A split hi/lo (3 MFMA, fp32-accurate). AMODE=1: A bf16 (2 MFMA; W stays hi/lo).
// DUAL writes a bf16 copy of the (post-act) output to C2. GATHER: row gm = [A[gi0[gm]] (128) |
// A2[gi1[gm]] (stride s2)] concat split at k=128.
template<int ACT, bool RES, bool OBF, bool GATHER, bool DUAL, int AMODE>
__global__ __launch_bounds__(256) void k_mm(
        const float* __restrict__ A, const float* __restrict__ A2,
        const int* __restrict__ gi0, const int* __restrict__ gi1,
        const unsigned short* __restrict__ Wh, const unsigned short* __restrict__ Wl,
        const float* __restrict__ bias, const float* __restrict__ res,
        float* __restrict__ C, unsigned short* __restrict__ C2,
        int M, int Nc, int K, int Kpad, int ldc, int s2) {
    __shared__ __align__(16) unsigned short sAh[128 * 32];
    __shared__ __align__(16) unsigned short sAl[AMODE == 2 ? 128 * 32 : 16];
    const int tid = threadIdx.x;
    const int bm = blockIdx.x * 128, bn = blockIdx.y * 64;
    const int wv = tid >> 6, lane = tid & 63;
    ffrag acc[2][4];
#pragma unroll
    for (int mt = 0; mt < 2; ++mt)
#pragma unroll
        for (int nt = 0; nt < 4; ++nt)
#pragma unroll
            for (int r = 0; r < 4; ++r) acc[mt][nt][r] = 0.f;
    const int sr = tid >> 1;
    const int sks = (tid & 1) * 16;
    const int gm_s = bm + sr;
    const int sgmt = sr >> 4, smm = sr & 15, qb = (tid & 1) * 2;
    int gidx0 = 0, gidx1 = 0;
    if (GATHER && gm_s < M) { gidx0 = gi0[gm_s]; gidx1 = gi1[gm_s]; }
    const int q = lane >> 4, mm = lane & 15;

    for (int k0 = 0; k0 < Kpad; k0 += 32) {
        float v[16];
        bool valid = (gm_s < M) && (k0 + sks < K);
        if (valid) {
            const float* src;
            int kk = k0 + sks;
            if (GATHER) src = (kk < 128) ? (A + (size_t)gidx0 * 128 + kk)
                                         : (A2 + (size_t)gidx1 * s2 + (kk - 128));
            else src = A + (size_t)gm_s * K + kk;
#pragma unroll
            for (int i = 0; i < 4; ++i) {
                float4 t4 = ((const float4*)src)[i];
                v[4 * i] = t4.x; v[4 * i + 1] = t4.y; v[4 * i + 2] = t4.z; v[4 * i + 3] = t4.w;
            }
        } else {
#pragma unroll
            for (int i = 0; i < 16; ++i) v[i] = 0.f;
        }
#pragma unroll
        for (int o = 0; o < 2; ++o) {
            unsigned hw[4], lw[4];
#pragma unroll
            for (int p = 0; p < 4; ++p) {
                float f0 = v[o * 8 + 2 * p], f1 = v[o * 8 + 2 * p + 1];
                if (AMODE == 2) {
                    unsigned short h0 = f2bf(f0), h1 = f2bf(f1);
                    unsigned short l0 = f2bf(f0 - bf2f(h0)), l1 = f2bf(f1 - bf2f(h1));
                    hw[p] = (unsigned)h0 | ((unsigned)h1 << 16);
                    lw[p] = (unsigned)l0 | ((unsigned)l1 << 16);
                } else {
                    hw[p] = pkbf(f0, f1);
                }
            }
            int off16 = (sgmt * 4 + qb + o) * 16 + smm;
            ((uint4*)sAh)[off16] = make_uint4(hw[0], hw[1], hw[2], hw[3]);
            if (AMODE == 2) ((uint4*)sAl)[off16] = make_uint4(lw[0], lw[1], lw[2], lw[3]);
        }
        __syncthreads();
        bfrag bh[4], bl[4];
#pragma unroll
        for (int nt = 0; nt < 4; ++nt) {
            size_t woff = (size_t)(bn + nt * 16 + mm) * Kpad + k0 + q * 8;
            bh[nt] = *(const bfrag*)(Wh + woff);
            bl[nt] = *(const bfrag*)(Wl + woff);
        }
#pragma unroll
        for (int mt = 0; mt < 2; ++mt) {
            int off16 = ((wv * 2 + mt) * 4 + q) * 16 + mm;
            bfrag ah = ((const bfrag*)sAh)[off16];
#pragma unroll
            for (int nt = 0; nt < 4; ++nt) {
                acc[mt][nt] = __builtin_amdgcn_mfma_f32_16x16x32_bf16(ah, bh[nt], acc[mt][nt], 0, 0, 0);
                acc[mt][nt] = __builtin_amdgcn_mfma_f32_16x16x32_bf16(ah, bl[nt], acc[mt][nt], 0, 0, 0);
            }
            if (AMODE == 2) {
                bfrag al = ((const bfrag*)sAl)[off16];
#pragma unroll
                for (int nt = 0; nt < 4; ++nt)
                    acc[mt][nt] = __builtin_amdgcn_mfma_f32_16x16x32_bf16(al, bh[nt], acc[mt][nt], 0, 0, 0);
            }
        }
        __syncthreads();
    }
#pragma unroll
    for (int mt = 0; mt < 2; ++mt) {
#pragma unroll
        for (int nt = 0; nt < 4; ++nt) {
            int gn = bn + nt * 16 + mm;
            if (gn >= Nc) continue;
#pragma unroll
            for (int r = 0; r < 4; ++r) {
                int gm = bm + wv * 32 + mt * 16 + q * 4 + r;
                if (gm >= M) continue;
                float vv = acc[mt][nt][r];
                if (bias) vv += bias[gn];
                if (ACT == 1) vv = reluf(vv);
                if (ACT == 2) vv = siluf(vv);
                if (RES) vv += res[(size_t)gm * Nc + gn];
                if (OBF) ((unsigned short*)C)[(size_t)gm * ldc + gn] = f2bf(vv);
                else C[(size_t)gm * ldc + gn] = vv;
                if (DUAL) C2[(size_t)gm * ldc + gn] = f2bf(vv);
            }
        }
    }
}

// ---------------- paired row dots (es/ed): wave per node ----------------
__global__ void k_rowdot2(const float* __restrict__ hs, const float* __restrict__ hd,
                          const float* __restrict__ a_s, const float* __restrict__ a_d,
                          float* __restrict__ es, float* __restrict__ ed, int n) {
    int w = blockIdx.x * 4 + (threadIdx.x >> 6);
    int lane = threadIdx.x & 63;
    if (w >= n) return;
    const float* r1 = hs + (size_t)w * H_D;
    const float* r2 = hd + (size_t)w * H_D;
    float s1 = r1[lane] * a_s[lane] + r1[lane + 64] * a_s[lane + 64];
    float s2 = r2[lane] * a_d[lane] + r2[lane + 64] * a_d[lane + 64];
#pragma unroll
    for (int off = 32; off; off >>= 1) { s1 += __shfl_xor(s1, off); s2 += __shfl_xor(s2, off); }
    if (lane == 0) { es[w] = s1; ed[w] = s2; }
}

__global__ void k_nodescore(const float* __restrict__ x, const float* __restrict__ wv,
                            const float* __restrict__ b, float* __restrict__ o, int n) {
    int w = blockIdx.x * 4 + (threadIdx.x >> 6);
    int lane = threadIdx.x & 63;
    if (w >= n) return;
    const float* r = x + (size_t)w * H_D;
    float s = r[lane] * wv[lane] + r[lane + 64] * wv[lane + 64];
#pragma unroll
    for (int off = 32; off; off >>= 1) s += __shfl_xor(s, off);
    if (lane == 0) o[w] = s + b[0];
}

// ---------------- fused GAT softmax-aggregate (single pass; softmax shift-invariance) -------
__global__ __launch_bounds__(256) void k_gat_fused(
        const int* __restrict__ rp, const int* __restrict__ cj, int hasSelf,
        const float* __restrict__ es, const float* __restrict__ ed,
        const unsigned* __restrict__ h16, const float* __restrict__ bias,
        float* __restrict__ out, int N) {
    int node = blockIdx.x * 4 + (threadIdx.x >> 6);
    int lane = threadIdx.x & 63;
    if (node >= N) return;
    int start = rp[node], end = rp[node + 1];
    float edi = ed[node];
    float den = 0.f, a0 = 0.f, a1 = 0.f;
    for (int p = start; p < end; ++p) {
        int j = cj[p];
        float v = es[j] + edi;
        v = v < 0.f ? 0.2f * v : v;
        float ex = __expf(v);
        den += ex;
        unsigned u = h16[(size_t)j * 64 + lane];
        a0 += ex * bf_lo(u);
        a1 += ex * bf_hi(u);
    }
    if (hasSelf) {
        float v = es[node] + edi;
        v = v < 0.f ? 0.2f * v : v;
        float ex = __expf(v);
        den += ex;
        unsigned u = h16[(size_t)node * 64 + lane];
        a0 += ex * bf_lo(u);
        a1 += ex * bf_hi(u);
    }
    float inv = 1.f / (den + 1e-16f);
    float2 o;
    o.x = reluf(a0 * inv + bias[2 * lane]);
    o.y = reluf(a1 * inv + bias[2 * lane + 1]);
    ((float2*)(out + (size_t)node * H_D))[lane] = o;
}

// ---------------- EGNN edge kernel: gather(bf16 A,B) + silu + MFMA + coord gate -------------
// g enters MFMA as bf16 (packed cvt); W keeps hi+lo -> 2 MFMA per k-tile.
__global__ __launch_bounds__(256) void k_edge_mfma(
        const int* __restrict__ dsti, const int* __restrict__ cj, int nE,
        const unsigned* __restrict__ A16,       // [N][BUPAD] bf16 pairs
        const unsigned* __restrict__ Bp,        // [N][BUPAD] bf16 pairs
        const float* __restrict__ coors,
        const float* __restrict__ w_rd, const float* __restrict__ eb1,   // [514]
        const unsigned short* __restrict__ Wfh, const unsigned short* __restrict__ Wfl,
        const float* __restrict__ eb2,
        const float* __restrict__ cw1, const float* __restrict__ cb1,
        const float* __restrict__ cw2, const float* __restrict__ cb2,
        unsigned short* __restrict__ me16, float* __restrict__ cvec) {
    __shared__ __align__(16) float s_w[APAD], s_b[APAD];
    __shared__ float s_cw1[1024];
    __shared__ float s_cb1[64], s_cw2[64], s_eb2[16];
    __shared__ float sM[4][16][17];
    for (int i = threadIdx.x; i < APAD; i += 256) {
        s_w[i] = (i < EHID_D) ? w_rd[i] : 0.f;
        s_b[i] = (i < EHID_D) ? eb1[i] : 0.f;
    }
    for (int i = threadIdx.x; i < 1024; i += 256) s_cw1[i] = cw1[i];
    if (threadIdx.x < 64) { s_cb1[threadIdx.x] = cb1[threadIdx.x]; s_cw2[threadIdx.x] = cw2[threadIdx.x]; }
    if (threadIdx.x < 16) s_eb2[threadIdx.x] = eb2[threadIdx.x];
    __syncthreads();
    const float cb2v = cb2[0];
    const int wv = threadIdx.x >> 6, lane = threadIdx.x & 63;
    const int q = lane >> 4, mm = lane & 15;
    const int ebase = blockIdx.x * 64 + wv * 16;
    const int e = ebase + mm;
    const bool ev = e < nE;
    int ii = ev ? dsti[e] : 0;
    int jj = ev ? cj[e] : 0;
    float dx = coors[(size_t)jj * 3]     - coors[(size_t)ii * 3];
    float dy = coors[(size_t)jj * 3 + 1] - coors[(size_t)ii * 3 + 1];
    float dz = coors[(size_t)jj * 3 + 2] - coors[(size_t)ii * 3 + 2];
    float rd = dx * dx + dy * dy + dz * dz;
    const unsigned* Ar = A16 + (size_t)ii * BUPAD;
    const unsigned* Br = Bp + (size_t)jj * BUPAD;
    ffrag acc = {0.f, 0.f, 0.f, 0.f};
#pragma unroll 4
    for (int t = 0; t < 17; ++t) {
        int ks = t * 32 + q * 8;
        int ku = ks >> 1;
        uint4 au = *(const uint4*)(Ar + ku);
        uint4 bu = *(const uint4*)(Br + ku);
        float4 w0 = *(const float4*)(s_w + ks);
        float4 w1 = *(const float4*)(s_w + ks + 4);
        float4 b0 = *(const float4*)(s_b + ks);
        float4 b1 = *(const float4*)(s_b + ks + 4);
        float g[8];
        g[0] = siluf(bf_lo(au.x) + bf_lo(bu.x) + rd * w0.x + b0.x);
        g[1] = siluf(bf_hi(au.x) + bf_hi(bu.x) + rd * w0.y + b0.y);
        g[2] = siluf(bf_lo(au.y) + bf_lo(bu.y) + rd * w0.z + b0.z);
        g[3] = siluf(bf_hi(au.y) + bf_hi(bu.y) + rd * w0.w + b0.w);
        g[4] = siluf(bf_lo(au.z) + bf_lo(bu.z) + rd * w1.x + b1.x);
        g[5] = siluf(bf_hi(au.z) + bf_hi(bu.z) + rd * w1.y + b1.y);
        g[6] = siluf(bf_lo(au.w) + bf_lo(bu.w) + rd * w1.z + b1.z);
        g[7] = siluf(bf_hi(au.w) + bf_hi(bu.w) + rd * w1.w + b1.w);
        bfrag ah;
        unsigned* ahp = (unsigned*)&ah;
        ahp[0] = pkbf(g[0], g[1]);
        ahp[1] = pkbf(g[2], g[3]);
        ahp[2] = pkbf(g[4], g[5]);
        ahp[3] = pkbf(g[6], g[7]);
        bfrag bh = *(const bfrag*)(Wfh + (size_t)(t * 64 + lane) * 8);
        bfrag bl = *(const bfrag*)(Wfl + (size_t)(t * 64 + lane) * 8);
        acc = __builtin_amdgcn_mfma_f32_16x16x32_bf16(ah, bh, acc, 0, 0, 0);
        acc = __builtin_amdgcn_mfma_f32_16x16x32_bf16(ah, bl, acc, 0, 0, 0);
    }
    // D row=q*4+r (edge), col=mm (channel); m_e = silu(D + eb2)
#pragma unroll
    for (int r = 0; r < 4; ++r) {
        int erow = q * 4 + r;
        float me = siluf(acc[r] + s_eb2[mm]);
        sM[wv][erow][mm] = me;
        int e2 = ebase + erow;
        if (e2 < nE) me16[(size_t)e2 * 16 + mm] = f2bf(me);
    }
    // coordinate gate MLP (16 -> 64 -> 1); lane==el owns edge el's (dx,dy,dz)
    for (int el = 0; el < 16; ++el) {
        int e3 = ebase + el;
        if (e3 >= nE) break;
        float a = s_cb1[lane];
#pragma unroll
        for (int c = 0; c < 16; ++c) a += sM[wv][el][c] * s_cw1[c * 64 + lane];
        float p = siluf(a) * s_cw2[lane];
#pragma unroll
        for (int off = 32; off; off >>= 1) p += __shfl_xor(p, off);
        float cwv = p + cb2v;
        if (lane == el) {
            cvec[(size_t)e3 * 3]     = cwv * dx;
            cvec[(size_t)e3 * 3 + 1] = cwv * dy;
            cvec[(size_t)e3 * 3 + 2] = cwv * dz;
        }
    }
}

// ---------------- EGNN CSR segment-sum: linear reads only ----------------
__global__ __launch_bounds__(256) void k_egnn_seg(
        const int* __restrict__ rp,
        const unsigned short* __restrict__ me16, const float* __restrict__ cvec,
        const float* __restrict__ coors,
        float* __restrict__ coorsOut, float* __restrict__ macc, int N) {
    int node = blockIdx.x * 4 + (threadIdx.x >> 6);
    int lane = threadIdx.x & 63;
    if (node >= N) return;
    int s = rp[node], en = rp[node + 1];
    int x = lane >> 4, c = lane & 15;
    float msum = 0.f, csum = 0.f;
    for (int p = s + x; p < en; p += 4) {
        msum += bf2f(me16[(size_t)p * 16 + c]);
        if (c < 3) csum += cvec[(size_t)p * 3 + c];
    }
    msum += __shfl_xor(msum, 16); msum += __shfl_xor(msum, 32);
    csum += __shfl_xor(csum, 16); csum += __shfl_xor(csum, 32);
    if (lane < 16) macc[(size_t)node * M_D + lane] = msum;
    if (lane < 3) coorsOut[(size_t)node * 3 + lane] = coors[(size_t)node * 3 + lane] + csum;
}

// ---------------- dist head final matvec ----------------
__global__ void k_dist(const float* __restrict__ Hb, const float* __restrict__ w2,
                       const float* __restrict__ b2, float* __restrict__ dist, int nE) {
    int e = blockIdx.x * 4 + (threadIdx.x >> 6);
    int lane = threadIdx.x & 63;
    if (e >= nE) return;
    const float* r = Hb + (size_t)e * H_D;
    float s = r[lane] * w2[lane] + r[lane + 64] * w2[lane + 64];
#pragma unroll
    for (int off = 32; off; off >>= 1) s += __shfl_xor(s, off);
    if (lane == 0) dist[e] = reluf(s + b2[0]);
}

// ---------------- host ----------------
extern "C" void kernel_launch(void* const* d_in, const int* in_sizes, int n_in,
                              void* d_out, int out_size, void* d_ws, size_t ws_size,
                              hipStream_t stream) {
    const float* x1_in = (const float*)d_in[0];
    const float* x2_in = (const float*)d_in[1];
    const float* pos1  = (const float*)d_in[2];
    const float* pos2  = (const float*)d_in[3];
    const int* ei_intra1 = (const int*)d_in[4];
    const int* ei_intra2 = (const int*)d_in[5];
    const int* ei_12 = (const int*)d_in[6];
    const int* ei_21 = (const int*)d_in[7];
    const int* ei_int = (const int*)d_in[8];
    const float* g0_w  = (const float*)d_in[9];
    const float* g0_as = (const float*)d_in[10];
    const float* g0_ad = (const float*)d_in[11];
    const float* g0_b  = (const float*)d_in[12];
    const float* g1_w  = (const float*)d_in[13];
    const float* g1_as = (const float*)d_in[14];
    const float* g1_ad = (const float*)d_in[15];
    const float* g1_b  = (const float*)d_in[16];
    const float* it_ws = (const float*)d_in[17];
    const float* it_wd = (const float*)d_in[18];
    const float* it_as = (const float*)d_in[19];
    const float* it_ad = (const float*)d_in[20];
    const float* it_b  = (const float*)d_in[21];
    const float* eg_e_w1 = (const float*)d_in[22];
    const float* eg_e_b1 = (const float*)d_in[23];
    const float* eg_e_w2 = (const float*)d_in[24];
    const float* eg_e_b2 = (const float*)d_in[25];
    const float* eg_c_w1 = (const float*)d_in[26];
    const float* eg_c_b1 = (const float*)d_in[27];
    const float* eg_c_w2 = (const float*)d_in[28];
    const float* eg_c_b2 = (const float*)d_in[29];
    const float* eg_n_w1 = (const float*)d_in[30];
    const float* eg_n_b1 = (const float*)d_in[31];
    const float* eg_n_w2 = (const float*)d_in[32];
    const float* eg_n_b2 = (const float*)d_in[33];
    const float* lin_w = (const float*)d_in[34];
    const float* lin_b = (const float*)d_in[35];
    const float* aux_w1 = (const float*)d_in[36];
    const float* aux_b1 = (const float*)d_in[37];
    const float* aux_w2 = (const float*)d_in[38];
    const float* aux_b2 = (const float*)d_in[39];
    float* dout = (float*)d_out;

    // ---- workspace layout ----
    float* wsf = (float*)d_ws;
    size_t off = 0;
    auto alloc = [&](size_t nfl) { float* p = wsf + off; off += (nfl + 255) & ~(size_t)255; return p; };
    float* x1a = alloc((size_t)NN * H_D);
    float* x2a = alloc((size_t)NN * H_D);
    float* x1b = alloc((size_t)NN * H_D);
    float* x2b = alloc((size_t)NN * H_D);
    float* gatbuf = alloc((size_t)2 * NN * H_D);   // hs|hd
    float* hs = gatbuf;
    float* hd = gatbuf + (size_t)NN * H_D;
    float* esb = alloc(NN);
    float* edb = alloc(NN);
    float* co1a = alloc(NN * 3);
    float* co1b = alloc(NN * 3);
    float* co2a = alloc(NN * 3);
    float* co2b = alloc(NN * 3);
    float* macc = alloc((size_t)NN * M_D);
    unsigned* A16 = (unsigned*)alloc((size_t)NN * BUPAD);     // [N][272] uints (bf16 pairs)
    unsigned* B16 = (unsigned*)alloc((size_t)NN * BUPAD);
    unsigned* h16 = (unsigned*)alloc((size_t)NN * 64);        // bf16 h table for GAT aggregate
    int* cnt4 = (int*)alloc(4 * NN);
    int* rp4 = (int*)alloc(4 * (NN + 1));
    int* cjI1 = (int*)alloc(EIA_D);
    int* cjI2 = (int*)alloc(EIA_D);
    int* cj12 = (int*)alloc(EIR_D);
    int* cj21 = (int*)alloc(EIR_D);
    int* dstI1 = (int*)alloc(EIA_D);
    int* dstI2 = (int*)alloc(EIA_D);
    int* iota = (int*)alloc(NN);
    unsigned short* Wt = (unsigned short*)alloc(1100000);     // 2.2M ushorts
    unsigned short* Wf = (unsigned short*)alloc(35000);       // ew2 frag tables (hi|lo x 4)
    unsigned short* me16 = (unsigned short*)alloc((size_t)EIA_D * 8);   // bf16 m_e [E][16]
    float* cvec = alloc((size_t)EIA_D * 3);                   // per-edge cw*(rel)
    float* nh   = alloc((size_t)NN * NHID_D);
    float* Hb   = alloc((size_t)EIT_D * H_D);

    const int N = NN, H = H_D;
    int gNW = (N + 3) / 4;
    int gEA = (EIA_D + 255) / 256;

    // ---- weight prep descriptors ----
    PrepArgs pa;
    unsigned woffs[29], wsz[29];
    unsigned wo = 0;
    int wi = 0;
    auto addw = [&](const float* src, int K, int Ncols) {
        int Kpad = (K + 31) & ~31;
        int Npad = (Ncols + 63) & ~63;
        pa.d[wi] = {src, wo, K, Ncols, Kpad, Npad};
        woffs[wi] = wo; wsz[wi] = (unsigned)(Npad * Kpad);
        wo += 2u * Npad * Kpad;
        ++wi;
    };
    addw(g0_w, FIN_D, H);                          // 0
    addw(g0_w + FIN_D * H, FIN_D, H);              // 1
    addw(g1_w, H, H);                              // 2
    addw(g1_w + H * H, H, H);                      // 3
    for (int p = 0; p < 4; ++p) addw(it_ws + (size_t)p * H * H, H, H);   // 4..7
    for (int p = 0; p < 4; ++p) addw(it_wd + (size_t)p * H * H, H, H);   // 8..11
    for (int p = 0; p < 4; ++p) {                  // 12..19
        const float* ew1 = eg_e_w1 + (size_t)p * EIN_D * EHID_D;
        addw(ew1, H, EHID_D);
        addw(ew1 + (size_t)H * EHID_D, H, EHID_D);
    }
    for (int p = 0; p < 4; ++p) addw(eg_n_w1 + (size_t)p * NIN_D * NHID_D, NIN_D, NHID_D);  // 20..23
    for (int p = 0; p < 4; ++p) addw(eg_n_w2 + (size_t)p * NHID_D * H, NHID_D, H);          // 24..27
    addw(aux_w1, 2 * H, H);                        // 28
    k_prep<<<dim3(29, 16), 256, 0, stream>>>(pa, Wt);
    k_prep_ew2<<<4, 256, 0, stream>>>(eg_e_w2, Wf);
    auto WH = [&](int i) { return (const unsigned short*)(Wt + woffs[i]); };
    auto WL = [&](int i) { return (const unsigned short*)(Wt + woffs[i] + wsz[i]); };

    // ---- build 4 CSRs (dest-sorted) + iota ----
    k_filli<<<(4 * N + 255) / 256, 256, 0, stream>>>(cnt4, 0, 4 * N);
    k_iota<<<(N + 255) / 256, 256, 0, stream>>>(iota, N);
    k_hist<<<gEA, 256, 0, stream>>>(ei_intra1 + EIA_D, EIA_D, cnt4);
    k_hist<<<gEA, 256, 0, stream>>>(ei_intra2 + EIA_D, EIA_D, cnt4 + N);
    k_hist<<<gEA, 256, 0, stream>>>(ei_12 + EIR_D, EIR_D, cnt4 + 2 * N);
    k_hist<<<gEA, 256, 0, stream>>>(ei_21 + EIR_D, EIR_D, cnt4 + 3 * N);
    k_scan4<<<4, 256, 0, stream>>>(cnt4, N, rp4);
    k_filli<<<(4 * N + 255) / 256, 256, 0, stream>>>(cnt4, 0, 4 * N);
    const int* rpI1 = rp4;
    const int* rpI2 = rp4 + (N + 1);
    const int* rp12 = rp4 + 2 * (N + 1);
    const int* rp21 = rp4 + 3 * (N + 1);
    k_scatter<<<gEA, 256, 0, stream>>>(ei_intra1, ei_intra1 + EIA_D, EIA_D, rpI1, cnt4, cjI1, dstI1);
    k_scatter<<<gEA, 256, 0, stream>>>(ei_intra2, ei_intra2 + EIA_D, EIA_D, rpI2, cnt4 + N, cjI2, dstI2);
    k_scatter<<<gEA, 256, 0, stream>>>(ei_12, ei_12 + EIR_D, EIR_D, rp12, cnt4 + 2 * N, cj12, nullptr);
    k_scatter<<<gEA, 256, 0, stream>>>(ei_21, ei_21 + EIR_D, EIR_D, rp21, cnt4 + 3 * N, cj21, nullptr);

    const int MB = (N + 127) / 128;   // 157
    dim3 grid_h(MB, 2);               // N=128 outputs
    dim3 grid_A(MB, 9);               // N=514 outputs (Npad 576)
    dim3 grid_nh(MB, 4);              // N=256 outputs

    // ---- GAT stage (h GEMMs at AMODE=1: outputs consumed via bf16 table / exp logits) ----
    auto gat = [&](const float* xsrc, const float* xdst, bool same, int wsi, int wdi,
                   const int* rp, const int* cjj, int hasSelf,
                   const float* as_, const float* ad_, const float* b_,
                   int K, float* outb) {
        int Kpad = (K + 31) & ~31;
        k_mm<0, false, false, false, true, 1><<<grid_h, 256, 0, stream>>>(
            xsrc, nullptr, nullptr, nullptr, WH(wsi), WL(wsi), nullptr, nullptr,
            hs, (unsigned short*)h16, N, H, K, Kpad, H, 0);
        const float* hdp = hs;
        if (!same) {
            k_mm<0, false, false, false, false, 1><<<grid_h, 256, 0, stream>>>(
                xdst, nullptr, nullptr, nullptr, WH(wdi), WL(wdi), nullptr, nullptr,
                hd, nullptr, N, H, K, Kpad, H, 0);
            hdp = hd;
        }
        k_rowdot2<<<gNW, 256, 0, stream>>>(hs, hdp, as_, ad_, esb, edb, N);
        k_gat_fused<<<gNW, 256, 0, stream>>>(rp, cjj, hasSelf, esb, edb, h16, b_, outb, N);
    };

    gat(x1_in, x1_in, true, 0, 0, rpI1, cjI1, 1, g0_as, g0_ad, g0_b, FIN_D, x1a);
    gat(x2_in, x2_in, true, 1, 1, rpI2, cjI2, 1, g0_as + H, g0_ad + H, g0_b + H, FIN_D, x2a);
    const float* cx1 = x1a;
    const float* cx2 = x2a;
    gat(cx1, cx1, true, 2, 2, rpI1, cjI1, 1, g1_as, g1_ad, g1_b, H, x1b);
    gat(cx2, cx2, true, 3, 3, rpI2, cjI2, 1, g1_as + H, g1_ad + H, g1_b + H, H, x2b);
    cx1 = x1b; cx2 = x2b;
    {
        float* outs1[2] = {x1a, x1b};
        float* outs2[2] = {x2a, x2b};
        for (int l = 0; l < 2; ++l) {
            int p0 = l * 2 + 0, p1 = l * 2 + 1;
            float* o2 = outs2[l == 0 ? 0 : 1];
            float* o1 = outs1[l == 0 ? 0 : 1];
            gat(cx1, cx2, false, 4 + p0, 8 + p0, rp12, cj12, 0,
                it_as + p0 * H, it_ad + p0 * H, it_b + p0 * H, H, o2);
            gat(cx2, cx1, false, 4 + p1, 8 + p1, rp21, cj21, 0,
                it_as + p1 * H, it_ad + p1 * H, it_b + p1 * H, H, o1);
            cx1 = o1; cx2 = o2;
        }
    }

    // ---- EGNN stage ----
    auto egnn = [&](const float* feats, const float* coors, const int* rp, const int* cjj,
                    const int* dsti, int pidx, float* featsOut, float* coorsOut) {
        // A/B tables stored bf16 -> AMODE=1 adds nothing beyond the storage rounding
        k_mm<0, false, true, false, false, 1><<<grid_A, 256, 0, stream>>>(
            feats, nullptr, nullptr, nullptr, WH(12 + 2 * pidx), WL(12 + 2 * pidx),
            nullptr, nullptr, (float*)A16, nullptr, N, EHID_D, H, H, APAD, 0);
        k_mm<0, false, true, false, false, 1><<<grid_A, 256, 0, stream>>>(
            feats, nullptr, nullptr, nullptr, WH(13 + 2 * pidx), WL(13 + 2 * pidx),
            nullptr, nullptr, (float*)B16, nullptr, N, EHID_D, H, H, APAD, 0);
        const float* ew1 = eg_e_w1 + (size_t)pidx * EIN_D * EHID_D;
        k_edge_mfma<<<(EIA_D + 63) / 64, 256, 0, stream>>>(
            dsti, cjj, EIA_D, A16, B16, coors,
            ew1 + (size_t)256 * EHID_D, eg_e_b1 + pidx * EHID_D,
            Wf + (size_t)pidx * 8704, Wf + 4 * 8704 + (size_t)pidx * 8704,
            eg_e_b2 + pidx * M_D,
            eg_c_w1 + pidx * M_D * 64, eg_c_b1 + pidx * 64,
            eg_c_w2 + pidx * 64, eg_c_b2 + pidx,
            me16, cvec);
        k_egnn_seg<<<gNW, 256, 0, stream>>>(rp, me16, cvec, coors, coorsOut, macc, N);
        // nh GEMM gathers [feats | macc] via iota (concat fused into staging)
        k_mm<2, false, false, true, false, 2><<<grid_nh, 256, 0, stream>>>(
            feats, macc, iota, iota, WH(20 + pidx), WL(20 + pidx),
            eg_n_b1 + pidx * NHID_D, nullptr, nh, nullptr, N, NHID_D, NIN_D, 160, NHID_D, M_D);
        k_mm<0, true, false, false, false, 2><<<grid_h, 256, 0, stream>>>(
            nh, nullptr, nullptr, nullptr, WH(24 + pidx), WL(24 + pidx),
            eg_n_b2 + pidx * H, feats, featsOut, nullptr, N, H, NHID_D, NHID_D, H, 0);
    };
    egnn(cx1, pos1, rpI1, cjI1, dstI1, 0, x1a, co1a);
    egnn(cx2, pos2, rpI2, cjI2, dstI2, 1, x2a, co2a);
    cx1 = x1a; cx2 = x2a;
    egnn(cx1, co1a, rpI1, cjI1, dstI1, 2, x1b, co1b);
    egnn(cx2, co2a, rpI2, cjI2, dstI2, 3, x2b, co2b);
    cx1 = x1b; cx2 = x2b;

    // ---- heads ----
    k_nodescore<<<gNW, 256, 0, stream>>>(cx1, lin_w, lin_b, dout, N);
    k_nodescore<<<gNW, 256, 0, stream>>>(cx2, lin_w, lin_b, dout + N, N);
    k_mm<1, false, false, true, false, 2><<<dim3((EIT_D + 127) / 128, 2), 256, 0, stream>>>(
        cx1, cx2, ei_int, ei_int + EIT_D, WH(28), WL(28),
        aux_b1, nullptr, Hb, nullptr, EIT_D, H, 2 * H, 2 * H, H, H_D);
    k_dist<<<(EIT_D + 3) / 4, 256, 0, stream>>>(Hb, aux_w2, aux_b2, dout + 2 * N, EIT_D);
}

// Round 8
// 1916.585 us; speedup vs baseline: 3.0518x; 1.0603x over previous
//
#include <hip/hip_runtime.h>
#include <hip/hip_bf16.h>
#include <cstdint>
#include <cstddef>

// ---- problem constants ----
#define NN     20000
#define FIN_D  64
#define H_D    128
#define M_D    16
#define EIA_D  256000
#define EIR_D  256000
#define EIT_D  100000
#define EIN_D  257
#define EHID_D 514
#define NIN_D  144
#define NHID_D 256
#define APAD   544          // padded EHID; 17 k-tiles of 32
#define BUPAD  272          // APAD/2 uints per bf16 row (A and B tables)

typedef short bfrag __attribute__((ext_vector_type(8)));   // 8 bf16 (4 VGPRs)
typedef float ffrag __attribute__((ext_vector_type(4)));   // 4 fp32 acc

// fast silu: v_rcp_f32 (~1 ulp) instead of precise-div sequence
__device__ __forceinline__ float siluf(float x) {
    return x * __builtin_amdgcn_rcpf(1.f + __expf(-x));
}
__device__ __forceinline__ float reluf(float x) { return x > 0.f ? x : 0.f; }
__device__ __forceinline__ unsigned short f2bf(float f) {  // RNE fp32->bf16
    unsigned u = __float_as_uint(f);
    return (unsigned short)((u + 0x7FFFu + ((u >> 16) & 1u)) >> 16);
}
__device__ __forceinline__ float bf2f(unsigned short h) { return __uint_as_float(((unsigned)h) << 16); }
__device__ __forceinline__ float bf_lo(unsigned u) { return __uint_as_float(u << 16); }
__device__ __forceinline__ float bf_hi(unsigned u) { return __uint_as_float(u & 0xFFFF0000u); }
// packed RNE cvt (v_cvt_pk_bf16_f32 on gfx950)
__device__ __forceinline__ unsigned pkbf(float f0, float f1) {
    __hip_bfloat162 h = __float22bfloat162_rn(make_float2(f0, f1));
    return *(unsigned*)&h;
}

// ---------------- CSR build ----------------
__global__ void k_filli(int* p, int v, int n) {
    int i = blockIdx.x * 256 + threadIdx.x; if (i < n) p[i] = v;
}
__global__ void k_iota(int* p, int n) {
    int i = blockIdx.x * 256 + threadIdx.x; if (i < n) p[i] = i;
}
__global__ void k_hist(const int* __restrict__ si, int nE, int* __restrict__ cnt) {
    int e = blockIdx.x * 256 + threadIdx.x; if (e < nE) atomicAdd(&cnt[si[e]], 1);
}
__global__ void k_scan4(const int* __restrict__ cnt4, int n, int* __restrict__ rp4) {
    const int* cnt = cnt4 + (size_t)blockIdx.x * n;
    int* rp = rp4 + (size_t)blockIdx.x * (n + 1);
    __shared__ int tmp[256];
    __shared__ int carry;
    if (threadIdx.x == 0) { carry = 0; rp[0] = 0; }
    __syncthreads();
    for (int base = 0; base < n; base += 256) {
        int i = base + threadIdx.x;
        int v = (i < n) ? cnt[i] : 0;
        tmp[threadIdx.x] = v;
        __syncthreads();
        for (int off = 1; off < 256; off <<= 1) {
            int t = (threadIdx.x >= off) ? tmp[threadIdx.x - off] : 0;
            __syncthreads();
            tmp[threadIdx.x] += t;
            __syncthreads();
        }
        if (i < n) rp[i + 1] = carry + tmp[threadIdx.x];
        __syncthreads();
        if (threadIdx.x == 0) carry += tmp[255];
        __syncthreads();
    }
}
__global__ void k_scatter(const int* __restrict__ sj, const int* __restrict__ si, int nE,
                          const int* __restrict__ rp, int* __restrict__ cursor,
                          int* __restrict__ colj, int* __restrict__ dsti) {
    int e = blockIdx.x * 256 + threadIdx.x;
    if (e >= nE) return;
    int i = si[e];
    int p = rp[i] + atomicAdd(&cursor[i], 1);
    colj[p] = sj[e];
    if (dsti) dsti[p] = i;
}

// ---------------- weight prep: transpose + hi/lo bf16 split ----------------
struct PrepDesc { const float* src; unsigned dstOff; int K, N, Kpad, Npad; };
struct PrepArgs { PrepDesc d[29]; };
__global__ void k_prep(PrepArgs pa, unsigned short* __restrict__ Wt) {
    PrepDesc de = pa.d[blockIdx.x];
    int tot = de.Npad * de.Kpad;
    unsigned short* hi = Wt + de.dstOff;
    unsigned short* lo = hi + tot;
    for (int i = blockIdx.y * 256 + threadIdx.x; i < tot; i += gridDim.y * 256) {
        int n = i / de.Kpad, k = i - n * de.Kpad;
        float v = (n < de.N && k < de.K) ? de.src[(size_t)k * de.N + n] : 0.f;
        unsigned short h = f2bf(v);
        hi[i] = h;
        lo[i] = f2bf(v - bf2f(h));
    }
}

// pack ew2 [514][16] into MFMA B-fragment order; zero beyond k>=514 (neutralizes pad garbage)
__global__ void k_prep_ew2(const float* __restrict__ eg_e_w2, unsigned short* __restrict__ Wf) {
    int pidx = blockIdx.x;
    const float* src = eg_e_w2 + (size_t)pidx * EHID_D * M_D;
    unsigned short* hi = Wf + (size_t)pidx * 8704;
    unsigned short* lo = Wf + 4 * 8704 + (size_t)pidx * 8704;
    for (int idx = threadIdx.x; idx < 8704; idx += 256) {
        int t = idx >> 9, rem = idx & 511;
        int lane = rem >> 3, j2 = rem & 7;
        int k = t * 32 + ((lane >> 4) << 3) + j2;
        int n = lane & 15;
        float v = (k < EHID_D) ? src[(size_t)k * 16 + n] : 0.f;
        unsigned short h = f2bf(v);
        hi[idx] = h;
        lo[idx] = f2bf(v - bf2f(h));
    }
}

// ---------------- MFMA GEMM: C = act(A@W + bias) (+res) --------------------------------
// AMODE=2: A split hi/lo (3 MFMA). AMODE=1: A bf16 (2 MFMA; W stays hi/lo).
// DUAL writes a bf16 copy of output to C2. GATHER: row gm = [A[gi0[gm]] | A2[gi1[gm]] (stride s2)].
template<int ACT, bool RES, bool OBF, bool GATHER, bool DUAL, int AMODE>
__global__ __launch_bounds__(256) void k_mm(
        const float* __restrict__ A, const float* __restrict__ A2,
        const int* __restrict__ gi0, const int* __restrict__ gi1,
        const unsigned short* __restrict__ Wh, const unsigned short* __restrict__ Wl,
        const float* __restrict__ bias, const float* __restrict__ res,
        float* __restrict__ C, unsigned short* __restrict__ C2,
        int M, int Nc, int K, int Kpad, int ldc, int s2) {
    __shared__ __align__(16) unsigned short sAh[128 * 32];
    __shared__ __align__(16) unsigned short sAl[AMODE == 2 ? 128 * 32 : 16];
    const int tid = threadIdx.x;
    const int bm = blockIdx.x * 128, bn = blockIdx.y * 64;
    const int wv = tid >> 6, lane = tid & 63;
    ffrag acc[2][4];
#pragma unroll
    for (int mt = 0; mt < 2; ++mt)
#pragma unroll
        for (int nt = 0; nt < 4; ++nt)
#pragma unroll
            for (int r = 0; r < 4; ++r) acc[mt][nt][r] = 0.f;
    const int sr = tid >> 1;
    const int sks = (tid & 1) * 16;
    const int gm_s = bm + sr;
    const int sgmt = sr >> 4, smm = sr & 15, qb = (tid & 1) * 2;
    int gidx0 = 0, gidx1 = 0;
    if (GATHER && gm_s < M) { gidx0 = gi0[gm_s]; gidx1 = gi1[gm_s]; }
    const int q = lane >> 4, mm = lane & 15;

    for (int k0 = 0; k0 < Kpad; k0 += 32) {
        float v[16];
        bool valid = (gm_s < M) && (k0 + sks < K);
        if (valid) {
            const float* src;
            int kk = k0 + sks;
            if (GATHER) src = (kk < 128) ? (A + (size_t)gidx0 * 128 + kk)
                                         : (A2 + (size_t)gidx1 * s2 + (kk - 128));
            else src = A + (size_t)gm_s * K + kk;
#pragma unroll
            for (int i = 0; i < 4; ++i) {
                float4 t4 = ((const float4*)src)[i];
                v[4 * i] = t4.x; v[4 * i + 1] = t4.y; v[4 * i + 2] = t4.z; v[4 * i + 3] = t4.w;
            }
        } else {
#pragma unroll
            for (int i = 0; i < 16; ++i) v[i] = 0.f;
        }
#pragma unroll
        for (int o = 0; o < 2; ++o) {
            unsigned hw[4], lw[4];
#pragma unroll
            for (int p = 0; p < 4; ++p) {
                float f0 = v[o * 8 + 2 * p], f1 = v[o * 8 + 2 * p + 1];
                if (AMODE == 2) {
                    unsigned short h0 = f2bf(f0), h1 = f2bf(f1);
                    unsigned short l0 = f2bf(f0 - bf2f(h0)), l1 = f2bf(f1 - bf2f(h1));
                    hw[p] = (unsigned)h0 | ((unsigned)h1 << 16);
                    lw[p] = (unsigned)l0 | ((unsigned)l1 << 16);
                } else {
                    hw[p] = pkbf(f0, f1);
                }
            }
            int off16 = (sgmt * 4 + qb + o) * 16 + smm;
            ((uint4*)sAh)[off16] = make_uint4(hw[0], hw[1], hw[2], hw[3]);
            if (AMODE == 2) ((uint4*)sAl)[off16] = make_uint4(lw[0], lw[1], lw[2], lw[3]);
        }
        __syncthreads();
        bfrag bh[4], bl[4];
#pragma unroll
        for (int nt = 0; nt < 4; ++nt) {
            size_t woff = (size_t)(bn + nt * 16 + mm) * Kpad + k0 + q * 8;
            bh[nt] = *(const bfrag*)(Wh + woff);
            bl[nt] = *(const bfrag*)(Wl + woff);
        }
#pragma unroll
        for (int mt = 0; mt < 2; ++mt) {
            int off16 = ((wv * 2 + mt) * 4 + q) * 16 + mm;
            bfrag ah = ((const bfrag*)sAh)[off16];
#pragma unroll
            for (int nt = 0; nt < 4; ++nt) {
                acc[mt][nt] = __builtin_amdgcn_mfma_f32_16x16x32_bf16(ah, bh[nt], acc[mt][nt], 0, 0, 0);
                acc[mt][nt] = __builtin_amdgcn_mfma_f32_16x16x32_bf16(ah, bl[nt], acc[mt][nt], 0, 0, 0);
            }
            if (AMODE == 2) {
                bfrag al = ((const bfrag*)sAl)[off16];
#pragma unroll
                for (int nt = 0; nt < 4; ++nt)
                    acc[mt][nt] = __builtin_amdgcn_mfma_f32_16x16x32_bf16(al, bh[nt], acc[mt][nt], 0, 0, 0);
            }
        }
        __syncthreads();
    }
#pragma unroll
    for (int mt = 0; mt < 2; ++mt) {
#pragma unroll
        for (int nt = 0; nt < 4; ++nt) {
            int gn = bn + nt * 16 + mm;
            if (gn >= Nc) continue;
#pragma unroll
            for (int r = 0; r < 4; ++r) {
                int gm = bm + wv * 32 + mt * 16 + q * 4 + r;
                if (gm >= M) continue;
                float vv = acc[mt][nt][r];
                if (bias) vv += bias[gn];
                if (ACT == 1) vv = reluf(vv);
                if (ACT == 2) vv = siluf(vv);
                if (RES) vv += res[(size_t)gm * Nc + gn];
                if (OBF) ((unsigned short*)C)[(size_t)gm * ldc + gn] = f2bf(vv);
                else C[(size_t)gm * ldc + gn] = vv;
                if (DUAL) C2[(size_t)gm * ldc + gn] = f2bf(vv);
            }
        }
    }
}

// ---------------- paired row dots (es/ed): wave per node ----------------
__global__ void k_rowdot2(const float* __restrict__ hs, const float* __restrict__ hd,
                          const float* __restrict__ a_s, const float* __restrict__ a_d,
                          float* __restrict__ es, float* __restrict__ ed, int n) {
    int w = blockIdx.x * 4 + (threadIdx.x >> 6);
    int lane = threadIdx.x & 63;
    if (w >= n) return;
    const float* r1 = hs + (size_t)w * H_D;
    const float* r2 = hd + (size_t)w * H_D;
    float s1 = r1[lane] * a_s[lane] + r1[lane + 64] * a_s[lane + 64];
    float s2 = r2[lane] * a_d[lane] + r2[lane + 64] * a_d[lane + 64];
#pragma unroll
    for (int off = 32; off; off >>= 1) { s1 += __shfl_xor(s1, off); s2 += __shfl_xor(s2, off); }
    if (lane == 0) { es[w] = s1; ed[w] = s2; }
}

__global__ void k_nodescore(const float* __restrict__ x, const float* __restrict__ wv,
                            const float* __restrict__ b, float* __restrict__ o, int n) {
    int w = blockIdx.x * 4 + (threadIdx.x >> 6);
    int lane = threadIdx.x & 63;
    if (w >= n) return;
    const float* r = x + (size_t)w * H_D;
    float s = r[lane] * wv[lane] + r[lane + 64] * wv[lane + 64];
#pragma unroll
    for (int off = 32; off; off >>= 1) s += __shfl_xor(s, off);
    if (lane == 0) o[w] = s + b[0];
}

// ---------------- fused GAT softmax-aggregate (single pass; shift-invariance) ---------------
__global__ __launch_bounds__(256) void k_gat_fused(
        const int* __restrict__ rp, const int* __restrict__ cj, int hasSelf,
        const float* __restrict__ es, const float* __restrict__ ed,
        const unsigned* __restrict__ h16, const float* __restrict__ bias,
        float* __restrict__ out, int N) {
    int node = blockIdx.x * 4 + (threadIdx.x >> 6);
    int lane = threadIdx.x & 63;
    if (node >= N) return;
    int start = rp[node], end = rp[node + 1];
    float edi = ed[node];
    float den = 0.f, a0 = 0.f, a1 = 0.f;
    for (int p = start; p < end; ++p) {
        int j = cj[p];
        float v = es[j] + edi;
        v = v < 0.f ? 0.2f * v : v;
        float ex = __expf(v);
        den += ex;
        unsigned u = h16[(size_t)j * 64 + lane];
        a0 += ex * bf_lo(u);
        a1 += ex * bf_hi(u);
    }
    if (hasSelf) {
        float v = es[node] + edi;
        v = v < 0.f ? 0.2f * v : v;
        float ex = __expf(v);
        den += ex;
        unsigned u = h16[(size_t)node * 64 + lane];
        a0 += ex * bf_lo(u);
        a1 += ex * bf_hi(u);
    }
    float inv = 1.f / (den + 1e-16f);
    float2 o;
    o.x = reluf(a0 * inv + bias[2 * lane]);
    o.y = reluf(a1 * inv + bias[2 * lane + 1]);
    ((float2*)(out + (size_t)node * H_D))[lane] = o;
}

// ---------------- EGNN edge kernel: gather(bf16 A,B) + silu + MFMA + coord gate -------------
// A table already contains eb1 (folded in GEMM bias). g enters MFMA as bf16; W hi+lo -> 2 MFMA.
__global__ __launch_bounds__(256) void k_edge_mfma(
        const int* __restrict__ dsti, const int* __restrict__ cj, int nE,
        const unsigned* __restrict__ A16,       // [N][BUPAD] bf16 pairs (incl. eb1)
        const unsigned* __restrict__ Bp,        // [N][BUPAD] bf16 pairs
        const float* __restrict__ coors,
        const float* __restrict__ w_rd,         // [514]
        const unsigned short* __restrict__ Wfh, const unsigned short* __restrict__ Wfl,
        const float* __restrict__ eb2,
        const float* __restrict__ cw1, const float* __restrict__ cb1,
        const float* __restrict__ cw2, const float* __restrict__ cb2,
        unsigned short* __restrict__ me16, float* __restrict__ cvec) {
    __shared__ __align__(16) float s_w[APAD];
    __shared__ float s_cw1[1024];
    __shared__ float s_cb1[64], s_cw2[64], s_eb2[16];
    __shared__ float sM[4][16][17];
    for (int i = threadIdx.x; i < APAD; i += 256)
        s_w[i] = (i < EHID_D) ? w_rd[i] : 0.f;
    for (int i = threadIdx.x; i < 1024; i += 256) s_cw1[i] = cw1[i];
    if (threadIdx.x < 64) { s_cb1[threadIdx.x] = cb1[threadIdx.x]; s_cw2[threadIdx.x] = cw2[threadIdx.x]; }
    if (threadIdx.x < 16) s_eb2[threadIdx.x] = eb2[threadIdx.x];
    __syncthreads();
    const float cb2v = cb2[0];
    const int wv = threadIdx.x >> 6, lane = threadIdx.x & 63;
    const int q = lane >> 4, mm = lane & 15;
    const int ebase = blockIdx.x * 64 + wv * 16;
    const int e = ebase + mm;
    const bool ev = e < nE;
    int ii = ev ? dsti[e] : 0;
    int jj = ev ? cj[e] : 0;
    float dx = coors[(size_t)jj * 3]     - coors[(size_t)ii * 3];
    float dy = coors[(size_t)jj * 3 + 1] - coors[(size_t)ii * 3 + 1];
    float dz = coors[(size_t)jj * 3 + 2] - coors[(size_t)ii * 3 + 2];
    float rd = dx * dx + dy * dy + dz * dz;
    const unsigned* Ar = A16 + (size_t)ii * BUPAD;
    const unsigned* Br = Bp + (size_t)jj * BUPAD;
    ffrag acc = {0.f, 0.f, 0.f, 0.f};
#pragma unroll 4
    for (int t = 0; t < 17; ++t) {
        int ks = t * 32 + q * 8;
        int ku = ks >> 1;
        uint4 au = *(const uint4*)(Ar + ku);
        uint4 bu = *(const uint4*)(Br + ku);
        float4 w0 = *(const float4*)(s_w + ks);
        float4 w1 = *(const float4*)(s_w + ks + 4);
        float g[8];
        g[0] = siluf(bf_lo(au.x) + bf_lo(bu.x) + rd * w0.x);
        g[1] = siluf(bf_hi(au.x) + bf_hi(bu.x) + rd * w0.y);
        g[2] = siluf(bf_lo(au.y) + bf_lo(bu.y) + rd * w0.z);
        g[3] = siluf(bf_hi(au.y) + bf_hi(bu.y) + rd * w0.w);
        g[4] = siluf(bf_lo(au.z) + bf_lo(bu.z) + rd * w1.x);
        g[5] = siluf(bf_hi(au.z) + bf_hi(bu.z) + rd * w1.y);
        g[6] = siluf(bf_lo(au.w) + bf_lo(bu.w) + rd * w1.z);
        g[7] = siluf(bf_hi(au.w) + bf_hi(bu.w) + rd * w1.w);
        bfrag ah;
        unsigned* ahp = (unsigned*)&ah;
        ahp[0] = pkbf(g[0], g[1]);
        ahp[1] = pkbf(g[2], g[3]);
        ahp[2] = pkbf(g[4], g[5]);
        ahp[3] = pkbf(g[6], g[7]);
        bfrag bh = *(const bfrag*)(Wfh + (size_t)(t * 64 + lane) * 8);
        bfrag bl = *(const bfrag*)(Wfl + (size_t)(t * 64 + lane) * 8);
        acc = __builtin_amdgcn_mfma_f32_16x16x32_bf16(ah, bh, acc, 0, 0, 0);
        acc = __builtin_amdgcn_mfma_f32_16x16x32_bf16(ah, bl, acc, 0, 0, 0);
    }
    // D row=q*4+r (edge), col=mm (channel); m_e = silu(D + eb2)
#pragma unroll
    for (int r = 0; r < 4; ++r) {
        int erow = q * 4 + r;
        float me = siluf(acc[r] + s_eb2[mm]);
        sM[wv][erow][mm] = me;
        int e2 = ebase + erow;
        if (e2 < nE) me16[(size_t)e2 * 16 + mm] = f2bf(me);
    }
    // coordinate gate MLP (16 -> 64 -> 1); lane==el owns edge el's (dx,dy,dz)
    for (int el = 0; el < 16; ++el) {
        int e3 = ebase + el;
        if (e3 >= nE) break;
        float a = s_cb1[lane];
#pragma unroll
        for (int c = 0; c < 16; ++c) a += sM[wv][el][c] * s_cw1[c * 64 + lane];
        float p = siluf(a) * s_cw2[lane];
#pragma unroll
        for (int off = 32; off; off >>= 1) p += __shfl_xor(p, off);
        float cwv = p + cb2v;
        if (lane == el) {
            cvec[(size_t)e3 * 3]     = cwv * dx;
            cvec[(size_t)e3 * 3 + 1] = cwv * dy;
            cvec[(size_t)e3 * 3 + 2] = cwv * dz;
        }
    }
}

// ---------------- EGNN CSR segment-sum: linear reads only ----------------
__global__ __launch_bounds__(256) void k_egnn_seg(
        const int* __restrict__ rp,
        const unsigned short* __restrict__ me16, const float* __restrict__ cvec,
        const float* __restrict__ coors,
        float* __restrict__ coorsOut, float* __restrict__ macc, int N) {
    int node = blockIdx.x * 4 + (threadIdx.x >> 6);
    int lane = threadIdx.x & 63;
    if (node >= N) return;
    int s = rp[node], en = rp[node + 1];
    int x = lane >> 4, c = lane & 15;
    float msum = 0.f, csum = 0.f;
    for (int p = s + x; p < en; p += 4) {
        msum += bf2f(me16[(size_t)p * 16 + c]);
        if (c < 3) csum += cvec[(size_t)p * 3 + c];
    }
    msum += __shfl_xor(msum, 16); msum += __shfl_xor(msum, 32);
    csum += __shfl_xor(csum, 16); csum += __shfl_xor(csum, 32);
    if (lane < 16) macc[(size_t)node * M_D + lane] = msum;
    if (lane < 3) coorsOut[(size_t)node * 3 + lane] = coors[(size_t)node * 3 + lane] + csum;
}

// ---------------- dist head final matvec ----------------
__global__ void k_dist(const float* __restrict__ Hb, const float* __restrict__ w2,
                       const float* __restrict__ b2, float* __restrict__ dist, int nE) {
    int e = blockIdx.x * 4 + (threadIdx.x >> 6);
    int lane = threadIdx.x & 63;
    if (e >= nE) return;
    const float* r = Hb + (size_t)e * H_D;
    float s = r[lane] * w2[lane] + r[lane + 64] * w2[lane + 64];
#pragma unroll
    for (int off = 32; off; off >>= 1) s += __shfl_xor(s, off);
    if (lane == 0) dist[e] = reluf(s + b2[0]);
}

// ---------------- host ----------------
extern "C" void kernel_launch(void* const* d_in, const int* in_sizes, int n_in,
                              void* d_out, int out_size, void* d_ws, size_t ws_size,
                              hipStream_t stream) {
    const float* x1_in = (const float*)d_in[0];
    const float* x2_in = (const float*)d_in[1];
    const float* pos1  = (const float*)d_in[2];
    const float* pos2  = (const float*)d_in[3];
    const int* ei_intra1 = (const int*)d_in[4];
    const int* ei_intra2 = (const int*)d_in[5];
    const int* ei_12 = (const int*)d_in[6];
    const int* ei_21 = (const int*)d_in[7];
    const int* ei_int = (const int*)d_in[8];
    const float* g0_w  = (const float*)d_in[9];
    const float* g0_as = (const float*)d_in[10];
    const float* g0_ad = (const float*)d_in[11];
    const float* g0_b  = (const float*)d_in[12];
    const float* g1_w  = (const float*)d_in[13];
    const float* g1_as = (const float*)d_in[14];
    const float* g1_ad = (const float*)d_in[15];
    const float* g1_b  = (const float*)d_in[16];
    const float* it_ws = (const float*)d_in[17];
    const float* it_wd = (const float*)d_in[18];
    const float* it_as = (const float*)d_in[19];
    const float* it_ad = (const float*)d_in[20];
    const float* it_b  = (const float*)d_in[21];
    const float* eg_e_w1 = (const float*)d_in[22];
    const float* eg_e_b1 = (const float*)d_in[23];
    const float* eg_e_w2 = (const float*)d_in[24];
    const float* eg_e_b2 = (const float*)d_in[25];
    const float* eg_c_w1 = (const float*)d_in[26];
    const float* eg_c_b1 = (const float*)d_in[27];
    const float* eg_c_w2 = (const float*)d_in[28];
    const float* eg_c_b2 = (const float*)d_in[29];
    const float* eg_n_w1 = (const float*)d_in[30];
    const float* eg_n_b1 = (const float*)d_in[31];
    const float* eg_n_w2 = (const float*)d_in[32];
    const float* eg_n_b2 = (const float*)d_in[33];
    const float* lin_w = (const float*)d_in[34];
    const float* lin_b = (const float*)d_in[35];
    const float* aux_w1 = (const float*)d_in[36];
    const float* aux_b1 = (const float*)d_in[37];
    const float* aux_w2 = (const float*)d_in[38];
    const float* aux_b2 = (const float*)d_in[39];
    float* dout = (float*)d_out;

    // ---- workspace layout ----
    float* wsf = (float*)d_ws;
    size_t off = 0;
    auto alloc = [&](size_t nfl) { float* p = wsf + off; off += (nfl + 255) & ~(size_t)255; return p; };
    float* x1a = alloc((size_t)NN * H_D);
    float* x2a = alloc((size_t)NN * H_D);
    float* x1b = alloc((size_t)NN * H_D);
    float* x2b = alloc((size_t)NN * H_D);
    float* gatbuf = alloc((size_t)2 * NN * H_D);   // hs|hd
    float* hs = gatbuf;
    float* hd = gatbuf + (size_t)NN * H_D;
    float* esb = alloc(NN);
    float* edb = alloc(NN);
    float* co1a = alloc(NN * 3);
    float* co1b = alloc(NN * 3);
    float* co2a = alloc(NN * 3);
    float* co2b = alloc(NN * 3);
    float* macc = alloc((size_t)NN * M_D);
    unsigned* A16 = (unsigned*)alloc((size_t)NN * BUPAD);     // [N][272] uints (bf16 pairs)
    unsigned* B16 = (unsigned*)alloc((size_t)NN * BUPAD);
    unsigned* h16 = (unsigned*)alloc((size_t)NN * 64);        // bf16 h table for GAT aggregate
    int* cnt4 = (int*)alloc(4 * NN);
    int* rp4 = (int*)alloc(4 * (NN + 1));
    int* cjI1 = (int*)alloc(EIA_D);
    int* cjI2 = (int*)alloc(EIA_D);
    int* cj12 = (int*)alloc(EIR_D);
    int* cj21 = (int*)alloc(EIR_D);
    int* dstI1 = (int*)alloc(EIA_D);
    int* dstI2 = (int*)alloc(EIA_D);
    int* iota = (int*)alloc(NN);
    unsigned short* Wt = (unsigned short*)alloc(1100000);     // 2.2M ushorts
    unsigned short* Wf = (unsigned short*)alloc(35000);       // ew2 frag tables (hi|lo x 4)
    unsigned short* me16 = (unsigned short*)alloc((size_t)EIA_D * 8);   // bf16 m_e [E][16]
    float* cvec = alloc((size_t)EIA_D * 3);                   // per-edge cw*(rel)
    float* nh   = alloc((size_t)NN * NHID_D);
    float* Hb   = alloc((size_t)EIT_D * H_D);

    const int N = NN, H = H_D;
    int gNW = (N + 3) / 4;
    int gEA = (EIA_D + 255) / 256;

    // ---- weight prep descriptors ----
    PrepArgs pa;
    unsigned woffs[29], wsz[29];
    unsigned wo = 0;
    int wi = 0;
    auto addw = [&](const float* src, int K, int Ncols) {
        int Kpad = (K + 31) & ~31;
        int Npad = (Ncols + 63) & ~63;
        pa.d[wi] = {src, wo, K, Ncols, Kpad, Npad};
        woffs[wi] = wo; wsz[wi] = (unsigned)(Npad * Kpad);
        wo += 2u * Npad * Kpad;
        ++wi;
    };
    addw(g0_w, FIN_D, H);                          // 0
    addw(g0_w + FIN_D * H, FIN_D, H);              // 1
    addw(g1_w, H, H);                              // 2
    addw(g1_w + H * H, H, H);                      // 3
    for (int p = 0; p < 4; ++p) addw(it_ws + (size_t)p * H * H, H, H);   // 4..7
    for (int p = 0; p < 4; ++p) addw(it_wd + (size_t)p * H * H, H, H);   // 8..11
    for (int p = 0; p < 4; ++p) {                  // 12..19
        const float* ew1 = eg_e_w1 + (size_t)p * EIN_D * EHID_D;
        addw(ew1, H, EHID_D);
        addw(ew1 + (size_t)H * EHID_D, H, EHID_D);
    }
    for (int p = 0; p < 4; ++p) addw(eg_n_w1 + (size_t)p * NIN_D * NHID_D, NIN_D, NHID_D);  // 20..23
    for (int p = 0; p < 4; ++p) addw(eg_n_w2 + (size_t)p * NHID_D * H, NHID_D, H);          // 24..27
    addw(aux_w1, 2 * H, H);                        // 28
    k_prep<<<dim3(29, 16), 256, 0, stream>>>(pa, Wt);
    k_prep_ew2<<<4, 256, 0, stream>>>(eg_e_w2, Wf);
    auto WH = [&](int i) { return (const unsigned short*)(Wt + woffs[i]); };
    auto WL = [&](int i) { return (const unsigned short*)(Wt + woffs[i] + wsz[i]); };

    // ---- build 4 CSRs (dest-sorted) + iota ----
    k_filli<<<(4 * N + 255) / 256, 256, 0, stream>>>(cnt4, 0, 4 * N);
    k_iota<<<(N + 255) / 256, 256, 0, stream>>>(iota, N);
    k_hist<<<gEA, 256, 0, stream>>>(ei_intra1 + EIA_D, EIA_D, cnt4);
    k_hist<<<gEA, 256, 0, stream>>>(ei_intra2 + EIA_D, EIA_D, cnt4 + N);
    k_hist<<<gEA, 256, 0, stream>>>(ei_12 + EIR_D, EIR_D, cnt4 + 2 * N);
    k_hist<<<gEA, 256, 0, stream>>>(ei_21 + EIR_D, EIR_D, cnt4 + 3 * N);
    k_scan4<<<4, 256, 0, stream>>>(cnt4, N, rp4);
    k_filli<<<(4 * N + 255) / 256, 256, 0, stream>>>(cnt4, 0, 4 * N);
    const int* rpI1 = rp4;
    const int* rpI2 = rp4 + (N + 1);
    const int* rp12 = rp4 + 2 * (N + 1);
    const int* rp21 = rp4 + 3 * (N + 1);
    k_scatter<<<gEA, 256, 0, stream>>>(ei_intra1, ei_intra1 + EIA_D, EIA_D, rpI1, cnt4, cjI1, dstI1);
    k_scatter<<<gEA, 256, 0, stream>>>(ei_intra2, ei_intra2 + EIA_D, EIA_D, rpI2, cnt4 + N, cjI2, dstI2);
    k_scatter<<<gEA, 256, 0, stream>>>(ei_12, ei_12 + EIR_D, EIR_D, rp12, cnt4 + 2 * N, cj12, nullptr);
    k_scatter<<<gEA, 256, 0, stream>>>(ei_21, ei_21 + EIR_D, EIR_D, rp21, cnt4 + 3 * N, cj21, nullptr);

    const int MB = (N + 127) / 128;   // 157
    dim3 grid_h(MB, 2);               // N=128 outputs
    dim3 grid_A(MB, 9);               // N=514 outputs (Npad 576)
    dim3 grid_nh(MB, 4);              // N=256 outputs

    // ---- GAT stage ----
    auto gat = [&](const float* xsrc, const float* xdst, bool same, int wsi, int wdi,
                   const int* rp, const int* cjj, int hasSelf,
                   const float* as_, const float* ad_, const float* b_,
                   int K, float* outb) {
        int Kpad = (K + 31) & ~31;
        k_mm<0, false, false, false, true, 1><<<grid_h, 256, 0, stream>>>(
            xsrc, nullptr, nullptr, nullptr, WH(wsi), WL(wsi), nullptr, nullptr,
            hs, (unsigned short*)h16, N, H, K, Kpad, H, 0);
        const float* hdp = hs;
        if (!same) {
            k_mm<0, false, false, false, false, 1><<<grid_h, 256, 0, stream>>>(
                xdst, nullptr, nullptr, nullptr, WH(wdi), WL(wdi), nullptr, nullptr,
                hd, nullptr, N, H, K, Kpad, H, 0);
            hdp = hd;
        }
        k_rowdot2<<<gNW, 256, 0, stream>>>(hs, hdp, as_, ad_, esb, edb, N);
        k_gat_fused<<<gNW, 256, 0, stream>>>(rp, cjj, hasSelf, esb, edb, h16, b_, outb, N);
    };

    gat(x1_in, x1_in, true, 0, 0, rpI1, cjI1, 1, g0_as, g0_ad, g0_b, FIN_D, x1a);
    gat(x2_in, x2_in, true, 1, 1, rpI2, cjI2, 1, g0_as + H, g0_ad + H, g0_b + H, FIN_D, x2a);
    const float* cx1 = x1a;
    const float* cx2 = x2a;
    gat(cx1, cx1, true, 2, 2, rpI1, cjI1, 1, g1_as, g1_ad, g1_b, H, x1b);
    gat(cx2, cx2, true, 3, 3, rpI2, cjI2, 1, g1_as + H, g1_ad + H, g1_b + H, H, x2b);
    cx1 = x1b; cx2 = x2b;
    {
        float* outs1[2] = {x1a, x1b};
        float* outs2[2] = {x2a, x2b};
        for (int l = 0; l < 2; ++l) {
            int p0 = l * 2 + 0, p1 = l * 2 + 1;
            float* o2 = outs2[l == 0 ? 0 : 1];
            float* o1 = outs1[l == 0 ? 0 : 1];
            gat(cx1, cx2, false, 4 + p0, 8 + p0, rp12, cj12, 0,
                it_as + p0 * H, it_ad + p0 * H, it_b + p0 * H, H, o2);
            gat(cx2, cx1, false, 4 + p1, 8 + p1, rp21, cj21, 0,
                it_as + p1 * H, it_ad + p1 * H, it_b + p1 * H, H, o1);
            cx1 = o1; cx2 = o2;
        }
    }

    // ---- EGNN stage ----
    auto egnn = [&](const float* feats, const float* coors, const int* rp, const int* cjj,
                    const int* dsti, int pidx, float* featsOut, float* coorsOut) {
        // A table = feats@ew1_A + eb1 (bias folded); B table = feats@ew1_B
        k_mm<0, false, true, false, false, 1><<<grid_A, 256, 0, stream>>>(
            feats, nullptr, nullptr, nullptr, WH(12 + 2 * pidx), WL(12 + 2 * pidx),
            eg_e_b1 + pidx * EHID_D, nullptr, (float*)A16, nullptr, N, EHID_D, H, H, APAD, 0);
        k_mm<0, false, true, false, false, 1><<<grid_A, 256, 0, stream>>>(
            feats, nullptr, nullptr, nullptr, WH(13 + 2 * pidx), WL(13 + 2 * pidx),
            nullptr, nullptr, (float*)B16, nullptr, N, EHID_D, H, H, APAD, 0);
        const float* ew1 = eg_e_w1 + (size_t)pidx * EIN_D * EHID_D;
        k_edge_mfma<<<(EIA_D + 63) / 64, 256, 0, stream>>>(
            dsti, cjj, EIA_D, A16, B16, coors,
            ew1 + (size_t)256 * EHID_D,
            Wf + (size_t)pidx * 8704, Wf + 4 * 8704 + (size_t)pidx * 8704,
            eg_e_b2 + pidx * M_D,
            eg_c_w1 + pidx * M_D * 64, eg_c_b1 + pidx * 64,
            eg_c_w2 + pidx * 64, eg_c_b2 + pidx,
            me16, cvec);
        k_egnn_seg<<<gNW, 256, 0, stream>>>(rp, me16, cvec, coors, coorsOut, macc, N);
        // nh GEMM gathers [feats | macc] via iota (concat fused into staging)
        k_mm<2, false, false, true, false, 2><<<grid_nh, 256, 0, stream>>>(
            feats, macc, iota, iota, WH(20 + pidx), WL(20 + pidx),
            eg_n_b1 + pidx * NHID_D, nullptr, nh, nullptr, N, NHID_D, NIN_D, 160, NHID_D, M_D);
        k_mm<0, true, false, false, false, 2><<<grid_h, 256, 0, stream>>>(
            nh, nullptr, nullptr, nullptr, WH(24 + pidx), WL(24 + pidx),
            eg_n_b2 + pidx * H, feats, featsOut, nullptr, N, H, NHID_D, NHID_D, H, 0);
    };
    egnn(cx1, pos1, rpI1, cjI1, dstI1, 0, x1a, co1a);
    egnn(cx2, pos2, rpI2, cjI2, dstI2, 1, x2a, co2a);
    cx1 = x1a; cx2 = x2a;
    egnn(cx1, co1a, rpI1, cjI1, dstI1, 2, x1b, co1b);
    egnn(cx2, co2a, rpI2, cjI2, dstI2, 3, x2b, co2b);
    cx1 = x1b; cx2 = x2b;

    // ---- heads ----
    k_nodescore<<<gNW, 256, 0, stream>>>(cx1, lin_w, lin_b, dout, N);
    k_nodescore<<<gNW, 256, 0, stream>>>(cx2, lin_w, lin_b, dout + N, N);
    k_mm<1, false, false, true, false, 2><<<dim3((EIT_D + 127) / 128, 2), 256, 0, stream>>>(
        cx1, cx2, ei_int, ei_int + EIT_D, WH(28), WL(28),
        aux_b1, nullptr, Hb, nullptr, EIT_D, H, 2 * H, 2 * H, H, H_D);
    k_dist<<<(EIT_D + 3) / 4, 256, 0, stream>>>(Hb, aux_w2, aux_b2, dout + 2 * N, EIT_D);
}

// Round 10
// 1601.416 us; speedup vs baseline: 3.6524x; 1.1968x over previous
//
#include <hip/hip_runtime.h>
#include <hip/hip_bf16.h>
#include <cstdint>
#include <cstddef>

// ---- problem constants ----
#define NN     20000
#define FIN_D  64
#define H_D    128
#define M_D    16
#define EIA_D  256000
#define EIR_D  256000
#define EIT_D  100000
#define EIN_D  257
#define EHID_D 514
#define NIN_D  144
#define NHID_D 256
#define APAD   544          // padded EHID; 17 k-tiles of 32
#define BUPAD  272          // APAD/2 uints per bf16 row (A and B tables)

typedef short bfrag __attribute__((ext_vector_type(8)));   // 8 bf16 (4 VGPRs)
typedef float ffrag __attribute__((ext_vector_type(4)));   // 4 fp32 acc

// fast silu: v_rcp_f32 (~1 ulp) instead of precise-div sequence
__device__ __forceinline__ float siluf(float x) {
    return x * __builtin_amdgcn_rcpf(1.f + __expf(-x));
}
__device__ __forceinline__ float reluf(float x) { return x > 0.f ? x : 0.f; }
__device__ __forceinline__ unsigned short f2bf(float f) {  // RNE fp32->bf16
    unsigned u = __float_as_uint(f);
    return (unsigned short)((u + 0x7FFFu + ((u >> 16) & 1u)) >> 16);
}
__device__ __forceinline__ float bf2f(unsigned short h) { return __uint_as_float(((unsigned)h) << 16); }
__device__ __forceinline__ float bf_lo(unsigned u) { return __uint_as_float(u << 16); }
__device__ __forceinline__ float bf_hi(unsigned u) { return __uint_as_float(u & 0xFFFF0000u); }
__device__ __forceinline__ unsigned pkbf(float f0, float f1) {
    __hip_bfloat162 h = __float22bfloat162_rn(make_float2(f0, f1));
    return *(unsigned*)&h;
}

// ---------------- CSR build ----------------
__global__ void k_filli(int* p, int v, int n) {
    int i = blockIdx.x * 256 + threadIdx.x; if (i < n) p[i] = v;
}
__global__ void k_iota(int* p, int n) {
    int i = blockIdx.x * 256 + threadIdx.x; if (i < n) p[i] = i;
}
__global__ void k_hist(const int* __restrict__ si, int nE, int* __restrict__ cnt) {
    int e = blockIdx.x * 256 + threadIdx.x; if (e < nE) atomicAdd(&cnt[si[e]], 1);
}
__global__ void k_scan4(const int* __restrict__ cnt4, int n, int* __restrict__ rp4) {
    const int* cnt = cnt4 + (size_t)blockIdx.x * n;
    int* rp = rp4 + (size_t)blockIdx.x * (n + 1);
    __shared__ int tmp[256];
    __shared__ int carry;
    if (threadIdx.x == 0) { carry = 0; rp[0] = 0; }
    __syncthreads();
    for (int base = 0; base < n; base += 256) {
        int i = base + threadIdx.x;
        int v = (i < n) ? cnt[i] : 0;
        tmp[threadIdx.x] = v;
        __syncthreads();
        for (int off = 1; off < 256; off <<= 1) {
            int t = (threadIdx.x >= off) ? tmp[threadIdx.x - off] : 0;
            __syncthreads();
            tmp[threadIdx.x] += t;
            __syncthreads();
        }
        if (i < n) rp[i + 1] = carry + tmp[threadIdx.x];
        __syncthreads();
        if (threadIdx.x == 0) carry += tmp[255];
        __syncthreads();
    }
}
__global__ void k_scatter(const int* __restrict__ sj, const int* __restrict__ si, int nE,
                          const int* __restrict__ rp, int* __restrict__ cursor,
                          int* __restrict__ colj, int* __restrict__ dsti) {
    int e = blockIdx.x * 256 + threadIdx.x;
    if (e >= nE) return;
    int i = si[e];
    int p = rp[i] + atomicAdd(&cursor[i], 1);
    colj[p] = sj[e];
    if (dsti) dsti[p] = i;
}

// ---------------- weight prep: transpose + hi/lo bf16 split ----------------
struct PrepDesc { const float* src; unsigned dstOff; int K, N, Kpad, Npad; };
struct PrepArgs { PrepDesc d[29]; };
__global__ void k_prep(PrepArgs pa, unsigned short* __restrict__ Wt) {
    PrepDesc de = pa.d[blockIdx.x];
    int tot = de.Npad * de.Kpad;
    unsigned short* hi = Wt + de.dstOff;
    unsigned short* lo = hi + tot;
    for (int i = blockIdx.y * 256 + threadIdx.x; i < tot; i += gridDim.y * 256) {
        int n = i / de.Kpad, k = i - n * de.Kpad;
        float v = (n < de.N && k < de.K) ? de.src[(size_t)k * de.N + n] : 0.f;
        unsigned short h = f2bf(v);
        hi[i] = h;
        lo[i] = f2bf(v - bf2f(h));
    }
}

// pack ew2 [514][16] into MFMA B-fragment order; zero beyond k>=514
__global__ void k_prep_ew2(const float* __restrict__ eg_e_w2, unsigned short* __restrict__ Wf) {
    int pidx = blockIdx.x;
    const float* src = eg_e_w2 + (size_t)pidx * EHID_D * M_D;
    unsigned short* hi = Wf + (size_t)pidx * 8704;
    unsigned short* lo = Wf + 4 * 8704 + (size_t)pidx * 8704;
    for (int idx = threadIdx.x; idx < 8704; idx += 256) {
        int t = idx >> 9, rem = idx & 511;
        int lane = rem >> 3, j2 = rem & 7;
        int k = t * 32 + ((lane >> 4) << 3) + j2;
        int n = lane & 15;
        float v = (k < EHID_D) ? src[(size_t)k * 16 + n] : 0.f;
        unsigned short h = f2bf(v);
        hi[idx] = h;
        lo[idx] = f2bf(v - bf2f(h));
    }
}

// ---------------- batched MFMA GEMM ----------------
// Per-z job: C = act(A@W + bias)(+res). AMODE=2 hi/lo A (3 MFMA), =1 bf16 A (2 MFMA).
// DUAL: bf16 copy to C2. NOC: suppress C. DOT>=1: atomicAdd per-row dot(acc,da)->dota
// (and db->dotb if DOT==2). GATHER: row = [A[gi0[r]](128) | A2[gi1[r]](stride s2)].
// OBF pad columns Nc..ldc-1 are ZEROED (bf16 tables are over-read to the padded
// stride by consumers; recycled workspace there can hold NaN-pattern bf16, and
// NaN*0 = NaN in MFMA — round-9 lesson).
struct MMJob {
    const float* A; const float* A2;
    const int* gi0; const int* gi1;
    const unsigned short* Wh; const unsigned short* Wl;
    const float* bias; const float* res;
    float* C; unsigned short* C2;
    const float* da; const float* db;
    float* dota; float* dotb;
};
struct MMJobs { MMJob j[4]; };

template<int ACT, bool RES, bool OBF, bool GATHER, bool DUAL, int AMODE, int DOT, bool NOC>
__global__ __launch_bounds__(256) void k_mm(MMJobs js, int M, int Nc, int K, int Kpad, int ldc, int s2) {
    __shared__ __align__(16) unsigned short sAh[128 * 32];
    __shared__ __align__(16) unsigned short sAl[AMODE == 2 ? 128 * 32 : 16];
    const MMJob jb = js.j[blockIdx.z];
    const int tid = threadIdx.x;
    const int bm = blockIdx.x * 128, bn = blockIdx.y * 64;
    const int wv = tid >> 6, lane = tid & 63;
    ffrag acc[2][4];
#pragma unroll
    for (int mt = 0; mt < 2; ++mt)
#pragma unroll
        for (int nt = 0; nt < 4; ++nt)
#pragma unroll
            for (int r = 0; r < 4; ++r) acc[mt][nt][r] = 0.f;
    const int sr = tid >> 1;
    const int sks = (tid & 1) * 16;
    const int gm_s = bm + sr;
    const int sgmt = sr >> 4, smm = sr & 15, qb = (tid & 1) * 2;
    int gidx0 = 0, gidx1 = 0;
    if (GATHER && gm_s < M) { gidx0 = jb.gi0[gm_s]; gidx1 = jb.gi1[gm_s]; }
    const int q = lane >> 4, mm = lane & 15;

    for (int k0 = 0; k0 < Kpad; k0 += 32) {
        float v[16];
        bool valid = (gm_s < M) && (k0 + sks < K);
        if (valid) {
            const float* src;
            int kk = k0 + sks;
            if (GATHER) src = (kk < 128) ? (jb.A + (size_t)gidx0 * 128 + kk)
                                         : (jb.A2 + (size_t)gidx1 * s2 + (kk - 128));
            else src = jb.A + (size_t)gm_s * K + kk;
#pragma unroll
            for (int i = 0; i < 4; ++i) {
                float4 t4 = ((const float4*)src)[i];
                v[4 * i] = t4.x; v[4 * i + 1] = t4.y; v[4 * i + 2] = t4.z; v[4 * i + 3] = t4.w;
            }
        } else {
#pragma unroll
            for (int i = 0; i < 16; ++i) v[i] = 0.f;
        }
#pragma unroll
        for (int o = 0; o < 2; ++o) {
            unsigned hw[4], lw[4];
#pragma unroll
            for (int p = 0; p < 4; ++p) {
                float f0 = v[o * 8 + 2 * p], f1 = v[o * 8 + 2 * p + 1];
                if (AMODE == 2) {
                    unsigned short h0 = f2bf(f0), h1 = f2bf(f1);
                    unsigned short l0 = f2bf(f0 - bf2f(h0)), l1 = f2bf(f1 - bf2f(h1));
                    hw[p] = (unsigned)h0 | ((unsigned)h1 << 16);
                    lw[p] = (unsigned)l0 | ((unsigned)l1 << 16);
                } else {
                    hw[p] = pkbf(f0, f1);
                }
            }
            int off16 = (sgmt * 4 + qb + o) * 16 + smm;
            ((uint4*)sAh)[off16] = make_uint4(hw[0], hw[1], hw[2], hw[3]);
            if (AMODE == 2) ((uint4*)sAl)[off16] = make_uint4(lw[0], lw[1], lw[2], lw[3]);
        }
        __syncthreads();
        bfrag bh[4], bl[4];
#pragma unroll
        for (int nt = 0; nt < 4; ++nt) {
            size_t woff = (size_t)(bn + nt * 16 + mm) * Kpad + k0 + q * 8;
            bh[nt] = *(const bfrag*)(jb.Wh + woff);
            bl[nt] = *(const bfrag*)(jb.Wl + woff);
        }
#pragma unroll
        for (int mt = 0; mt < 2; ++mt) {
            int off16 = ((wv * 2 + mt) * 4 + q) * 16 + mm;
            bfrag ah = ((const bfrag*)sAh)[off16];
#pragma unroll
            for (int nt = 0; nt < 4; ++nt) {
                acc[mt][nt] = __builtin_amdgcn_mfma_f32_16x16x32_bf16(ah, bh[nt], acc[mt][nt], 0, 0, 0);
                acc[mt][nt] = __builtin_amdgcn_mfma_f32_16x16x32_bf16(ah, bl[nt], acc[mt][nt], 0, 0, 0);
            }
            if (AMODE == 2) {
                bfrag al = ((const bfrag*)sAl)[off16];
#pragma unroll
                for (int nt = 0; nt < 4; ++nt)
                    acc[mt][nt] = __builtin_amdgcn_mfma_f32_16x16x32_bf16(al, bh[nt], acc[mt][nt], 0, 0, 0);
            }
        }
        __syncthreads();
    }
    // ---- DOT epilogue: per-row dot(acc, da/db) -> atomicAdd ----
    if (DOT >= 1) {
        float dav[4], dbv[4];
#pragma unroll
        for (int nt = 0; nt < 4; ++nt) {
            int gn = bn + nt * 16 + mm;
            dav[nt] = (gn < Nc) ? jb.da[gn] : 0.f;
            if (DOT == 2) dbv[nt] = (gn < Nc) ? jb.db[gn] : 0.f;
        }
#pragma unroll
        for (int mt = 0; mt < 2; ++mt)
#pragma unroll
            for (int r = 0; r < 4; ++r) {
                int gm = bm + wv * 32 + mt * 16 + q * 4 + r;
                float sa = 0.f, sb = 0.f;
#pragma unroll
                for (int nt = 0; nt < 4; ++nt) {
                    sa += acc[mt][nt][r] * dav[nt];
                    if (DOT == 2) sb += acc[mt][nt][r] * dbv[nt];
                }
                sa += __shfl_xor(sa, 1); sa += __shfl_xor(sa, 2);
                sa += __shfl_xor(sa, 4); sa += __shfl_xor(sa, 8);
                if (DOT == 2) {
                    sb += __shfl_xor(sb, 1); sb += __shfl_xor(sb, 2);
                    sb += __shfl_xor(sb, 4); sb += __shfl_xor(sb, 8);
                }
                if (mm == 0 && gm < M) {
                    atomicAdd(jb.dota + gm, sa);
                    if (DOT == 2) atomicAdd(jb.dotb + gm, sb);
                }
            }
    }
    // ---- store epilogue ----
    if (!NOC || DUAL) {
#pragma unroll
        for (int mt = 0; mt < 2; ++mt) {
#pragma unroll
            for (int nt = 0; nt < 4; ++nt) {
                int gn = bn + nt * 16 + mm;
                bool inb = gn < Nc;
                bool padz = OBF && !NOC && !inb && gn < ldc;   // zero bf16 pad cols
                if (!inb && !padz) continue;
#pragma unroll
                for (int r = 0; r < 4; ++r) {
                    int gm = bm + wv * 32 + mt * 16 + q * 4 + r;
                    if (gm >= M) continue;
                    if (padz) {
                        ((unsigned short*)jb.C)[(size_t)gm * ldc + gn] = 0;
                        continue;
                    }
                    float vv = acc[mt][nt][r];
                    if (jb.bias) vv += jb.bias[gn];
                    if (ACT == 1) vv = reluf(vv);
                    if (ACT == 2) vv = siluf(vv);
                    if (RES) vv += jb.res[(size_t)gm * Nc + gn];
                    if (!NOC) {
                        if (OBF) ((unsigned short*)jb.C)[(size_t)gm * ldc + gn] = f2bf(vv);
                        else jb.C[(size_t)gm * ldc + gn] = vv;
                    }
                    if (DUAL) jb.C2[(size_t)gm * ldc + gn] = f2bf(vv);
                }
            }
        }
    }
}

__global__ void k_nodescore(const float* __restrict__ x, const float* __restrict__ wv,
                            const float* __restrict__ b, float* __restrict__ o, int n) {
    int w = blockIdx.x * 4 + (threadIdx.x >> 6);
    int lane = threadIdx.x & 63;
    if (w >= n) return;
    const float* r = x + (size_t)w * H_D;
    float s = r[lane] * wv[lane] + r[lane + 64] * wv[lane + 64];
#pragma unroll
    for (int off = 32; off; off >>= 1) s += __shfl_xor(s, off);
    if (lane == 0) o[w] = s + b[0];
}

// ---------------- fused GAT softmax-aggregate (single pass, 2-edge unrolled) ----------------
__global__ __launch_bounds__(256) void k_gat_fused(
        const int* __restrict__ rp, const int* __restrict__ cj, int hasSelf,
        const float* __restrict__ es, const float* __restrict__ ed,
        const unsigned* __restrict__ h16, const float* __restrict__ bias,
        float* __restrict__ out, int N) {
    int node = blockIdx.x * 4 + (threadIdx.x >> 6);
    int lane = threadIdx.x & 63;
    if (node >= N) return;
    int start = rp[node], end = rp[node + 1];
    float edi = ed[node];
    float den = 0.f, a0 = 0.f, a1 = 0.f;
    int p = start;
    for (; p + 2 <= end; p += 2) {
        int j0 = cj[p], j1 = cj[p + 1];
        float e0 = es[j0], e1 = es[j1];
        unsigned u0 = h16[(size_t)j0 * 64 + lane];
        unsigned u1 = h16[(size_t)j1 * 64 + lane];
        float v0 = e0 + edi; v0 = v0 < 0.f ? 0.2f * v0 : v0;
        float v1 = e1 + edi; v1 = v1 < 0.f ? 0.2f * v1 : v1;
        float x0 = __expf(v0), x1 = __expf(v1);
        den += x0 + x1;
        a0 += x0 * bf_lo(u0) + x1 * bf_lo(u1);
        a1 += x0 * bf_hi(u0) + x1 * bf_hi(u1);
    }
    if (p < end) {
        int j = cj[p];
        float v = es[j] + edi;
        v = v < 0.f ? 0.2f * v : v;
        float ex = __expf(v);
        den += ex;
        unsigned u = h16[(size_t)j * 64 + lane];
        a0 += ex * bf_lo(u);
        a1 += ex * bf_hi(u);
    }
    if (hasSelf) {
        float v = es[node] + edi;
        v = v < 0.f ? 0.2f * v : v;
        float ex = __expf(v);
        den += ex;
        unsigned u = h16[(size_t)node * 64 + lane];
        a0 += ex * bf_lo(u);
        a1 += ex * bf_hi(u);
    }
    float inv = 1.f / (den + 1e-16f);
    float2 o;
    o.x = reluf(a0 * inv + bias[2 * lane]);
    o.y = reluf(a1 * inv + bias[2 * lane + 1]);
    ((float2*)(out + (size_t)node * H_D))[lane] = o;
}

// ---------------- EGNN edge kernel ----------------
__global__ __launch_bounds__(256) void k_edge_mfma(
        const int* __restrict__ dsti, const int* __restrict__ cj, int nE,
        const unsigned* __restrict__ A16, const unsigned* __restrict__ Bp,
        const float* __restrict__ coors,
        const float* __restrict__ w_rd,
        const unsigned short* __restrict__ Wfh, const unsigned short* __restrict__ Wfl,
        const float* __restrict__ eb2,
        const float* __restrict__ cw1, const float* __restrict__ cb1,
        const float* __restrict__ cw2, const float* __restrict__ cb2,
        unsigned short* __restrict__ me16, float* __restrict__ cvec) {
    __shared__ __align__(16) float s_w[APAD];
    __shared__ float s_cw1[1024];
    __shared__ float s_cb1[64], s_cw2[64], s_eb2[16];
    __shared__ float sM[4][16][17];
    for (int i = threadIdx.x; i < APAD; i += 256)
        s_w[i] = (i < EHID_D) ? w_rd[i] : 0.f;
    for (int i = threadIdx.x; i < 1024; i += 256) s_cw1[i] = cw1[i];
    if (threadIdx.x < 64) { s_cb1[threadIdx.x] = cb1[threadIdx.x]; s_cw2[threadIdx.x] = cw2[threadIdx.x]; }
    if (threadIdx.x < 16) s_eb2[threadIdx.x] = eb2[threadIdx.x];
    __syncthreads();
    const float cb2v = cb2[0];
    const int wv = threadIdx.x >> 6, lane = threadIdx.x & 63;
    const int q = lane >> 4, mm = lane & 15;
    const int ebase = blockIdx.x * 64 + wv * 16;
    const int e = ebase + mm;
    const bool ev = e < nE;
    int ii = ev ? dsti[e] : 0;
    int jj = ev ? cj[e] : 0;
    float dx = coors[(size_t)jj * 3]     - coors[(size_t)ii * 3];
    float dy = coors[(size_t)jj * 3 + 1] - coors[(size_t)ii * 3 + 1];
    float dz = coors[(size_t)jj * 3 + 2] - coors[(size_t)ii * 3 + 2];
    float rd = dx * dx + dy * dy + dz * dz;
    const unsigned* Ar = A16 + (size_t)ii * BUPAD;
    const unsigned* Br = Bp + (size_t)jj * BUPAD;
    ffrag acc = {0.f, 0.f, 0.f, 0.f};
#pragma unroll 4
    for (int t = 0; t < 17; ++t) {
        int ks = t * 32 + q * 8;
        int ku = ks >> 1;
        uint4 au = *(const uint4*)(Ar + ku);
        uint4 bu = *(const uint4*)(Br + ku);
        float4 w0 = *(const float4*)(s_w + ks);
        float4 w1 = *(const float4*)(s_w + ks + 4);
        float g[8];
        g[0] = siluf(bf_lo(au.x) + bf_lo(bu.x) + rd * w0.x);
        g[1] = siluf(bf_hi(au.x) + bf_hi(bu.x) + rd * w0.y);
        g[2] = siluf(bf_lo(au.y) + bf_lo(bu.y) + rd * w0.z);
        g[3] = siluf(bf_hi(au.y) + bf_hi(bu.y) + rd * w0.w);
        g[4] = siluf(bf_lo(au.z) + bf_lo(bu.z) + rd * w1.x);
        g[5] = siluf(bf_hi(au.z) + bf_hi(bu.z) + rd * w1.y);
        g[6] = siluf(bf_lo(au.w) + bf_lo(bu.w) + rd * w1.z);
        g[7] = siluf(bf_hi(au.w) + bf_hi(bu.w) + rd * w1.w);
        bfrag ah;
        unsigned* ahp = (unsigned*)&ah;
        ahp[0] = pkbf(g[0], g[1]);
        ahp[1] = pkbf(g[2], g[3]);
        ahp[2] = pkbf(g[4], g[5]);
        ahp[3] = pkbf(g[6], g[7]);
        bfrag bh = *(const bfrag*)(Wfh + (size_t)(t * 64 + lane) * 8);
        bfrag bl = *(const bfrag*)(Wfl + (size_t)(t * 64 + lane) * 8);
        acc = __builtin_amdgcn_mfma_f32_16x16x32_bf16(ah, bh, acc, 0, 0, 0);
        acc = __builtin_amdgcn_mfma_f32_16x16x32_bf16(ah, bl, acc, 0, 0, 0);
    }
#pragma unroll
    for (int r = 0; r < 4; ++r) {
        int erow = q * 4 + r;
        float me = siluf(acc[r] + s_eb2[mm]);
        sM[wv][erow][mm] = me;
        int e2 = ebase + erow;
        if (e2 < nE) me16[(size_t)e2 * 16 + mm] = f2bf(me);
    }
    for (int el = 0; el < 16; ++el) {
        int e3 = ebase + el;
        if (e3 >= nE) break;
        float a = s_cb1[lane];
#pragma unroll
        for (int c = 0; c < 16; ++c) a += sM[wv][el][c] * s_cw1[c * 64 + lane];
        float p = siluf(a) * s_cw2[lane];
#pragma unroll
        for (int off = 32; off; off >>= 1) p += __shfl_xor(p, off);
        float cwv = p + cb2v;
        if (lane == el) {
            cvec[(size_t)e3 * 3]     = cwv * dx;
            cvec[(size_t)e3 * 3 + 1] = cwv * dy;
            cvec[(size_t)e3 * 3 + 2] = cwv * dz;
        }
    }
}

// ---------------- EGNN CSR segment-sum ----------------
__global__ __launch_bounds__(256) void k_egnn_seg(
        const int* __restrict__ rp,
        const unsigned short* __restrict__ me16, const float* __restrict__ cvec,
        const float* __restrict__ coors,
        float* __restrict__ coorsOut, float* __restrict__ macc, int N) {
    int node = blockIdx.x * 4 + (threadIdx.x >> 6);
    int lane = threadIdx.x & 63;
    if (node >= N) return;
    int s = rp[node], en = rp[node + 1];
    int x = lane >> 4, c = lane & 15;
    float msum = 0.f, csum = 0.f;
    for (int p = s + x; p < en; p += 4) {
        msum += bf2f(me16[(size_t)p * 16 + c]);
        if (c < 3) csum += cvec[(size_t)p * 3 + c];
    }
    msum += __shfl_xor(msum, 16); msum += __shfl_xor(msum, 32);
    csum += __shfl_xor(csum, 16); csum += __shfl_xor(csum, 32);
    if (lane < 16) macc[(size_t)node * M_D + lane] = msum;
    if (lane < 3) coorsOut[(size_t)node * 3 + lane] = coors[(size_t)node * 3 + lane] + csum;
}

// ---------------- dist head final matvec ----------------
__global__ void k_dist(const float* __restrict__ Hb, const float* __restrict__ w2,
                       const float* __restrict__ b2, float* __restrict__ dist, int nE) {
    int e = blockIdx.x * 4 + (threadIdx.x >> 6);
    int lane = threadIdx.x & 63;
    if (e >= nE) return;
    const float* r = Hb + (size_t)e * H_D;
    float s = r[lane] * w2[lane] + r[lane + 64] * w2[lane + 64];
#pragma unroll
    for (int off = 32; off; off >>= 1) s += __shfl_xor(s, off);
    if (lane == 0) dist[e] = reluf(s + b2[0]);
}

// ---------------- host ----------------
extern "C" void kernel_launch(void* const* d_in, const int* in_sizes, int n_in,
                              void* d_out, int out_size, void* d_ws, size_t ws_size,
                              hipStream_t stream) {
    const float* x1_in = (const float*)d_in[0];
    const float* x2_in = (const float*)d_in[1];
    const float* pos1  = (const float*)d_in[2];
    const float* pos2  = (const float*)d_in[3];
    const int* ei_intra1 = (const int*)d_in[4];
    const int* ei_intra2 = (const int*)d_in[5];
    const int* ei_12 = (const int*)d_in[6];
    const int* ei_21 = (const int*)d_in[7];
    const int* ei_int = (const int*)d_in[8];
    const float* g0_w  = (const float*)d_in[9];
    const float* g0_as = (const float*)d_in[10];
    const float* g0_ad = (const float*)d_in[11];
    const float* g0_b  = (const float*)d_in[12];
    const float* g1_w  = (const float*)d_in[13];
    const float* g1_as = (const float*)d_in[14];
    const float* g1_ad = (const float*)d_in[15];
    const float* g1_b  = (const float*)d_in[16];
    const float* it_ws = (const float*)d_in[17];
    const float* it_wd = (const float*)d_in[18];
    const float* it_as = (const float*)d_in[19];
    const float* it_ad = (const float*)d_in[20];
    const float* it_b  = (const float*)d_in[21];
    const float* eg_e_w1 = (const float*)d_in[22];
    const float* eg_e_b1 = (const float*)d_in[23];
    const float* eg_e_w2 = (const float*)d_in[24];
    const float* eg_e_b2 = (const float*)d_in[25];
    const float* eg_c_w1 = (const float*)d_in[26];
    const float* eg_c_b1 = (const float*)d_in[27];
    const float* eg_c_w2 = (const float*)d_in[28];
    const float* eg_c_b2 = (const float*)d_in[29];
    const float* eg_n_w1 = (const float*)d_in[30];
    const float* eg_n_b1 = (const float*)d_in[31];
    const float* eg_n_w2 = (const float*)d_in[32];
    const float* eg_n_b2 = (const float*)d_in[33];
    const float* lin_w = (const float*)d_in[34];
    const float* lin_b = (const float*)d_in[35];
    const float* aux_w1 = (const float*)d_in[36];
    const float* aux_b1 = (const float*)d_in[37];
    const float* aux_w2 = (const float*)d_in[38];
    const float* aux_b2 = (const float*)d_in[39];
    float* dout = (float*)d_out;

    // ---- workspace layout (~175 MB of 256 MiB) ----
    float* wsf = (float*)d_ws;
    size_t off = 0;
    auto alloc = [&](size_t nfl) { float* p = wsf + off; off += (nfl + 255) & ~(size_t)255; return p; };
    float* x1a = alloc((size_t)NN * H_D);
    float* x2a = alloc((size_t)NN * H_D);
    float* x1b = alloc((size_t)NN * H_D);
    float* x2b = alloc((size_t)NN * H_D);
    float* esed = alloc(4 * NN);                  // es1|es2|ed1|ed2
    float* es1 = esed, *es2 = esed + NN, *ed1 = esed + 2 * NN, *ed2 = esed + 3 * NN;
    float* co1a = alloc(NN * 3);
    float* co1b = alloc(NN * 3);
    float* co2a = alloc(NN * 3);
    float* co2b = alloc(NN * 3);
    float* macc1 = alloc((size_t)NN * M_D);
    float* macc2 = alloc((size_t)NN * M_D);
    unsigned* A16a = (unsigned*)alloc((size_t)NN * BUPAD);
    unsigned* B16a = (unsigned*)alloc((size_t)NN * BUPAD);
    unsigned* A16b = (unsigned*)alloc((size_t)NN * BUPAD);
    unsigned* B16b = (unsigned*)alloc((size_t)NN * BUPAD);
    unsigned* h16a = (unsigned*)alloc((size_t)NN * 64);
    unsigned* h16b = (unsigned*)alloc((size_t)NN * 64);
    int* cnt4 = (int*)alloc(4 * NN);
    int* rp4 = (int*)alloc(4 * (NN + 1));
    int* cjI1 = (int*)alloc(EIA_D);
    int* cjI2 = (int*)alloc(EIA_D);
    int* cj12 = (int*)alloc(EIR_D);
    int* cj21 = (int*)alloc(EIR_D);
    int* dstI1 = (int*)alloc(EIA_D);
    int* dstI2 = (int*)alloc(EIA_D);
    int* iota = (int*)alloc(NN);
    unsigned short* Wt = (unsigned short*)alloc(1100000);
    unsigned short* Wf = (unsigned short*)alloc(35000);
    unsigned short* me16a = (unsigned short*)alloc((size_t)EIA_D * 8);
    unsigned short* me16b = (unsigned short*)alloc((size_t)EIA_D * 8);
    float* cveca = alloc((size_t)EIA_D * 3);
    float* cvecb = alloc((size_t)EIA_D * 3);
    // aliases: nh over B-tables (dead after edge kernel; pad cols now zeroed in k_mm so
    // recycled bits can't leak NaN bf16 into the next layer's tables);
    // Hb over the whole A/B-table block (dead at aux time)
    float* nh1 = (float*)B16a;     // 20000*256 fp32 = 20.5 MB <= 21.8 MB
    float* nh2 = (float*)B16b;
    float* Hb  = (float*)A16a;     // 100000*128 fp32 = 51.2 MB <= 87 MB table block

    const int N = NN, H = H_D;
    int gNW = (N + 3) / 4;
    int gEA = (EIA_D + 255) / 256;

    // ---- weight prep ----
    PrepArgs pa;
    unsigned woffs[29], wsz[29];
    unsigned wo = 0;
    int wi = 0;
    auto addw = [&](const float* src, int K, int Ncols) {
        int Kpad = (K + 31) & ~31;
        int Npad = (Ncols + 63) & ~63;
        pa.d[wi] = {src, wo, K, Ncols, Kpad, Npad};
        woffs[wi] = wo; wsz[wi] = (unsigned)(Npad * Kpad);
        wo += 2u * Npad * Kpad;
        ++wi;
    };
    addw(g0_w, FIN_D, H);                          // 0
    addw(g0_w + FIN_D * H, FIN_D, H);              // 1
    addw(g1_w, H, H);                              // 2
    addw(g1_w + H * H, H, H);                      // 3
    for (int p = 0; p < 4; ++p) addw(it_ws + (size_t)p * H * H, H, H);   // 4..7
    for (int p = 0; p < 4; ++p) addw(it_wd + (size_t)p * H * H, H, H);   // 8..11
    for (int p = 0; p < 4; ++p) {                  // 12..19
        const float* ew1 = eg_e_w1 + (size_t)p * EIN_D * EHID_D;
        addw(ew1, H, EHID_D);
        addw(ew1 + (size_t)H * EHID_D, H, EHID_D);
    }
    for (int p = 0; p < 4; ++p) addw(eg_n_w1 + (size_t)p * NIN_D * NHID_D, NIN_D, NHID_D);  // 20..23
    for (int p = 0; p < 4; ++p) addw(eg_n_w2 + (size_t)p * NHID_D * H, NHID_D, H);          // 24..27
    addw(aux_w1, 2 * H, H);                        // 28
    k_prep<<<dim3(29, 16), 256, 0, stream>>>(pa, Wt);
    k_prep_ew2<<<4, 256, 0, stream>>>(eg_e_w2, Wf);
    auto WH = [&](int i) { return (const unsigned short*)(Wt + woffs[i]); };
    auto WL = [&](int i) { return (const unsigned short*)(Wt + woffs[i] + wsz[i]); };

    // ---- CSRs + iota ----
    k_filli<<<(4 * N + 255) / 256, 256, 0, stream>>>(cnt4, 0, 4 * N);
    k_iota<<<(N + 255) / 256, 256, 0, stream>>>(iota, N);
    k_hist<<<gEA, 256, 0, stream>>>(ei_intra1 + EIA_D, EIA_D, cnt4);
    k_hist<<<gEA, 256, 0, stream>>>(ei_intra2 + EIA_D, EIA_D, cnt4 + N);
    k_hist<<<gEA, 256, 0, stream>>>(ei_12 + EIR_D, EIR_D, cnt4 + 2 * N);
    k_hist<<<gEA, 256, 0, stream>>>(ei_21 + EIR_D, EIR_D, cnt4 + 3 * N);
    k_scan4<<<4, 256, 0, stream>>>(cnt4, N, rp4);
    k_filli<<<(4 * N + 255) / 256, 256, 0, stream>>>(cnt4, 0, 4 * N);
    const int* rpI1 = rp4;
    const int* rpI2 = rp4 + (N + 1);
    const int* rp12 = rp4 + 2 * (N + 1);
    const int* rp21 = rp4 + 3 * (N + 1);
    k_scatter<<<gEA, 256, 0, stream>>>(ei_intra1, ei_intra1 + EIA_D, EIA_D, rpI1, cnt4, cjI1, dstI1);
    k_scatter<<<gEA, 256, 0, stream>>>(ei_intra2, ei_intra2 + EIA_D, EIA_D, rpI2, cnt4 + N, cjI2, dstI2);
    k_scatter<<<gEA, 256, 0, stream>>>(ei_12, ei_12 + EIR_D, EIR_D, rp12, cnt4 + 2 * N, cj12, nullptr);
    k_scatter<<<gEA, 256, 0, stream>>>(ei_21, ei_21 + EIR_D, EIR_D, rp21, cnt4 + 3 * N, cj21, nullptr);

    const int MB = (N + 127) / 128;   // 157
    MMJobs js{};

    // ---- GAT intra layers (z=2: graph1, graph2; DOT=2 computes es,ed; no fp32 C) ----
    auto intra = [&](const float* xa, const float* xb, int wa, int wb,
                     const float* as_a, const float* ad_a, const float* as_b, const float* ad_b,
                     const float* b_a, const float* b_b, int K, float* oa, float* ob) {
        int Kpad = (K + 31) & ~31;
        k_filli<<<(4 * N + 255) / 256, 256, 0, stream>>>((int*)esed, 0, 4 * N);
        js.j[0] = {xa, nullptr, nullptr, nullptr, WH(wa), WL(wa), nullptr, nullptr,
                   nullptr, (unsigned short*)h16a, as_a, ad_a, es1, ed1};
        js.j[1] = {xb, nullptr, nullptr, nullptr, WH(wb), WL(wb), nullptr, nullptr,
                   nullptr, (unsigned short*)h16b, as_b, ad_b, es2, ed2};
        k_mm<0, false, false, false, true, 1, 2, true><<<dim3(MB, 2, 2), 256, 0, stream>>>(
            js, N, H, K, Kpad, H, 0);
        k_gat_fused<<<gNW, 256, 0, stream>>>(rpI1, cjI1, 1, es1, ed1, h16a, b_a, oa, N);
        k_gat_fused<<<gNW, 256, 0, stream>>>(rpI2, cjI2, 1, es2, ed2, h16b, b_b, ob, N);
    };

    intra(x1_in, x2_in, 0, 1, g0_as, g0_ad, g0_as + H, g0_ad + H, g0_b, g0_b + H, FIN_D, x1a, x2a);
    const float* cx1 = x1a;
    const float* cx2 = x2a;
    intra(cx1, cx2, 2, 3, g1_as, g1_ad, g1_as + H, g1_ad + H, g1_b, g1_b + H, H, x1b, x2b);
    cx1 = x1b; cx2 = x2b;

    // ---- GAT cross layers ----
    {
        float* outs1[2] = {x1a, x1b};
        float* outs2[2] = {x2a, x2b};
        for (int l = 0; l < 2; ++l) {
            int p0 = l * 2 + 0, p1 = l * 2 + 1;
            float* o2 = outs2[l];
            float* o1 = outs1[l];
            k_filli<<<(4 * N + 255) / 256, 256, 0, stream>>>((int*)esed, 0, 4 * N);
            // hs pair: h16 + es
            js.j[0] = {cx1, nullptr, nullptr, nullptr, WH(4 + p0), WL(4 + p0), nullptr, nullptr,
                       nullptr, (unsigned short*)h16a, it_as + p0 * H, nullptr, es1, nullptr};
            js.j[1] = {cx2, nullptr, nullptr, nullptr, WH(4 + p1), WL(4 + p1), nullptr, nullptr,
                       nullptr, (unsigned short*)h16b, it_as + p1 * H, nullptr, es2, nullptr};
            k_mm<0, false, false, false, true, 1, 1, true><<<dim3(MB, 2, 2), 256, 0, stream>>>(
                js, N, H, H, H, H, 0);
            // hd pair: ed only (no output at all)
            js.j[0] = {cx2, nullptr, nullptr, nullptr, WH(8 + p0), WL(8 + p0), nullptr, nullptr,
                       nullptr, nullptr, it_ad + p0 * H, nullptr, ed1, nullptr};
            js.j[1] = {cx1, nullptr, nullptr, nullptr, WH(8 + p1), WL(8 + p1), nullptr, nullptr,
                       nullptr, nullptr, it_ad + p1 * H, nullptr, ed2, nullptr};
            k_mm<0, false, false, false, false, 1, 1, true><<<dim3(MB, 2, 2), 256, 0, stream>>>(
                js, N, H, H, H, H, 0);
            k_gat_fused<<<gNW, 256, 0, stream>>>(rp12, cj12, 0, es1, ed1, h16a, it_b + p0 * H, o2, N);
            k_gat_fused<<<gNW, 256, 0, stream>>>(rp21, cj21, 0, es2, ed2, h16b, it_b + p1 * H, o1, N);
            cx1 = o1; cx2 = o2;
        }
    }

    // ---- EGNN layers (graph pair batched) ----
    auto egnn_pair = [&](const float* f1, const float* f2, const float* c1, const float* c2,
                         int l, float* fo1, float* fo2, float* co1, float* co2) {
        int p0 = 2 * l, p1 = 2 * l + 1;
        // A/B tables z=4 (pad cols zeroed by k_mm)
        js.j[0] = {f1, nullptr, nullptr, nullptr, WH(12 + 2 * p0), WL(12 + 2 * p0),
                   eg_e_b1 + p0 * EHID_D, nullptr, (float*)A16a, nullptr, nullptr, nullptr, nullptr, nullptr};
        js.j[1] = {f1, nullptr, nullptr, nullptr, WH(13 + 2 * p0), WL(13 + 2 * p0),
                   nullptr, nullptr, (float*)B16a, nullptr, nullptr, nullptr, nullptr, nullptr};
        js.j[2] = {f2, nullptr, nullptr, nullptr, WH(12 + 2 * p1), WL(12 + 2 * p1),
                   eg_e_b1 + p1 * EHID_D, nullptr, (float*)A16b, nullptr, nullptr, nullptr, nullptr, nullptr};
        js.j[3] = {f2, nullptr, nullptr, nullptr, WH(13 + 2 * p1), WL(13 + 2 * p1),
                   nullptr, nullptr, (float*)B16b, nullptr, nullptr, nullptr, nullptr, nullptr};
        k_mm<0, false, true, false, false, 1, 0, false><<<dim3(MB, 9, 4), 256, 0, stream>>>(
            js, N, EHID_D, H, H, APAD, 0);
        const float* ew1a = eg_e_w1 + (size_t)p0 * EIN_D * EHID_D;
        const float* ew1b = eg_e_w1 + (size_t)p1 * EIN_D * EHID_D;
        k_edge_mfma<<<(EIA_D + 63) / 64, 256, 0, stream>>>(
            dstI1, cjI1, EIA_D, A16a, B16a, c1, ew1a + (size_t)256 * EHID_D,
            Wf + (size_t)p0 * 8704, Wf + 4 * 8704 + (size_t)p0 * 8704,
            eg_e_b2 + p0 * M_D, eg_c_w1 + p0 * M_D * 64, eg_c_b1 + p0 * 64,
            eg_c_w2 + p0 * 64, eg_c_b2 + p0, me16a, cveca);
        k_edge_mfma<<<(EIA_D + 63) / 64, 256, 0, stream>>>(
            dstI2, cjI2, EIA_D, A16b, B16b, c2, ew1b + (size_t)256 * EHID_D,
            Wf + (size_t)p1 * 8704, Wf + 4 * 8704 + (size_t)p1 * 8704,
            eg_e_b2 + p1 * M_D, eg_c_w1 + p1 * M_D * 64, eg_c_b1 + p1 * 64,
            eg_c_w2 + p1 * 64, eg_c_b2 + p1, me16b, cvecb);
        k_egnn_seg<<<gNW, 256, 0, stream>>>(rpI1, me16a, cveca, c1, co1, macc1, N);
        k_egnn_seg<<<gNW, 256, 0, stream>>>(rpI2, me16b, cvecb, c2, co2, macc2, N);
        // nh z=2 (gather-concat [feats|macc])
        js.j[0] = {f1, macc1, iota, iota, WH(20 + p0), WL(20 + p0),
                   eg_n_b1 + p0 * NHID_D, nullptr, nh1, nullptr, nullptr, nullptr, nullptr, nullptr};
        js.j[1] = {f2, macc2, iota, iota, WH(20 + p1), WL(20 + p1),
                   eg_n_b1 + p1 * NHID_D, nullptr, nh2, nullptr, nullptr, nullptr, nullptr, nullptr};
        k_mm<2, false, false, true, false, 2, 0, false><<<dim3(MB, 4, 2), 256, 0, stream>>>(
            js, N, NHID_D, NIN_D, 160, NHID_D, M_D);
        // n_w2 z=2 (+residual)
        js.j[0] = {nh1, nullptr, nullptr, nullptr, WH(24 + p0), WL(24 + p0),
                   eg_n_b2 + p0 * H, f1, fo1, nullptr, nullptr, nullptr, nullptr, nullptr};
        js.j[1] = {nh2, nullptr, nullptr, nullptr, WH(24 + p1), WL(24 + p1),
                   eg_n_b2 + p1 * H, f2, fo2, nullptr, nullptr, nullptr, nullptr, nullptr};
        k_mm<0, true, false, false, false, 2, 0, false><<<dim3(MB, 2, 2), 256, 0, stream>>>(
            js, N, H, NHID_D, NHID_D, H, 0);
    };
    egnn_pair(cx1, cx2, pos1, pos2, 0, x1a, x2a, co1a, co2a);
    cx1 = x1a; cx2 = x2a;
    egnn_pair(cx1, cx2, co1a, co2a, 1, x1b, x2b, co1b, co2b);
    cx1 = x1b; cx2 = x2b;

    // ---- heads ----
    k_nodescore<<<gNW, 256, 0, stream>>>(cx1, lin_w, lin_b, dout, N);
    k_nodescore<<<gNW, 256, 0, stream>>>(cx2, lin_w, lin_b, dout + N, N);
    js.j[0] = {cx1, cx2, ei_int, ei_int + EIT_D, WH(28), WL(28),
               aux_b1, nullptr, Hb, nullptr, nullptr, nullptr, nullptr, nullptr};
    k_mm<1, false, false, true, false, 2, 0, false><<<dim3((EIT_D + 127) / 128, 2, 1), 256, 0, stream>>>(
        js, EIT_D, H, 2 * H, 2 * H, H, H_D);
    k_dist<<<(EIT_D + 3) / 4, 256, 0, stream>>>(Hb, aux_w2, aux_b2, dout + 2 * N, EIT_D);
}

// Round 11
// 1498.951 us; speedup vs baseline: 3.9021x; 1.0684x over previous
//
#include <hip/hip_runtime.h>
#include <hip/hip_bf16.h>
#include <cstdint>
#include <cstddef>

// ---- problem constants ----
#define NN     20000
#define FIN_D  64
#define H_D    128
#define M_D    16
#define EIA_D  256000
#define EIR_D  256000
#define EIT_D  100000
#define EIN_D  257
#define EHID_D 514
#define NIN_D  144
#define NHID_D 256
#define APAD   544          // padded EHID; 17 k-tiles of 32
#define BUPAD  272          // APAD/2 uints per bf16 row (A and B tables)

typedef short bfrag __attribute__((ext_vector_type(8)));   // 8 bf16 (4 VGPRs)
typedef float ffrag __attribute__((ext_vector_type(4)));   // 4 fp32 acc

__device__ __forceinline__ float siluf(float x) {
    return x * __builtin_amdgcn_rcpf(1.f + __expf(-x));
}
__device__ __forceinline__ float reluf(float x) { return x > 0.f ? x : 0.f; }
__device__ __forceinline__ unsigned short f2bf(float f) {  // RNE fp32->bf16
    unsigned u = __float_as_uint(f);
    return (unsigned short)((u + 0x7FFFu + ((u >> 16) & 1u)) >> 16);
}
__device__ __forceinline__ float bf2f(unsigned short h) { return __uint_as_float(((unsigned)h) << 16); }
__device__ __forceinline__ float bf_lo(unsigned u) { return __uint_as_float(u << 16); }
__device__ __forceinline__ float bf_hi(unsigned u) { return __uint_as_float(u & 0xFFFF0000u); }
__device__ __forceinline__ unsigned pkbf(float f0, float f1) {
    __hip_bfloat162 h = __float22bfloat162_rn(make_float2(f0, f1));
    return *(unsigned*)&h;
}

// ---------------- CSR build ----------------
__global__ void k_filli(int* p, int v, int n) {
    int i = blockIdx.x * 256 + threadIdx.x; if (i < n) p[i] = v;
}
__global__ void k_iota(int* p, int n) {
    int i = blockIdx.x * 256 + threadIdx.x; if (i < n) p[i] = i;
}
__global__ void k_hist(const int* __restrict__ si, int nE, int* __restrict__ cnt) {
    int e = blockIdx.x * 256 + threadIdx.x; if (e < nE) atomicAdd(&cnt[si[e]], 1);
}
__global__ void k_scan4(const int* __restrict__ cnt4, int n, int* __restrict__ rp4) {
    const int* cnt = cnt4 + (size_t)blockIdx.x * n;
    int* rp = rp4 + (size_t)blockIdx.x * (n + 1);
    __shared__ int tmp[256];
    __shared__ int carry;
    if (threadIdx.x == 0) { carry = 0; rp[0] = 0; }
    __syncthreads();
    for (int base = 0; base < n; base += 256) {
        int i = base + threadIdx.x;
        int v = (i < n) ? cnt[i] : 0;
        tmp[threadIdx.x] = v;
        __syncthreads();
        for (int off = 1; off < 256; off <<= 1) {
            int t = (threadIdx.x >= off) ? tmp[threadIdx.x - off] : 0;
            __syncthreads();
            tmp[threadIdx.x] += t;
            __syncthreads();
        }
        if (i < n) rp[i + 1] = carry + tmp[threadIdx.x];
        __syncthreads();
        if (threadIdx.x == 0) carry += tmp[255];
        __syncthreads();
    }
}
__global__ void k_scatter(const int* __restrict__ sj, const int* __restrict__ si, int nE,
                          const int* __restrict__ rp, int* __restrict__ cursor,
                          int* __restrict__ colj, int* __restrict__ dsti) {
    int e = blockIdx.x * 256 + threadIdx.x;
    if (e >= nE) return;
    int i = si[e];
    int p = rp[i] + atomicAdd(&cursor[i], 1);
    colj[p] = sj[e];
    if (dsti) dsti[p] = i;
}

// ---------------- weight prep: transpose + hi/lo bf16 split ----------------
struct PrepDesc { const float* src; unsigned dstOff; int K, N, Kpad, Npad; };
struct PrepArgs { PrepDesc d[29]; };
__global__ void k_prep(PrepArgs pa, unsigned short* __restrict__ Wt) {
    PrepDesc de = pa.d[blockIdx.x];
    int tot = de.Npad * de.Kpad;
    unsigned short* hi = Wt + de.dstOff;
    unsigned short* lo = hi + tot;
    for (int i = blockIdx.y * 256 + threadIdx.x; i < tot; i += gridDim.y * 256) {
        int n = i / de.Kpad, k = i - n * de.Kpad;
        float v = (n < de.N && k < de.K) ? de.src[(size_t)k * de.N + n] : 0.f;
        unsigned short h = f2bf(v);
        hi[i] = h;
        lo[i] = f2bf(v - bf2f(h));
    }
}

__global__ void k_prep_ew2(const float* __restrict__ eg_e_w2, unsigned short* __restrict__ Wf) {
    int pidx = blockIdx.x;
    const float* src = eg_e_w2 + (size_t)pidx * EHID_D * M_D;
    unsigned short* hi = Wf + (size_t)pidx * 8704;
    unsigned short* lo = Wf + 4 * 8704 + (size_t)pidx * 8704;
    for (int idx = threadIdx.x; idx < 8704; idx += 256) {
        int t = idx >> 9, rem = idx & 511;
        int lane = rem >> 3, j2 = rem & 7;
        int k = t * 32 + ((lane >> 4) << 3) + j2;
        int n = lane & 15;
        float v = (k < EHID_D) ? src[(size_t)k * 16 + n] : 0.f;
        unsigned short h = f2bf(v);
        hi[idx] = h;
        lo[idx] = f2bf(v - bf2f(h));
    }
}

struct MMJob {
    const float* A; const float* A2;
    const int* gi0; const int* gi1;
    const unsigned short* Wh; const unsigned short* Wl;
    const float* bias; const float* res;
    float* C; unsigned short* C2;
    const float* da; const float* db;
    float* dota; float* dotb;
};
struct MMJobs { MMJob j[4]; };

// ---------------- full-K resident MFMA GEMM (K = KT*32 <= 128, AMODE=1) ----------------
// A staged once in LDS (bf16), bn tiles looped internally (A fetched exactly once, 1 barrier).
// DOT>=1: per-row dot(acc,da[,db]) accumulated across bn -> DIRECT store (one block per row).
// Runtime DUAL via jb.C2. OBF pad columns Nc..ldc-1 zeroed (NaN-in-pad lesson, round 9).
template<int ACT, bool OBF, int DOT, bool NOC, int KT>
__global__ __launch_bounds__(256) void k_mmf(MMJobs js, int M, int Nc, int ldc, int nbn) {
    constexpr int K = KT * 32;
    __shared__ __align__(16) unsigned short sAh[128 * K];
    const MMJob jb = js.j[blockIdx.z];
    const int tid = threadIdx.x;
    const int bm = blockIdx.x * 128;
    const int wv = tid >> 6, lane = tid & 63;
    const int q = lane >> 4, mm = lane & 15;
    // ---- stage all K once ----
    const int sr = tid >> 1;
    const int sks = (tid & 1) * 16;
    const int gm_s = bm + sr;
    const int sgmt = sr >> 4, smm = sr & 15, qb = (tid & 1) * 2;
#pragma unroll
    for (int t = 0; t < KT; ++t) {
        float v[16];
        if (gm_s < M) {
            const float* src = jb.A + (size_t)gm_s * K + t * 32 + sks;
#pragma unroll
            for (int i = 0; i < 4; ++i) {
                float4 t4 = ((const float4*)src)[i];
                v[4 * i] = t4.x; v[4 * i + 1] = t4.y; v[4 * i + 2] = t4.z; v[4 * i + 3] = t4.w;
            }
        } else {
#pragma unroll
            for (int i = 0; i < 16; ++i) v[i] = 0.f;
        }
#pragma unroll
        for (int o = 0; o < 2; ++o) {
            unsigned hw[4];
#pragma unroll
            for (int p = 0; p < 4; ++p)
                hw[p] = pkbf(v[o * 8 + 2 * p], v[o * 8 + 2 * p + 1]);
            int off16 = ((sgmt * KT + t) * 4 + qb + o) * 16 + smm;
            ((uint4*)sAh)[off16] = make_uint4(hw[0], hw[1], hw[2], hw[3]);
        }
    }
    __syncthreads();
    float dra[2][4] = {}, drb[2][4] = {};
    for (int b = 0; b < nbn; ++b) {
        const int bn = b * 64;
        ffrag acc[2][4];
#pragma unroll
        for (int mt = 0; mt < 2; ++mt)
#pragma unroll
            for (int nt = 0; nt < 4; ++nt)
#pragma unroll
                for (int r = 0; r < 4; ++r) acc[mt][nt][r] = 0.f;
#pragma unroll
        for (int t = 0; t < KT; ++t) {
            bfrag bh[4], bl[4];
#pragma unroll
            for (int nt = 0; nt < 4; ++nt) {
                size_t woff = (size_t)(bn + nt * 16 + mm) * K + t * 32 + q * 8;
                bh[nt] = *(const bfrag*)(jb.Wh + woff);
                bl[nt] = *(const bfrag*)(jb.Wl + woff);
            }
#pragma unroll
            for (int mt = 0; mt < 2; ++mt) {
                int off16 = (((wv * 2 + mt) * KT + t) * 4 + q) * 16 + mm;
                bfrag ah = ((const bfrag*)sAh)[off16];
#pragma unroll
                for (int nt = 0; nt < 4; ++nt) {
                    acc[mt][nt] = __builtin_amdgcn_mfma_f32_16x16x32_bf16(ah, bh[nt], acc[mt][nt], 0, 0, 0);
                    acc[mt][nt] = __builtin_amdgcn_mfma_f32_16x16x32_bf16(ah, bl[nt], acc[mt][nt], 0, 0, 0);
                }
            }
        }
        if (DOT >= 1) {
            float dav[4], dbv[4];
#pragma unroll
            for (int nt = 0; nt < 4; ++nt) {
                int gn = bn + nt * 16 + mm;
                dav[nt] = (gn < Nc) ? jb.da[gn] : 0.f;
                if (DOT == 2) dbv[nt] = (gn < Nc) ? jb.db[gn] : 0.f;
            }
#pragma unroll
            for (int mt = 0; mt < 2; ++mt)
#pragma unroll
                for (int r = 0; r < 4; ++r)
#pragma unroll
                    for (int nt = 0; nt < 4; ++nt) {
                        dra[mt][r] += acc[mt][nt][r] * dav[nt];
                        if (DOT == 2) drb[mt][r] += acc[mt][nt][r] * dbv[nt];
                    }
        }
        const bool doC2 = jb.C2 != nullptr;
        if (!NOC || doC2) {
#pragma unroll
            for (int mt = 0; mt < 2; ++mt) {
#pragma unroll
                for (int nt = 0; nt < 4; ++nt) {
                    int gn = bn + nt * 16 + mm;
                    bool inb = gn < Nc;
                    bool padz = OBF && !NOC && !inb && gn < ldc;
                    if (!inb && !padz) continue;
#pragma unroll
                    for (int r = 0; r < 4; ++r) {
                        int gm = bm + wv * 32 + mt * 16 + q * 4 + r;
                        if (gm >= M) continue;
                        if (padz) {
                            ((unsigned short*)jb.C)[(size_t)gm * ldc + gn] = 0;
                            continue;
                        }
                        float vv = acc[mt][nt][r];
                        if (jb.bias) vv += jb.bias[gn];
                        if (ACT == 1) vv = reluf(vv);
                        if (ACT == 2) vv = siluf(vv);
                        if (!NOC) {
                            if (OBF) ((unsigned short*)jb.C)[(size_t)gm * ldc + gn] = f2bf(vv);
                            else jb.C[(size_t)gm * ldc + gn] = vv;
                        }
                        if (doC2) jb.C2[(size_t)gm * ldc + gn] = f2bf(vv);
                    }
                }
            }
        }
    }
    if (DOT >= 1) {
#pragma unroll
        for (int mt = 0; mt < 2; ++mt)
#pragma unroll
            for (int r = 0; r < 4; ++r) {
                float sa = dra[mt][r];
                sa += __shfl_xor(sa, 1); sa += __shfl_xor(sa, 2);
                sa += __shfl_xor(sa, 4); sa += __shfl_xor(sa, 8);
                float sb = 0.f;
                if (DOT == 2) {
                    sb = drb[mt][r];
                    sb += __shfl_xor(sb, 1); sb += __shfl_xor(sb, 2);
                    sb += __shfl_xor(sb, 4); sb += __shfl_xor(sb, 8);
                }
                int gm = bm + wv * 32 + mt * 16 + q * 4 + r;
                if (mm == 0 && gm < M) {
                    jb.dota[gm] = sa;
                    if (DOT == 2) jb.dotb[gm] = sb;
                }
            }
    }
}

// ---------------- general MFMA GEMM (AMODE=2 hi/lo, GATHER, RES) for K>128 paths ----------
template<int ACT, bool RES, bool GATHER>
__global__ __launch_bounds__(256) void k_mm(MMJobs js, int M, int Nc, int K, int Kpad, int ldc, int s2) {
    __shared__ __align__(16) unsigned short sAh[128 * 32];
    __shared__ __align__(16) unsigned short sAl[128 * 32];
    const MMJob jb = js.j[blockIdx.z];
    const int tid = threadIdx.x;
    const int bm = blockIdx.x * 128, bn = blockIdx.y * 64;
    const int wv = tid >> 6, lane = tid & 63;
    ffrag acc[2][4];
#pragma unroll
    for (int mt = 0; mt < 2; ++mt)
#pragma unroll
        for (int nt = 0; nt < 4; ++nt)
#pragma unroll
            for (int r = 0; r < 4; ++r) acc[mt][nt][r] = 0.f;
    const int sr = tid >> 1;
    const int sks = (tid & 1) * 16;
    const int gm_s = bm + sr;
    const int sgmt = sr >> 4, smm = sr & 15, qb = (tid & 1) * 2;
    int gidx0 = 0, gidx1 = 0;
    if (GATHER && gm_s < M) { gidx0 = jb.gi0[gm_s]; gidx1 = jb.gi1[gm_s]; }
    const int q = lane >> 4, mm = lane & 15;

    for (int k0 = 0; k0 < Kpad; k0 += 32) {
        float v[16];
        bool valid = (gm_s < M) && (k0 + sks < K);
        if (valid) {
            const float* src;
            int kk = k0 + sks;
            if (GATHER) src = (kk < 128) ? (jb.A + (size_t)gidx0 * 128 + kk)
                                         : (jb.A2 + (size_t)gidx1 * s2 + (kk - 128));
            else src = jb.A + (size_t)gm_s * K + kk;
#pragma unroll
            for (int i = 0; i < 4; ++i) {
                float4 t4 = ((const float4*)src)[i];
                v[4 * i] = t4.x; v[4 * i + 1] = t4.y; v[4 * i + 2] = t4.z; v[4 * i + 3] = t4.w;
            }
        } else {
#pragma unroll
            for (int i = 0; i < 16; ++i) v[i] = 0.f;
        }
#pragma unroll
        for (int o = 0; o < 2; ++o) {
            unsigned hw[4], lw[4];
#pragma unroll
            for (int p = 0; p < 4; ++p) {
                float f0 = v[o * 8 + 2 * p], f1 = v[o * 8 + 2 * p + 1];
                unsigned short h0 = f2bf(f0), h1 = f2bf(f1);
                unsigned short l0 = f2bf(f0 - bf2f(h0)), l1 = f2bf(f1 - bf2f(h1));
                hw[p] = (unsigned)h0 | ((unsigned)h1 << 16);
                lw[p] = (unsigned)l0 | ((unsigned)l1 << 16);
            }
            int off16 = (sgmt * 4 + qb + o) * 16 + smm;
            ((uint4*)sAh)[off16] = make_uint4(hw[0], hw[1], hw[2], hw[3]);
            ((uint4*)sAl)[off16] = make_uint4(lw[0], lw[1], lw[2], lw[3]);
        }
        __syncthreads();
        bfrag bh[4], bl[4];
#pragma unroll
        for (int nt = 0; nt < 4; ++nt) {
            size_t woff = (size_t)(bn + nt * 16 + mm) * Kpad + k0 + q * 8;
            bh[nt] = *(const bfrag*)(jb.Wh + woff);
            bl[nt] = *(const bfrag*)(jb.Wl + woff);
        }
#pragma unroll
        for (int mt = 0; mt < 2; ++mt) {
            int off16 = ((wv * 2 + mt) * 4 + q) * 16 + mm;
            bfrag ah = ((const bfrag*)sAh)[off16];
            bfrag al = ((const bfrag*)sAl)[off16];
#pragma unroll
            for (int nt = 0; nt < 4; ++nt) {
                acc[mt][nt] = __builtin_amdgcn_mfma_f32_16x16x32_bf16(ah, bh[nt], acc[mt][nt], 0, 0, 0);
                acc[mt][nt] = __builtin_amdgcn_mfma_f32_16x16x32_bf16(ah, bl[nt], acc[mt][nt], 0, 0, 0);
                acc[mt][nt] = __builtin_amdgcn_mfma_f32_16x16x32_bf16(al, bh[nt], acc[mt][nt], 0, 0, 0);
            }
        }
        __syncthreads();
    }
#pragma unroll
    for (int mt = 0; mt < 2; ++mt) {
#pragma unroll
        for (int nt = 0; nt < 4; ++nt) {
            int gn = bn + nt * 16 + mm;
            if (gn >= Nc) continue;
#pragma unroll
            for (int r = 0; r < 4; ++r) {
                int gm = bm + wv * 32 + mt * 16 + q * 4 + r;
                if (gm >= M) continue;
                float vv = acc[mt][nt][r];
                if (jb.bias) vv += jb.bias[gn];
                if (ACT == 1) vv = reluf(vv);
                if (ACT == 2) vv = siluf(vv);
                if (RES) vv += jb.res[(size_t)gm * Nc + gn];
                jb.C[(size_t)gm * ldc + gn] = vv;
            }
        }
    }
}

__global__ void k_nodescore(const float* __restrict__ x, const float* __restrict__ wv,
                            const float* __restrict__ b, float* __restrict__ o, int n) {
    int w = blockIdx.x * 4 + (threadIdx.x >> 6);
    int lane = threadIdx.x & 63;
    if (w >= n) return;
    const float* r = x + (size_t)w * H_D;
    float s = r[lane] * wv[lane] + r[lane + 64] * wv[lane + 64];
#pragma unroll
    for (int off = 32; off; off >>= 1) s += __shfl_xor(s, off);
    if (lane == 0) o[w] = s + b[0];
}

// ---------------- fused GAT softmax-aggregate: both graphs per launch, 4-edge unroll --------
struct GatJob {
    const int* rp; const int* cj; int hasSelf;
    const float* es; const float* ed;
    const unsigned* h16; const float* bias; float* out;
};
__global__ __launch_bounds__(256) void k_gat2(GatJob j0, GatJob j1, int N) {
    const GatJob jb = blockIdx.y ? j1 : j0;
    int node = blockIdx.x * 4 + (threadIdx.x >> 6);
    int lane = threadIdx.x & 63;
    if (node >= N) return;
    int start = jb.rp[node], end = jb.rp[node + 1];
    float edi = jb.ed[node];
    float den = 0.f, a0 = 0.f, a1 = 0.f;
    int p = start;
    for (; p + 4 <= end; p += 4) {
        int j[4]; float e[4]; unsigned u[4];
#pragma unroll
        for (int x = 0; x < 4; ++x) j[x] = jb.cj[p + x];
#pragma unroll
        for (int x = 0; x < 4; ++x) { e[x] = jb.es[j[x]]; u[x] = jb.h16[(size_t)j[x] * 64 + lane]; }
#pragma unroll
        for (int x = 0; x < 4; ++x) {
            float v = e[x] + edi;
            v = v < 0.f ? 0.2f * v : v;
            float ex = __expf(v);
            den += ex;
            a0 += ex * bf_lo(u[x]);
            a1 += ex * bf_hi(u[x]);
        }
    }
    for (; p < end; ++p) {
        int j = jb.cj[p];
        float v = jb.es[j] + edi;
        v = v < 0.f ? 0.2f * v : v;
        float ex = __expf(v);
        den += ex;
        unsigned u = jb.h16[(size_t)j * 64 + lane];
        a0 += ex * bf_lo(u);
        a1 += ex * bf_hi(u);
    }
    if (jb.hasSelf) {
        float v = jb.es[node] + edi;
        v = v < 0.f ? 0.2f * v : v;
        float ex = __expf(v);
        den += ex;
        unsigned u = jb.h16[(size_t)node * 64 + lane];
        a0 += ex * bf_lo(u);
        a1 += ex * bf_hi(u);
    }
    float inv = 1.f / (den + 1e-16f);
    float2 o;
    o.x = reluf(a0 * inv + jb.bias[2 * lane]);
    o.y = reluf(a1 * inv + jb.bias[2 * lane + 1]);
    ((float2*)(jb.out + (size_t)node * H_D))[lane] = o;
}

// ---------------- EGNN edge kernel: both graphs per launch ----------------
struct EJob {
    const int* dsti; const int* cj;
    const unsigned* A16; const unsigned* Bp; const float* coors;
    const float* w_rd;
    const unsigned short* Wfh; const unsigned short* Wfl;
    const float* eb2; const float* cw1; const float* cb1;
    const float* cw2; const float* cb2;
    unsigned short* me16; float* cvec;
};
__global__ __launch_bounds__(256) void k_edge2(EJob e0, EJob e1, int nE) {
    const EJob jb = blockIdx.y ? e1 : e0;
    __shared__ __align__(16) float s_w[APAD];
    __shared__ float s_cw1[1024];
    __shared__ float s_cb1[64], s_cw2[64], s_eb2[16];
    __shared__ float sM[4][16][17];
    for (int i = threadIdx.x; i < APAD; i += 256)
        s_w[i] = (i < EHID_D) ? jb.w_rd[i] : 0.f;
    for (int i = threadIdx.x; i < 1024; i += 256) s_cw1[i] = jb.cw1[i];
    if (threadIdx.x < 64) { s_cb1[threadIdx.x] = jb.cb1[threadIdx.x]; s_cw2[threadIdx.x] = jb.cw2[threadIdx.x]; }
    if (threadIdx.x < 16) s_eb2[threadIdx.x] = jb.eb2[threadIdx.x];
    __syncthreads();
    const float cb2v = jb.cb2[0];
    const int wv = threadIdx.x >> 6, lane = threadIdx.x & 63;
    const int q = lane >> 4, mm = lane & 15;
    const int ebase = blockIdx.x * 64 + wv * 16;
    const int e = ebase + mm;
    const bool ev = e < nE;
    int ii = ev ? jb.dsti[e] : 0;
    int jj = ev ? jb.cj[e] : 0;
    float dx = jb.coors[(size_t)jj * 3]     - jb.coors[(size_t)ii * 3];
    float dy = jb.coors[(size_t)jj * 3 + 1] - jb.coors[(size_t)ii * 3 + 1];
    float dz = jb.coors[(size_t)jj * 3 + 2] - jb.coors[(size_t)ii * 3 + 2];
    float rd = dx * dx + dy * dy + dz * dz;
    const unsigned* Ar = jb.A16 + (size_t)ii * BUPAD;
    const unsigned* Br = jb.Bp + (size_t)jj * BUPAD;
    ffrag acc = {0.f, 0.f, 0.f, 0.f};
#pragma unroll 4
    for (int t = 0; t < 17; ++t) {
        int ks = t * 32 + q * 8;
        int ku = ks >> 1;
        uint4 au = *(const uint4*)(Ar + ku);
        uint4 bu = *(const uint4*)(Br + ku);
        float4 w0 = *(const float4*)(s_w + ks);
        float4 w1 = *(const float4*)(s_w + ks + 4);
        float g[8];
        g[0] = siluf(bf_lo(au.x) + bf_lo(bu.x) + rd * w0.x);
        g[1] = siluf(bf_hi(au.x) + bf_hi(bu.x) + rd * w0.y);
        g[2] = siluf(bf_lo(au.y) + bf_lo(bu.y) + rd * w0.z);
        g[3] = siluf(bf_hi(au.y) + bf_hi(bu.y) + rd * w0.w);
        g[4] = siluf(bf_lo(au.z) + bf_lo(bu.z) + rd * w1.x);
        g[5] = siluf(bf_hi(au.z) + bf_hi(bu.z) + rd * w1.y);
        g[6] = siluf(bf_lo(au.w) + bf_lo(bu.w) + rd * w1.z);
        g[7] = siluf(bf_hi(au.w) + bf_hi(bu.w) + rd * w1.w);
        bfrag ah;
        unsigned* ahp = (unsigned*)&ah;
        ahp[0] = pkbf(g[0], g[1]);
        ahp[1] = pkbf(g[2], g[3]);
        ahp[2] = pkbf(g[4], g[5]);
        ahp[3] = pkbf(g[6], g[7]);
        bfrag bh = *(const bfrag*)(jb.Wfh + (size_t)(t * 64 + lane) * 8);
        bfrag bl = *(const bfrag*)(jb.Wfl + (size_t)(t * 64 + lane) * 8);
        acc = __builtin_amdgcn_mfma_f32_16x16x32_bf16(ah, bh, acc, 0, 0, 0);
        acc = __builtin_amdgcn_mfma_f32_16x16x32_bf16(ah, bl, acc, 0, 0, 0);
    }
#pragma unroll
    for (int r = 0; r < 4; ++r) {
        int erow = q * 4 + r;
        float me = siluf(acc[r] + s_eb2[mm]);
        sM[wv][erow][mm] = me;
        int e2 = ebase + erow;
        if (e2 < nE) jb.me16[(size_t)e2 * 16 + mm] = f2bf(me);
    }
    for (int el = 0; el < 16; ++el) {
        int e3 = ebase + el;
        if (e3 >= nE) break;
        float a = s_cb1[lane];
#pragma unroll
        for (int c = 0; c < 16; ++c) a += sM[wv][el][c] * s_cw1[c * 64 + lane];
        float p = siluf(a) * s_cw2[lane];
#pragma unroll
        for (int off = 32; off; off >>= 1) p += __shfl_xor(p, off);
        float cwv = p + cb2v;
        if (lane == el) {
            jb.cvec[(size_t)e3 * 3]     = cwv * dx;
            jb.cvec[(size_t)e3 * 3 + 1] = cwv * dy;
            jb.cvec[(size_t)e3 * 3 + 2] = cwv * dz;
        }
    }
}

// ---------------- EGNN CSR segment-sum: both graphs per launch ----------------
struct SJob {
    const int* rp; const unsigned short* me16; const float* cvec;
    const float* coors; float* coorsOut; float* macc;
};
__global__ __launch_bounds__(256) void k_seg2(SJob s0, SJob s1, int N) {
    const SJob jb = blockIdx.y ? s1 : s0;
    int node = blockIdx.x * 4 + (threadIdx.x >> 6);
    int lane = threadIdx.x & 63;
    if (node >= N) return;
    int s = jb.rp[node], en = jb.rp[node + 1];
    int x = lane >> 4, c = lane & 15;
    float msum = 0.f, csum = 0.f;
    for (int p = s + x; p < en; p += 4) {
        msum += bf2f(jb.me16[(size_t)p * 16 + c]);
        if (c < 3) csum += jb.cvec[(size_t)p * 3 + c];
    }
    msum += __shfl_xor(msum, 16); msum += __shfl_xor(msum, 32);
    csum += __shfl_xor(csum, 16); csum += __shfl_xor(csum, 32);
    if (lane < 16) jb.macc[(size_t)node * M_D + lane] = msum;
    if (lane < 3) jb.coorsOut[(size_t)node * 3 + lane] = jb.coors[(size_t)node * 3 + lane] + csum;
}

__global__ void k_dist(const float* __restrict__ Hb, const float* __restrict__ w2,
                       const float* __restrict__ b2, float* __restrict__ dist, int nE) {
    int e = blockIdx.x * 4 + (threadIdx.x >> 6);
    int lane = threadIdx.x & 63;
    if (e >= nE) return;
    const float* r = Hb + (size_t)e * H_D;
    float s = r[lane] * w2[lane] + r[lane + 64] * w2[lane + 64];
#pragma unroll
    for (int off = 32; off; off >>= 1) s += __shfl_xor(s, off);
    if (lane == 0) dist[e] = reluf(s + b2[0]);
}

// ---------------- host ----------------
extern "C" void kernel_launch(void* const* d_in, const int* in_sizes, int n_in,
                              void* d_out, int out_size, void* d_ws, size_t ws_size,
                              hipStream_t stream) {
    const float* x1_in = (const float*)d_in[0];
    const float* x2_in = (const float*)d_in[1];
    const float* pos1  = (const float*)d_in[2];
    const float* pos2  = (const float*)d_in[3];
    const int* ei_intra1 = (const int*)d_in[4];
    const int* ei_intra2 = (const int*)d_in[5];
    const int* ei_12 = (const int*)d_in[6];
    const int* ei_21 = (const int*)d_in[7];
    const int* ei_int = (const int*)d_in[8];
    const float* g0_w  = (const float*)d_in[9];
    const float* g0_as = (const float*)d_in[10];
    const float* g0_ad = (const float*)d_in[11];
    const float* g0_b  = (const float*)d_in[12];
    const float* g1_w  = (const float*)d_in[13];
    const float* g1_as = (const float*)d_in[14];
    const float* g1_ad = (const float*)d_in[15];
    const float* g1_b  = (const float*)d_in[16];
    const float* it_ws = (const float*)d_in[17];
    const float* it_wd = (const float*)d_in[18];
    const float* it_as = (const float*)d_in[19];
    const float* it_ad = (const float*)d_in[20];
    const float* it_b  = (const float*)d_in[21];
    const float* eg_e_w1 = (const float*)d_in[22];
    const float* eg_e_b1 = (const float*)d_in[23];
    const float* eg_e_w2 = (const float*)d_in[24];
    const float* eg_e_b2 = (const float*)d_in[25];
    const float* eg_c_w1 = (const float*)d_in[26];
    const float* eg_c_b1 = (const float*)d_in[27];
    const float* eg_c_w2 = (const float*)d_in[28];
    const float* eg_c_b2 = (const float*)d_in[29];
    const float* eg_n_w1 = (const float*)d_in[30];
    const float* eg_n_b1 = (const float*)d_in[31];
    const float* eg_n_w2 = (const float*)d_in[32];
    const float* eg_n_b2 = (const float*)d_in[33];
    const float* lin_w = (const float*)d_in[34];
    const float* lin_b = (const float*)d_in[35];
    const float* aux_w1 = (const float*)d_in[36];
    const float* aux_b1 = (const float*)d_in[37];
    const float* aux_w2 = (const float*)d_in[38];
    const float* aux_b2 = (const float*)d_in[39];
    float* dout = (float*)d_out;

    // ---- workspace layout ----
    float* wsf = (float*)d_ws;
    size_t off = 0;
    auto alloc = [&](size_t nfl) { float* p = wsf + off; off += (nfl + 255) & ~(size_t)255; return p; };
    float* x1a = alloc((size_t)NN * H_D);
    float* x2a = alloc((size_t)NN * H_D);
    float* x1b = alloc((size_t)NN * H_D);
    float* x2b = alloc((size_t)NN * H_D);
    float* esed = alloc(4 * NN);
    float* es1 = esed, *es2 = esed + NN, *ed1 = esed + 2 * NN, *ed2 = esed + 3 * NN;
    float* co1a = alloc(NN * 3);
    float* co1b = alloc(NN * 3);
    float* co2a = alloc(NN * 3);
    float* co2b = alloc(NN * 3);
    float* macc1 = alloc((size_t)NN * M_D);
    float* macc2 = alloc((size_t)NN * M_D);
    unsigned* A16a = (unsigned*)alloc((size_t)NN * BUPAD);
    unsigned* B16a = (unsigned*)alloc((size_t)NN * BUPAD);
    unsigned* A16b = (unsigned*)alloc((size_t)NN * BUPAD);
    unsigned* B16b = (unsigned*)alloc((size_t)NN * BUPAD);
    unsigned* h16a = (unsigned*)alloc((size_t)NN * 64);
    unsigned* h16b = (unsigned*)alloc((size_t)NN * 64);
    int* cnt4 = (int*)alloc(4 * NN);
    int* rp4 = (int*)alloc(4 * (NN + 1));
    int* cjI1 = (int*)alloc(EIA_D);
    int* cjI2 = (int*)alloc(EIA_D);
    int* cj12 = (int*)alloc(EIR_D);
    int* cj21 = (int*)alloc(EIR_D);
    int* dstI1 = (int*)alloc(EIA_D);
    int* dstI2 = (int*)alloc(EIA_D);
    int* iota = (int*)alloc(NN);
    unsigned short* Wt = (unsigned short*)alloc(1100000);
    unsigned short* Wf = (unsigned short*)alloc(35000);
    unsigned short* me16a = (unsigned short*)alloc((size_t)EIA_D * 8);
    unsigned short* me16b = (unsigned short*)alloc((size_t)EIA_D * 8);
    float* cveca = alloc((size_t)EIA_D * 3);
    float* cvecb = alloc((size_t)EIA_D * 3);
    float* nh1 = (float*)B16a;     // alias: B tables dead post-edge; pad cols re-zeroed each rebuild
    float* nh2 = (float*)B16b;
    float* Hb  = (float*)A16a;     // alias: table block dead at aux time

    const int N = NN, H = H_D;
    int gNW = (N + 3) / 4;
    int gEA = (EIA_D + 255) / 256;

    // ---- weight prep ----
    PrepArgs pa;
    unsigned woffs[29], wsz[29];
    unsigned wo = 0;
    int wi = 0;
    auto addw = [&](const float* src, int K, int Ncols) {
        int Kpad = (K + 31) & ~31;
        int Npad = (Ncols + 63) & ~63;
        pa.d[wi] = {src, wo, K, Ncols, Kpad, Npad};
        woffs[wi] = wo; wsz[wi] = (unsigned)(Npad * Kpad);
        wo += 2u * Npad * Kpad;
        ++wi;
    };
    addw(g0_w, FIN_D, H);                          // 0
    addw(g0_w + FIN_D * H, FIN_D, H);              // 1
    addw(g1_w, H, H);                              // 2
    addw(g1_w + H * H, H, H);                      // 3
    for (int p = 0; p < 4; ++p) addw(it_ws + (size_t)p * H * H, H, H);   // 4..7
    for (int p = 0; p < 4; ++p) addw(it_wd + (size_t)p * H * H, H, H);   // 8..11
    for (int p = 0; p < 4; ++p) {                  // 12..19
        const float* ew1 = eg_e_w1 + (size_t)p * EIN_D * EHID_D;
        addw(ew1, H, EHID_D);
        addw(ew1 + (size_t)H * EHID_D, H, EHID_D);
    }
    for (int p = 0; p < 4; ++p) addw(eg_n_w1 + (size_t)p * NIN_D * NHID_D, NIN_D, NHID_D);  // 20..23
    for (int p = 0; p < 4; ++p) addw(eg_n_w2 + (size_t)p * NHID_D * H, NHID_D, H);          // 24..27
    addw(aux_w1, 2 * H, H);                        // 28
    k_prep<<<dim3(29, 16), 256, 0, stream>>>(pa, Wt);
    k_prep_ew2<<<4, 256, 0, stream>>>(eg_e_w2, Wf);
    auto WH = [&](int i) { return (const unsigned short*)(Wt + woffs[i]); };
    auto WL = [&](int i) { return (const unsigned short*)(Wt + woffs[i] + wsz[i]); };

    // ---- CSRs + iota ----
    k_filli<<<(4 * N + 255) / 256, 256, 0, stream>>>(cnt4, 0, 4 * N);
    k_iota<<<(N + 255) / 256, 256, 0, stream>>>(iota, N);
    k_hist<<<gEA, 256, 0, stream>>>(ei_intra1 + EIA_D, EIA_D, cnt4);
    k_hist<<<gEA, 256, 0, stream>>>(ei_intra2 + EIA_D, EIA_D, cnt4 + N);
    k_hist<<<gEA, 256, 0, stream>>>(ei_12 + EIR_D, EIR_D, cnt4 + 2 * N);
    k_hist<<<gEA, 256, 0, stream>>>(ei_21 + EIR_D, EIR_D, cnt4 + 3 * N);
    k_scan4<<<4, 256, 0, stream>>>(cnt4, N, rp4);
    k_filli<<<(4 * N + 255) / 256, 256, 0, stream>>>(cnt4, 0, 4 * N);
    const int* rpI1 = rp4;
    const int* rpI2 = rp4 + (N + 1);
    const int* rp12 = rp4 + 2 * (N + 1);
    const int* rp21 = rp4 + 3 * (N + 1);
    k_scatter<<<gEA, 256, 0, stream>>>(ei_intra1, ei_intra1 + EIA_D, EIA_D, rpI1, cnt4, cjI1, dstI1);
    k_scatter<<<gEA, 256, 0, stream>>>(ei_intra2, ei_intra2 + EIA_D, EIA_D, rpI2, cnt4 + N, cjI2, dstI2);
    k_scatter<<<gEA, 256, 0, stream>>>(ei_12, ei_12 + EIR_D, EIR_D, rp12, cnt4 + 2 * N, cj12, nullptr);
    k_scatter<<<gEA, 256, 0, stream>>>(ei_21, ei_21 + EIR_D, EIR_D, rp21, cnt4 + 3 * N, cj21, nullptr);

    const int MB = (N + 127) / 128;   // 157
    MMJobs js{};

    // ---- GAT intra layers (k_mmf z=2, DOT=2 direct-store es/ed, DUAL h16) ----
    auto intraL = [&](auto kt_tag, const float* xa, const float* xb, int wa, int wb,
                      const float* as_a, const float* ad_a, const float* as_b, const float* ad_b,
                      const float* b_a, const float* b_b, float* oa, float* ob) {
        constexpr int KT = decltype(kt_tag)::value;
        js.j[0] = {xa, nullptr, nullptr, nullptr, WH(wa), WL(wa), nullptr, nullptr,
                   nullptr, (unsigned short*)h16a, as_a, ad_a, es1, ed1};
        js.j[1] = {xb, nullptr, nullptr, nullptr, WH(wb), WL(wb), nullptr, nullptr,
                   nullptr, (unsigned short*)h16b, as_b, ad_b, es2, ed2};
        k_mmf<0, false, 2, true, KT><<<dim3(MB, 1, 2), 256, 0, stream>>>(js, N, H, H, 2);
        GatJob g0{rpI1, cjI1, 1, es1, ed1, h16a, b_a, oa};
        GatJob g1{rpI2, cjI2, 1, es2, ed2, h16b, b_b, ob};
        k_gat2<<<dim3(gNW, 2), 256, 0, stream>>>(g0, g1, N);
    };

    intraL(std::integral_constant<int, 2>{}, x1_in, x2_in, 0, 1,
           g0_as, g0_ad, g0_as + H, g0_ad + H, g0_b, g0_b + H, x1a, x2a);
    const float* cx1 = x1a;
    const float* cx2 = x2a;
    intraL(std::integral_constant<int, 4>{}, cx1, cx2, 2, 3,
           g1_as, g1_ad, g1_as + H, g1_ad + H, g1_b, g1_b + H, x1b, x2b);
    cx1 = x1b; cx2 = x2b;

    // ---- GAT cross layers: hs+hd in ONE z=4 launch (runtime C2) ----
    {
        float* outs1[2] = {x1a, x1b};
        float* outs2[2] = {x2a, x2b};
        for (int l = 0; l < 2; ++l) {
            int p0 = l * 2 + 0, p1 = l * 2 + 1;
            float* o2 = outs2[l];
            float* o1 = outs1[l];
            js.j[0] = {cx1, nullptr, nullptr, nullptr, WH(4 + p0), WL(4 + p0), nullptr, nullptr,
                       nullptr, (unsigned short*)h16a, it_as + p0 * H, nullptr, es1, nullptr};
            js.j[1] = {cx2, nullptr, nullptr, nullptr, WH(4 + p1), WL(4 + p1), nullptr, nullptr,
                       nullptr, (unsigned short*)h16b, it_as + p1 * H, nullptr, es2, nullptr};
            js.j[2] = {cx2, nullptr, nullptr, nullptr, WH(8 + p0), WL(8 + p0), nullptr, nullptr,
                       nullptr, nullptr, it_ad + p0 * H, nullptr, ed1, nullptr};
            js.j[3] = {cx1, nullptr, nullptr, nullptr, WH(8 + p1), WL(8 + p1), nullptr, nullptr,
                       nullptr, nullptr, it_ad + p1 * H, nullptr, ed2, nullptr};
            k_mmf<0, false, 1, true, 4><<<dim3(MB, 1, 4), 256, 0, stream>>>(js, N, H, H, 2);
            GatJob g0{rp12, cj12, 0, es1, ed1, h16a, it_b + p0 * H, o2};
            GatJob g1{rp21, cj21, 0, es2, ed2, h16b, it_b + p1 * H, o1};
            k_gat2<<<dim3(gNW, 2), 256, 0, stream>>>(g0, g1, N);
            cx1 = o1; cx2 = o2;
        }
    }

    // ---- EGNN layers ----
    auto egnn_pair = [&](const float* f1, const float* f2, const float* c1, const float* c2,
                         int l, float* fo1, float* fo2, float* co1, float* co2) {
        int p0 = 2 * l, p1 = 2 * l + 1;
        // A/B tables z=4 via k_mmf (A fetched once; pad cols zeroed)
        js.j[0] = {f1, nullptr, nullptr, nullptr, WH(12 + 2 * p0), WL(12 + 2 * p0),
                   eg_e_b1 + p0 * EHID_D, nullptr, (float*)A16a, nullptr, nullptr, nullptr, nullptr, nullptr};
        js.j[1] = {f1, nullptr, nullptr, nullptr, WH(13 + 2 * p0), WL(13 + 2 * p0),
                   nullptr, nullptr, (float*)B16a, nullptr, nullptr, nullptr, nullptr, nullptr};
        js.j[2] = {f2, nullptr, nullptr, nullptr, WH(12 + 2 * p1), WL(12 + 2 * p1),
                   eg_e_b1 + p1 * EHID_D, nullptr, (float*)A16b, nullptr, nullptr, nullptr, nullptr, nullptr};
        js.j[3] = {f2, nullptr, nullptr, nullptr, WH(13 + 2 * p1), WL(13 + 2 * p1),
                   nullptr, nullptr, (float*)B16b, nullptr, nullptr, nullptr, nullptr, nullptr};
        k_mmf<0, true, 0, false, 4><<<dim3(MB, 1, 4), 256, 0, stream>>>(js, N, EHID_D, APAD, 9);
        const float* ew1a = eg_e_w1 + (size_t)p0 * EIN_D * EHID_D;
        const float* ew1b = eg_e_w1 + (size_t)p1 * EIN_D * EHID_D;
        EJob e0{dstI1, cjI1, A16a, B16a, c1, ew1a + (size_t)256 * EHID_D,
                Wf + (size_t)p0 * 8704, Wf + 4 * 8704 + (size_t)p0 * 8704,
                eg_e_b2 + p0 * M_D, eg_c_w1 + p0 * M_D * 64, eg_c_b1 + p0 * 64,
                eg_c_w2 + p0 * 64, eg_c_b2 + p0, me16a, cveca};
        EJob e1{dstI2, cjI2, A16b, B16b, c2, ew1b + (size_t)256 * EHID_D,
                Wf + (size_t)p1 * 8704, Wf + 4 * 8704 + (size_t)p1 * 8704,
                eg_e_b2 + p1 * M_D, eg_c_w1 + p1 * M_D * 64, eg_c_b1 + p1 * 64,
                eg_c_w2 + p1 * 64, eg_c_b2 + p1, me16b, cvecb};
        k_edge2<<<dim3((EIA_D + 63) / 64, 2), 256, 0, stream>>>(e0, e1, EIA_D);
        SJob s0{rpI1, me16a, cveca, c1, co1, macc1};
        SJob s1{rpI2, me16b, cvecb, c2, co2, macc2};
        k_seg2<<<dim3(gNW, 2), 256, 0, stream>>>(s0, s1, N);
        // nh z=2 (gather-concat, AMODE2 path)
        js.j[0] = {f1, macc1, iota, iota, WH(20 + p0), WL(20 + p0),
                   eg_n_b1 + p0 * NHID_D, nullptr, nh1, nullptr, nullptr, nullptr, nullptr, nullptr};
        js.j[1] = {f2, macc2, iota, iota, WH(20 + p1), WL(20 + p1),
                   eg_n_b1 + p1 * NHID_D, nullptr, nh2, nullptr, nullptr, nullptr, nullptr, nullptr};
        k_mm<2, false, true><<<dim3(MB, 4, 2), 256, 0, stream>>>(js, N, NHID_D, NIN_D, 160, NHID_D, M_D);
        // n_w2 z=2 (+residual)
        js.j[0] = {nh1, nullptr, nullptr, nullptr, WH(24 + p0), WL(24 + p0),
                   eg_n_b2 + p0 * H, f1, fo1, nullptr, nullptr, nullptr, nullptr, nullptr};
        js.j[1] = {nh2, nullptr, nullptr, nullptr, WH(24 + p1), WL(24 + p1),
                   eg_n_b2 + p1 * H, f2, fo2, nullptr, nullptr, nullptr, nullptr, nullptr};
        k_mm<0, true, false><<<dim3(MB, 2, 2), 256, 0, stream>>>(js, N, H, NHID_D, NHID_D, H, 0);
    };
    egnn_pair(cx1, cx2, pos1, pos2, 0, x1a, x2a, co1a, co2a);
    cx1 = x1a; cx2 = x2a;
    egnn_pair(cx1, cx2, co1a, co2a, 1, x1b, x2b, co1b, co2b);
    cx1 = x1b; cx2 = x2b;

    // ---- heads ----
    k_nodescore<<<gNW, 256, 0, stream>>>(cx1, lin_w, lin_b, dout, N);
    k_nodescore<<<gNW, 256, 0, stream>>>(cx2, lin_w, lin_b, dout + N, N);
    js.j[0] = {cx1, cx2, ei_int, ei_int + EIT_D, WH(28), WL(28),
               aux_b1, nullptr, Hb, nullptr, nullptr, nullptr, nullptr, nullptr};
    k_mm<1, false, true><<<dim3((EIT_D + 127) / 128, 2, 1), 256, 0, stream>>>(
        js, EIT_D, H, 2 * H, 2 * H, H, H_D);
    k_dist<<<(EIT_D + 3) / 4, 256, 0, stream>>>(Hb, aux_w2, aux_b2, dout + 2 * N, EIT_D);
}

// Round 12
// 1434.484 us; speedup vs baseline: 4.0774x; 1.0449x over previous
//
#include <hip/hip_runtime.h>
#include <hip/hip_bf16.h>
#include <cstdint>
#include <cstddef>

// ---- problem constants ----
#define NN     20000
#define FIN_D  64
#define H_D    128
#define M_D    16
#define EIA_D  256000
#define EIR_D  256000
#define EIT_D  100000
#define EIN_D  257
#define EHID_D 514
#define NIN_D  144
#define NHID_D 256
#define APAD   544          // padded EHID; 17 k-tiles of 32
#define BUPAD  272          // APAD/2 uints per bf16 row (A and B tables)

typedef short bfrag __attribute__((ext_vector_type(8)));   // 8 bf16 (4 VGPRs)
typedef float ffrag __attribute__((ext_vector_type(4)));   // 4 fp32 acc

__device__ __forceinline__ float siluf(float x) {
    return x * __builtin_amdgcn_rcpf(1.f + __expf(-x));
}
__device__ __forceinline__ float reluf(float x) { return x > 0.f ? x : 0.f; }
__device__ __forceinline__ unsigned short f2bf(float f) {  // RNE fp32->bf16
    unsigned u = __float_as_uint(f);
    return (unsigned short)((u + 0x7FFFu + ((u >> 16) & 1u)) >> 16);
}
__device__ __forceinline__ float bf2f(unsigned short h) { return __uint_as_float(((unsigned)h) << 16); }
__device__ __forceinline__ float bf_lo(unsigned u) { return __uint_as_float(u << 16); }
__device__ __forceinline__ float bf_hi(unsigned u) { return __uint_as_float(u & 0xFFFF0000u); }
__device__ __forceinline__ unsigned pkbf(float f0, float f1) {
    __hip_bfloat162 h = __float22bfloat162_rn(make_float2(f0, f1));
    return *(unsigned*)&h;
}

// ---------------- CSR build ----------------
__global__ void k_filli(int* p, int v, int n) {
    int i = blockIdx.x * 256 + threadIdx.x; if (i < n) p[i] = v;
}
__global__ void k_iota(int* p, int n) {
    int i = blockIdx.x * 256 + threadIdx.x; if (i < n) p[i] = i;
}
__global__ void k_hist(const int* __restrict__ si, int nE, int* __restrict__ cnt) {
    int e = blockIdx.x * 256 + threadIdx.x; if (e < nE) atomicAdd(&cnt[si[e]], 1);
}
__global__ void k_scan4(const int* __restrict__ cnt4, int n, int* __restrict__ rp4) {
    const int* cnt = cnt4 + (size_t)blockIdx.x * n;
    int* rp = rp4 + (size_t)blockIdx.x * (n + 1);
    __shared__ int tmp[256];
    __shared__ int carry;
    if (threadIdx.x == 0) { carry = 0; rp[0] = 0; }
    __syncthreads();
    for (int base = 0; base < n; base += 256) {
        int i = base + threadIdx.x;
        int v = (i < n) ? cnt[i] : 0;
        tmp[threadIdx.x] = v;
        __syncthreads();
        for (int off = 1; off < 256; off <<= 1) {
            int t = (threadIdx.x >= off) ? tmp[threadIdx.x - off] : 0;
            __syncthreads();
            tmp[threadIdx.x] += t;
            __syncthreads();
        }
        if (i < n) rp[i + 1] = carry + tmp[threadIdx.x];
        __syncthreads();
        if (threadIdx.x == 0) carry += tmp[255];
        __syncthreads();
    }
}
__global__ void k_scatter(const int* __restrict__ sj, const int* __restrict__ si, int nE,
                          const int* __restrict__ rp, int* __restrict__ cursor,
                          int* __restrict__ colj, int* __restrict__ dsti) {
    int e = blockIdx.x * 256 + threadIdx.x;
    if (e >= nE) return;
    int i = si[e];
    int p = rp[i] + atomicAdd(&cursor[i], 1);
    colj[p] = sj[e];
    if (dsti) dsti[p] = i;
}

// ---------------- weight prep: transpose + hi/lo bf16 split ----------------
struct PrepDesc { const float* src; unsigned dstOff; int K, N, Kpad, Npad; };
struct PrepArgs { PrepDesc d[29]; };
__global__ void k_prep(PrepArgs pa, unsigned short* __restrict__ Wt) {
    PrepDesc de = pa.d[blockIdx.x];
    int tot = de.Npad * de.Kpad;
    unsigned short* hi = Wt + de.dstOff;
    unsigned short* lo = hi + tot;
    for (int i = blockIdx.y * 256 + threadIdx.x; i < tot; i += gridDim.y * 256) {
        int n = i / de.Kpad, k = i - n * de.Kpad;
        float v = (n < de.N && k < de.K) ? de.src[(size_t)k * de.N + n] : 0.f;
        unsigned short h = f2bf(v);
        hi[i] = h;
        lo[i] = f2bf(v - bf2f(h));
    }
}

// ew2 [514][16] -> MFMA B-frag order (zero beyond k>=514); cw1 [16][64] -> gate B-frags
// (k=channel padded 16->32 with zeros).
__global__ void k_prep_ew2(const float* __restrict__ eg_e_w2, const float* __restrict__ eg_c_w1,
                           unsigned short* __restrict__ Wf) {
    int pidx = blockIdx.x;
    const float* src = eg_e_w2 + (size_t)pidx * EHID_D * M_D;
    unsigned short* hi = Wf + (size_t)pidx * 8704;
    unsigned short* lo = Wf + 4 * 8704 + (size_t)pidx * 8704;
    for (int idx = threadIdx.x; idx < 8704; idx += 256) {
        int t = idx >> 9, rem = idx & 511;
        int lane = rem >> 3, j2 = rem & 7;
        int k = t * 32 + ((lane >> 4) << 3) + j2;
        int n = lane & 15;
        float v = (k < EHID_D) ? src[(size_t)k * 16 + n] : 0.f;
        unsigned short h = f2bf(v);
        hi[idx] = h;
        lo[idx] = f2bf(v - bf2f(h));
    }
    // gate frags: Wf[69632 + pidx*4096 + (0 hi | 2048 lo)], idx = nt*512+lane*8+j
    const float* cw1 = eg_c_w1 + (size_t)pidx * 16 * 64;
    unsigned short* ghi = Wf + 69632 + (size_t)pidx * 4096;
    unsigned short* glo = ghi + 2048;
    for (int idx = threadIdx.x; idx < 2048; idx += 256) {
        int nt = idx >> 9, rem = idx & 511;
        int lane = rem >> 3, j = rem & 7;
        int q = lane >> 4, mm = lane & 15;
        int k = q * 8 + j;
        float v = (k < 16) ? cw1[(size_t)k * 64 + nt * 16 + mm] : 0.f;
        unsigned short h = f2bf(v);
        ghi[idx] = h;
        glo[idx] = f2bf(v - bf2f(h));
    }
}

struct MMJob {
    const float* A; const float* A2;
    const int* gi0; const int* gi1;
    const unsigned short* Wh; const unsigned short* Wl;
    const float* bias; const float* res;
    float* C; unsigned short* C2;
    const float* da; const float* db;
    float* dota; float* dotb;
};
struct MMJobs { MMJob j[4]; };

// ---------------- full-K resident MFMA GEMM (K = KT*32 <= 128, AMODE=1) ----------------
template<int ACT, bool OBF, int DOT, bool NOC, int KT>
__global__ __launch_bounds__(256) void k_mmf(MMJobs js, int M, int Nc, int ldc, int nbn) {
    constexpr int K = KT * 32;
    __shared__ __align__(16) unsigned short sAh[128 * K];
    const MMJob jb = js.j[blockIdx.z];
    const int tid = threadIdx.x;
    const int bm = blockIdx.x * 128;
    const int wv = tid >> 6, lane = tid & 63;
    const int q = lane >> 4, mm = lane & 15;
    const int sr = tid >> 1;
    const int sks = (tid & 1) * 16;
    const int gm_s = bm + sr;
    const int sgmt = sr >> 4, smm = sr & 15, qb = (tid & 1) * 2;
#pragma unroll
    for (int t = 0; t < KT; ++t) {
        float v[16];
        if (gm_s < M) {
            const float* src = jb.A + (size_t)gm_s * K + t * 32 + sks;
#pragma unroll
            for (int i = 0; i < 4; ++i) {
                float4 t4 = ((const float4*)src)[i];
                v[4 * i] = t4.x; v[4 * i + 1] = t4.y; v[4 * i + 2] = t4.z; v[4 * i + 3] = t4.w;
            }
        } else {
#pragma unroll
            for (int i = 0; i < 16; ++i) v[i] = 0.f;
        }
#pragma unroll
        for (int o = 0; o < 2; ++o) {
            unsigned hw[4];
#pragma unroll
            for (int p = 0; p < 4; ++p)
                hw[p] = pkbf(v[o * 8 + 2 * p], v[o * 8 + 2 * p + 1]);
            int off16 = ((sgmt * KT + t) * 4 + qb + o) * 16 + smm;
            ((uint4*)sAh)[off16] = make_uint4(hw[0], hw[1], hw[2], hw[3]);
        }
    }
    __syncthreads();
    float dra[2][4] = {}, drb[2][4] = {};
    for (int b = 0; b < nbn; ++b) {
        const int bn = b * 64;
        ffrag acc[2][4];
#pragma unroll
        for (int mt = 0; mt < 2; ++mt)
#pragma unroll
            for (int nt = 0; nt < 4; ++nt)
#pragma unroll
                for (int r = 0; r < 4; ++r) acc[mt][nt][r] = 0.f;
#pragma unroll
        for (int t = 0; t < KT; ++t) {
            bfrag bh[4], bl[4];
#pragma unroll
            for (int nt = 0; nt < 4; ++nt) {
                size_t woff = (size_t)(bn + nt * 16 + mm) * K + t * 32 + q * 8;
                bh[nt] = *(const bfrag*)(jb.Wh + woff);
                bl[nt] = *(const bfrag*)(jb.Wl + woff);
            }
#pragma unroll
            for (int mt = 0; mt < 2; ++mt) {
                int off16 = (((wv * 2 + mt) * KT + t) * 4 + q) * 16 + mm;
                bfrag ah = ((const bfrag*)sAh)[off16];
#pragma unroll
                for (int nt = 0; nt < 4; ++nt) {
                    acc[mt][nt] = __builtin_amdgcn_mfma_f32_16x16x32_bf16(ah, bh[nt], acc[mt][nt], 0, 0, 0);
                    acc[mt][nt] = __builtin_amdgcn_mfma_f32_16x16x32_bf16(ah, bl[nt], acc[mt][nt], 0, 0, 0);
                }
            }
        }
        if (DOT >= 1) {
            float dav[4], dbv[4];
#pragma unroll
            for (int nt = 0; nt < 4; ++nt) {
                int gn = bn + nt * 16 + mm;
                dav[nt] = (gn < Nc) ? jb.da[gn] : 0.f;
                if (DOT == 2) dbv[nt] = (gn < Nc) ? jb.db[gn] : 0.f;
            }
#pragma unroll
            for (int mt = 0; mt < 2; ++mt)
#pragma unroll
                for (int r = 0; r < 4; ++r)
#pragma unroll
                    for (int nt = 0; nt < 4; ++nt) {
                        dra[mt][r] += acc[mt][nt][r] * dav[nt];
                        if (DOT == 2) drb[mt][r] += acc[mt][nt][r] * dbv[nt];
                    }
        }
        const bool doC2 = jb.C2 != nullptr;
        if (!NOC || doC2) {
#pragma unroll
            for (int mt = 0; mt < 2; ++mt) {
#pragma unroll
                for (int nt = 0; nt < 4; ++nt) {
                    int gn = bn + nt * 16 + mm;
                    bool inb = gn < Nc;
                    bool padz = OBF && !NOC && !inb && gn < ldc;
                    if (!inb && !padz) continue;
#pragma unroll
                    for (int r = 0; r < 4; ++r) {
                        int gm = bm + wv * 32 + mt * 16 + q * 4 + r;
                        if (gm >= M) continue;
                        if (padz) {
                            ((unsigned short*)jb.C)[(size_t)gm * ldc + gn] = 0;
                            continue;
                        }
                        float vv = acc[mt][nt][r];
                        if (jb.bias) vv += jb.bias[gn];
                        if (ACT == 1) vv = reluf(vv);
                        if (ACT == 2) vv = siluf(vv);
                        if (!NOC) {
                            if (OBF) ((unsigned short*)jb.C)[(size_t)gm * ldc + gn] = f2bf(vv);
                            else jb.C[(size_t)gm * ldc + gn] = vv;
                        }
                        if (doC2) jb.C2[(size_t)gm * ldc + gn] = f2bf(vv);
                    }
                }
            }
        }
    }
    if (DOT >= 1) {
#pragma unroll
        for (int mt = 0; mt < 2; ++mt)
#pragma unroll
            for (int r = 0; r < 4; ++r) {
                float sa = dra[mt][r];
                sa += __shfl_xor(sa, 1); sa += __shfl_xor(sa, 2);
                sa += __shfl_xor(sa, 4); sa += __shfl_xor(sa, 8);
                float sb = 0.f;
                if (DOT == 2) {
                    sb = drb[mt][r];
                    sb += __shfl_xor(sb, 1); sb += __shfl_xor(sb, 2);
                    sb += __shfl_xor(sb, 4); sb += __shfl_xor(sb, 8);
                }
                int gm = bm + wv * 32 + mt * 16 + q * 4 + r;
                if (mm == 0 && gm < M) {
                    jb.dota[gm] = sa;
                    if (DOT == 2) jb.dotb[gm] = sb;
                }
            }
    }
}

// ---------------- general MFMA GEMM (AMODE=2 hi/lo, GATHER, RES) for K>128 paths ----------
template<int ACT, bool RES, bool GATHER>
__global__ __launch_bounds__(256) void k_mm(MMJobs js, int M, int Nc, int K, int Kpad, int ldc, int s2) {
    __shared__ __align__(16) unsigned short sAh[128 * 32];
    __shared__ __align__(16) unsigned short sAl[128 * 32];
    const MMJob jb = js.j[blockIdx.z];
    const int tid = threadIdx.x;
    const int bm = blockIdx.x * 128, bn = blockIdx.y * 64;
    const int wv = tid >> 6, lane = tid & 63;
    ffrag acc[2][4];
#pragma unroll
    for (int mt = 0; mt < 2; ++mt)
#pragma unroll
        for (int nt = 0; nt < 4; ++nt)
#pragma unroll
            for (int r = 0; r < 4; ++r) acc[mt][nt][r] = 0.f;
    const int sr = tid >> 1;
    const int sks = (tid & 1) * 16;
    const int gm_s = bm + sr;
    const int sgmt = sr >> 4, smm = sr & 15, qb = (tid & 1) * 2;
    int gidx0 = 0, gidx1 = 0;
    if (GATHER && gm_s < M) { gidx0 = jb.gi0[gm_s]; gidx1 = jb.gi1[gm_s]; }
    const int q = lane >> 4, mm = lane & 15;

    for (int k0 = 0; k0 < Kpad; k0 += 32) {
        float v[16];
        bool valid = (gm_s < M) && (k0 + sks < K);
        if (valid) {
            const float* src;
            int kk = k0 + sks;
            if (GATHER) src = (kk < 128) ? (jb.A + (size_t)gidx0 * 128 + kk)
                                         : (jb.A2 + (size_t)gidx1 * s2 + (kk - 128));
            else src = jb.A + (size_t)gm_s * K + kk;
#pragma unroll
            for (int i = 0; i < 4; ++i) {
                float4 t4 = ((const float4*)src)[i];
                v[4 * i] = t4.x; v[4 * i + 1] = t4.y; v[4 * i + 2] = t4.z; v[4 * i + 3] = t4.w;
            }
        } else {
#pragma unroll
            for (int i = 0; i < 16; ++i) v[i] = 0.f;
        }
#pragma unroll
        for (int o = 0; o < 2; ++o) {
            unsigned hw[4], lw[4];
#pragma unroll
            for (int p = 0; p < 4; ++p) {
                float f0 = v[o * 8 + 2 * p], f1 = v[o * 8 + 2 * p + 1];
                unsigned short h0 = f2bf(f0), h1 = f2bf(f1);
                unsigned short l0 = f2bf(f0 - bf2f(h0)), l1 = f2bf(f1 - bf2f(h1));
                hw[p] = (unsigned)h0 | ((unsigned)h1 << 16);
                lw[p] = (unsigned)l0 | ((unsigned)l1 << 16);
            }
            int off16 = (sgmt * 4 + qb + o) * 16 + smm;
            ((uint4*)sAh)[off16] = make_uint4(hw[0], hw[1], hw[2], hw[3]);
            ((uint4*)sAl)[off16] = make_uint4(lw[0], lw[1], lw[2], lw[3]);
        }
        __syncthreads();
        bfrag bh[4], bl[4];
#pragma unroll
        for (int nt = 0; nt < 4; ++nt) {
            size_t woff = (size_t)(bn + nt * 16 + mm) * Kpad + k0 + q * 8;
            bh[nt] = *(const bfrag*)(jb.Wh + woff);
            bl[nt] = *(const bfrag*)(jb.Wl + woff);
        }
#pragma unroll
        for (int mt = 0; mt < 2; ++mt) {
            int off16 = ((wv * 2 + mt) * 4 + q) * 16 + mm;
            bfrag ah = ((const bfrag*)sAh)[off16];
            bfrag al = ((const bfrag*)sAl)[off16];
#pragma unroll
            for (int nt = 0; nt < 4; ++nt) {
                acc[mt][nt] = __builtin_amdgcn_mfma_f32_16x16x32_bf16(ah, bh[nt], acc[mt][nt], 0, 0, 0);
                acc[mt][nt] = __builtin_amdgcn_mfma_f32_16x16x32_bf16(ah, bl[nt], acc[mt][nt], 0, 0, 0);
                acc[mt][nt] = __builtin_amdgcn_mfma_f32_16x16x32_bf16(al, bh[nt], acc[mt][nt], 0, 0, 0);
            }
        }
        __syncthreads();
    }
#pragma unroll
    for (int mt = 0; mt < 2; ++mt) {
#pragma unroll
        for (int nt = 0; nt < 4; ++nt) {
            int gn = bn + nt * 16 + mm;
            if (gn >= Nc) continue;
#pragma unroll
            for (int r = 0; r < 4; ++r) {
                int gm = bm + wv * 32 + mt * 16 + q * 4 + r;
                if (gm >= M) continue;
                float vv = acc[mt][nt][r];
                if (jb.bias) vv += jb.bias[gn];
                if (ACT == 1) vv = reluf(vv);
                if (ACT == 2) vv = siluf(vv);
                if (RES) vv += jb.res[(size_t)gm * Nc + gn];
                jb.C[(size_t)gm * ldc + gn] = vv;
            }
        }
    }
}

__global__ void k_nodescore(const float* __restrict__ x, const float* __restrict__ wv,
                            const float* __restrict__ b, float* __restrict__ o, int n) {
    int w = blockIdx.x * 4 + (threadIdx.x >> 6);
    int lane = threadIdx.x & 63;
    if (w >= n) return;
    const float* r = x + (size_t)w * H_D;
    float s = r[lane] * wv[lane] + r[lane + 64] * wv[lane + 64];
#pragma unroll
    for (int off = 32; off; off >>= 1) s += __shfl_xor(s, off);
    if (lane == 0) o[w] = s + b[0];
}

// ---------------- fused GAT softmax-aggregate: both graphs per launch, 4-edge unroll --------
struct GatJob {
    const int* rp; const int* cj; int hasSelf;
    const float* es; const float* ed;
    const unsigned* h16; const float* bias; float* out;
};
__global__ __launch_bounds__(256) void k_gat2(GatJob j0, GatJob j1, int N) {
    const GatJob jb = blockIdx.y ? j1 : j0;
    int node = blockIdx.x * 4 + (threadIdx.x >> 6);
    int lane = threadIdx.x & 63;
    if (node >= N) return;
    int start = jb.rp[node], end = jb.rp[node + 1];
    float edi = jb.ed[node];
    float den = 0.f, a0 = 0.f, a1 = 0.f;
    int p = start;
    for (; p + 4 <= end; p += 4) {
        int j[4]; float e[4]; unsigned u[4];
#pragma unroll
        for (int x = 0; x < 4; ++x) j[x] = jb.cj[p + x];
#pragma unroll
        for (int x = 0; x < 4; ++x) { e[x] = jb.es[j[x]]; u[x] = jb.h16[(size_t)j[x] * 64 + lane]; }
#pragma unroll
        for (int x = 0; x < 4; ++x) {
            float v = e[x] + edi;
            v = v < 0.f ? 0.2f * v : v;
            float ex = __expf(v);
            den += ex;
            a0 += ex * bf_lo(u[x]);
            a1 += ex * bf_hi(u[x]);
        }
    }
    for (; p < end; ++p) {
        int j = jb.cj[p];
        float v = jb.es[j] + edi;
        v = v < 0.f ? 0.2f * v : v;
        float ex = __expf(v);
        den += ex;
        unsigned u = jb.h16[(size_t)j * 64 + lane];
        a0 += ex * bf_lo(u);
        a1 += ex * bf_hi(u);
    }
    if (jb.hasSelf) {
        float v = jb.es[node] + edi;
        v = v < 0.f ? 0.2f * v : v;
        float ex = __expf(v);
        den += ex;
        unsigned u = jb.h16[(size_t)node * 64 + lane];
        a0 += ex * bf_lo(u);
        a1 += ex * bf_hi(u);
    }
    float inv = 1.f / (den + 1e-16f);
    float2 o;
    o.x = reluf(a0 * inv + jb.bias[2 * lane]);
    o.y = reluf(a1 * inv + jb.bias[2 * lane + 1]);
    ((float2*)(jb.out + (size_t)node * H_D))[lane] = o;
}

// ---------------- EGNN edge kernel: both graphs per launch; MFMA gate ----------------
struct EJob {
    const int* dsti; const int* cj;
    const unsigned* A16; const unsigned* Bp; const float* coors;
    const float* w_rd;
    const unsigned short* Wfh; const unsigned short* Wfl;
    const unsigned short* Wgh; const unsigned short* Wgl;   // gate cw1 frags
    const float* eb2; const float* cb1;
    const float* cw2; const float* cb2;
    unsigned short* me16; float* cvec;
};
__global__ __launch_bounds__(256) void k_edge2(EJob e0, EJob e1, int nE) {
    const EJob jb = blockIdx.y ? e1 : e0;
    __shared__ __align__(16) float s_w[APAD];
    __shared__ float s_cb1[64], s_cw2[64], s_eb2[16];
    __shared__ __align__(16) float sM[4][16][20];   // stride 20: rows 80B (16B-aligned)
    for (int i = threadIdx.x; i < APAD; i += 256)
        s_w[i] = (i < EHID_D) ? jb.w_rd[i] : 0.f;
    if (threadIdx.x < 64) { s_cb1[threadIdx.x] = jb.cb1[threadIdx.x]; s_cw2[threadIdx.x] = jb.cw2[threadIdx.x]; }
    if (threadIdx.x < 16) s_eb2[threadIdx.x] = jb.eb2[threadIdx.x];
    __syncthreads();
    const float cb2v = jb.cb2[0];
    const int wv = threadIdx.x >> 6, lane = threadIdx.x & 63;
    const int q = lane >> 4, mm = lane & 15;
    const int ebase = blockIdx.x * 64 + wv * 16;
    const int e = ebase + mm;
    const bool ev = e < nE;
    int ii = ev ? jb.dsti[e] : 0;
    int jj = ev ? jb.cj[e] : 0;
    float dx = jb.coors[(size_t)jj * 3]     - jb.coors[(size_t)ii * 3];
    float dy = jb.coors[(size_t)jj * 3 + 1] - jb.coors[(size_t)ii * 3 + 1];
    float dz = jb.coors[(size_t)jj * 3 + 2] - jb.coors[(size_t)ii * 3 + 2];
    float rd = dx * dx + dy * dy + dz * dz;
    const unsigned* Ar = jb.A16 + (size_t)ii * BUPAD;
    const unsigned* Br = jb.Bp + (size_t)jj * BUPAD;
    ffrag acc = {0.f, 0.f, 0.f, 0.f};
#pragma unroll 4
    for (int t = 0; t < 17; ++t) {
        int ks = t * 32 + q * 8;
        int ku = ks >> 1;
        uint4 au = *(const uint4*)(Ar + ku);
        uint4 bu = *(const uint4*)(Br + ku);
        float4 w0 = *(const float4*)(s_w + ks);
        float4 w1 = *(const float4*)(s_w + ks + 4);
        float g[8];
        g[0] = siluf(bf_lo(au.x) + bf_lo(bu.x) + rd * w0.x);
        g[1] = siluf(bf_hi(au.x) + bf_hi(bu.x) + rd * w0.y);
        g[2] = siluf(bf_lo(au.y) + bf_lo(bu.y) + rd * w0.z);
        g[3] = siluf(bf_hi(au.y) + bf_hi(bu.y) + rd * w0.w);
        g[4] = siluf(bf_lo(au.z) + bf_lo(bu.z) + rd * w1.x);
        g[5] = siluf(bf_hi(au.z) + bf_hi(bu.z) + rd * w1.y);
        g[6] = siluf(bf_lo(au.w) + bf_lo(bu.w) + rd * w1.z);
        g[7] = siluf(bf_hi(au.w) + bf_hi(bu.w) + rd * w1.w);
        bfrag ah;
        unsigned* ahp = (unsigned*)&ah;
        ahp[0] = pkbf(g[0], g[1]);
        ahp[1] = pkbf(g[2], g[3]);
        ahp[2] = pkbf(g[4], g[5]);
        ahp[3] = pkbf(g[6], g[7]);
        bfrag bh = *(const bfrag*)(jb.Wfh + (size_t)(t * 64 + lane) * 8);
        bfrag bl = *(const bfrag*)(jb.Wfl + (size_t)(t * 64 + lane) * 8);
        acc = __builtin_amdgcn_mfma_f32_16x16x32_bf16(ah, bh, acc, 0, 0, 0);
        acc = __builtin_amdgcn_mfma_f32_16x16x32_bf16(ah, bl, acc, 0, 0, 0);
    }
    // me = silu(D + eb2); D row=q*4+r (edge), col=mm (channel)
#pragma unroll
    for (int r = 0; r < 4; ++r) {
        int erow = q * 4 + r;
        float me = siluf(acc[r] + s_eb2[mm]);
        sM[wv][erow][mm] = me;
        int e2 = ebase + erow;
        if (e2 < nE) jb.me16[(size_t)e2 * 16 + mm] = f2bf(me);
    }
    // ---- coordinate gate via MFMA: [16 edges] x [64 hid], k=16 channels (padded 32) ----
    // A-frag: lane (q,mm) holds me[edge mm][ch q*8+j]; q>=2 -> zeros (sM transposed read).
    bfrag ag;
    unsigned* agp = (unsigned*)&ag;
    if (q < 2) {
        float4 m0 = *(const float4*)&sM[wv][mm][q * 8];
        float4 m1 = *(const float4*)&sM[wv][mm][q * 8 + 4];
        agp[0] = pkbf(m0.x, m0.y);
        agp[1] = pkbf(m0.z, m0.w);
        agp[2] = pkbf(m1.x, m1.y);
        agp[3] = pkbf(m1.z, m1.w);
    } else {
        agp[0] = agp[1] = agp[2] = agp[3] = 0u;
    }
    float part[4] = {0.f, 0.f, 0.f, 0.f};
#pragma unroll
    for (int nt = 0; nt < 4; ++nt) {
        bfrag gh = *(const bfrag*)(jb.Wgh + (size_t)(nt * 64 + lane) * 8);
        bfrag gl = *(const bfrag*)(jb.Wgl + (size_t)(nt * 64 + lane) * 8);
        ffrag a2 = {0.f, 0.f, 0.f, 0.f};
        a2 = __builtin_amdgcn_mfma_f32_16x16x32_bf16(ag, gh, a2, 0, 0, 0);
        a2 = __builtin_amdgcn_mfma_f32_16x16x32_bf16(ag, gl, a2, 0, 0, 0);
        int n = nt * 16 + mm;
        float c1 = s_cb1[n], c2 = s_cw2[n];
#pragma unroll
        for (int r = 0; r < 4; ++r) part[r] += siluf(a2[r] + c1) * c2;
    }
#pragma unroll
    for (int r = 0; r < 4; ++r) {
        part[r] += __shfl_xor(part[r], 1);
        part[r] += __shfl_xor(part[r], 2);
        part[r] += __shfl_xor(part[r], 4);
        part[r] += __shfl_xor(part[r], 8);
    }
    // lane el (<16) needs edge el's total: r=el&3 from source lane (el>>2)*16
    int srcl = (lane >> 2) << 4;
    float cand0 = __shfl(part[0], srcl);
    float cand1 = __shfl(part[1], srcl);
    float cand2 = __shfl(part[2], srcl);
    float cand3 = __shfl(part[3], srcl);
    if (lane < 16) {
        int rr = lane & 3;
        float cwv = (rr == 0 ? cand0 : rr == 1 ? cand1 : rr == 2 ? cand2 : cand3) + cb2v;
        int e3 = ebase + lane;
        if (e3 < nE) {
            jb.cvec[(size_t)e3 * 3]     = cwv * dx;
            jb.cvec[(size_t)e3 * 3 + 1] = cwv * dy;
            jb.cvec[(size_t)e3 * 3 + 2] = cwv * dz;
        }
    }
}

// ---------------- EGNN CSR segment-sum: both graphs per launch ----------------
struct SJob {
    const int* rp; const unsigned short* me16; const float* cvec;
    const float* coors; float* coorsOut; float* macc;
};
__global__ __launch_bounds__(256) void k_seg2(SJob s0, SJob s1, int N) {
    const SJob jb = blockIdx.y ? s1 : s0;
    int node = blockIdx.x * 4 + (threadIdx.x >> 6);
    int lane = threadIdx.x & 63;
    if (node >= N) return;
    int s = jb.rp[node], en = jb.rp[node + 1];
    int x = lane >> 4, c = lane & 15;
    float msum = 0.f, csum = 0.f;
    for (int p = s + x; p < en; p += 4) {
        msum += bf2f(jb.me16[(size_t)p * 16 + c]);
        if (c < 3) csum += jb.cvec[(size_t)p * 3 + c];
    }
    msum += __shfl_xor(msum, 16); msum += __shfl_xor(msum, 32);
    csum += __shfl_xor(csum, 16); csum += __shfl_xor(csum, 32);
    if (lane < 16) jb.macc[(size_t)node * M_D + lane] = msum;
    if (lane < 3) jb.coorsOut[(size_t)node * 3 + lane] = jb.coors[(size_t)node * 3 + lane] + csum;
}

__global__ void k_dist(const float* __restrict__ Hb, const float* __restrict__ w2,
                       const float* __restrict__ b2, float* __restrict__ dist, int nE) {
    int e = blockIdx.x * 4 + (threadIdx.x >> 6);
    int lane = threadIdx.x & 63;
    if (e >= nE) return;
    const float* r = Hb + (size_t)e * H_D;
    float s = r[lane] * w2[lane] + r[lane + 64] * w2[lane + 64];
#pragma unroll
    for (int off = 32; off; off >>= 1) s += __shfl_xor(s, off);
    if (lane == 0) dist[e] = reluf(s + b2[0]);
}

// ---------------- host ----------------
extern "C" void kernel_launch(void* const* d_in, const int* in_sizes, int n_in,
                              void* d_out, int out_size, void* d_ws, size_t ws_size,
                              hipStream_t stream) {
    const float* x1_in = (const float*)d_in[0];
    const float* x2_in = (const float*)d_in[1];
    const float* pos1  = (const float*)d_in[2];
    const float* pos2  = (const float*)d_in[3];
    const int* ei_intra1 = (const int*)d_in[4];
    const int* ei_intra2 = (const int*)d_in[5];
    const int* ei_12 = (const int*)d_in[6];
    const int* ei_21 = (const int*)d_in[7];
    const int* ei_int = (const int*)d_in[8];
    const float* g0_w  = (const float*)d_in[9];
    const float* g0_as = (const float*)d_in[10];
    const float* g0_ad = (const float*)d_in[11];
    const float* g0_b  = (const float*)d_in[12];
    const float* g1_w  = (const float*)d_in[13];
    const float* g1_as = (const float*)d_in[14];
    const float* g1_ad = (const float*)d_in[15];
    const float* g1_b  = (const float*)d_in[16];
    const float* it_ws = (const float*)d_in[17];
    const float* it_wd = (const float*)d_in[18];
    const float* it_as = (const float*)d_in[19];
    const float* it_ad = (const float*)d_in[20];
    const float* it_b  = (const float*)d_in[21];
    const float* eg_e_w1 = (const float*)d_in[22];
    const float* eg_e_b1 = (const float*)d_in[23];
    const float* eg_e_w2 = (const float*)d_in[24];
    const float* eg_e_b2 = (const float*)d_in[25];
    const float* eg_c_w1 = (const float*)d_in[26];
    const float* eg_c_b1 = (const float*)d_in[27];
    const float* eg_c_w2 = (const float*)d_in[28];
    const float* eg_c_b2 = (const float*)d_in[29];
    const float* eg_n_w1 = (const float*)d_in[30];
    const float* eg_n_b1 = (const float*)d_in[31];
    const float* eg_n_w2 = (const float*)d_in[32];
    const float* eg_n_b2 = (const float*)d_in[33];
    const float* lin_w = (const float*)d_in[34];
    const float* lin_b = (const float*)d_in[35];
    const float* aux_w1 = (const float*)d_in[36];
    const float* aux_b1 = (const float*)d_in[37];
    const float* aux_w2 = (const float*)d_in[38];
    const float* aux_b2 = (const float*)d_in[39];
    float* dout = (float*)d_out;

    // ---- workspace layout ----
    float* wsf = (float*)d_ws;
    size_t off = 0;
    auto alloc = [&](size_t nfl) { float* p = wsf + off; off += (nfl + 255) & ~(size_t)255; return p; };
    float* x1a = alloc((size_t)NN * H_D);
    float* x2a = alloc((size_t)NN * H_D);
    float* x1b = alloc((size_t)NN * H_D);
    float* x2b = alloc((size_t)NN * H_D);
    float* esed = alloc(4 * NN);
    float* es1 = esed, *es2 = esed + NN, *ed1 = esed + 2 * NN, *ed2 = esed + 3 * NN;
    float* co1a = alloc(NN * 3);
    float* co1b = alloc(NN * 3);
    float* co2a = alloc(NN * 3);
    float* co2b = alloc(NN * 3);
    float* macc1 = alloc((size_t)NN * M_D);
    float* macc2 = alloc((size_t)NN * M_D);
    unsigned* A16a = (unsigned*)alloc((size_t)NN * BUPAD);
    unsigned* B16a = (unsigned*)alloc((size_t)NN * BUPAD);
    unsigned* A16b = (unsigned*)alloc((size_t)NN * BUPAD);
    unsigned* B16b = (unsigned*)alloc((size_t)NN * BUPAD);
    unsigned* h16a = (unsigned*)alloc((size_t)NN * 64);
    unsigned* h16b = (unsigned*)alloc((size_t)NN * 64);
    int* cnt4 = (int*)alloc(4 * NN);
    int* rp4 = (int*)alloc(4 * (NN + 1));
    int* cjI1 = (int*)alloc(EIA_D);
    int* cjI2 = (int*)alloc(EIA_D);
    int* cj12 = (int*)alloc(EIR_D);
    int* cj21 = (int*)alloc(EIR_D);
    int* dstI1 = (int*)alloc(EIA_D);
    int* dstI2 = (int*)alloc(EIA_D);
    int* iota = (int*)alloc(NN);
    unsigned short* Wt = (unsigned short*)alloc(1100000);
    unsigned short* Wf = (unsigned short*)alloc(45000);       // ew2 frags + gate cw1 frags
    unsigned short* me16a = (unsigned short*)alloc((size_t)EIA_D * 8);
    unsigned short* me16b = (unsigned short*)alloc((size_t)EIA_D * 8);
    float* cveca = alloc((size_t)EIA_D * 3);
    float* cvecb = alloc((size_t)EIA_D * 3);
    float* nh1 = (float*)B16a;     // alias: B tables dead post-edge; pad cols re-zeroed each rebuild
    float* nh2 = (float*)B16b;
    float* Hb  = (float*)A16a;     // alias: table block dead at aux time

    const int N = NN, H = H_D;
    int gNW = (N + 3) / 4;
    int gEA = (EIA_D + 255) / 256;

    // ---- weight prep ----
    PrepArgs pa;
    unsigned woffs[29], wsz[29];
    unsigned wo = 0;
    int wi = 0;
    auto addw = [&](const float* src, int K, int Ncols) {
        int Kpad = (K + 31) & ~31;
        int Npad = (Ncols + 63) & ~63;
        pa.d[wi] = {src, wo, K, Ncols, Kpad, Npad};
        woffs[wi] = wo; wsz[wi] = (unsigned)(Npad * Kpad);
        wo += 2u * Npad * Kpad;
        ++wi;
    };
    addw(g0_w, FIN_D, H);                          // 0
    addw(g0_w + FIN_D * H, FIN_D, H);              // 1
    addw(g1_w, H, H);                              // 2
    addw(g1_w + H * H, H, H);                      // 3
    for (int p = 0; p < 4; ++p) addw(it_ws + (size_t)p * H * H, H, H);   // 4..7
    for (int p = 0; p < 4; ++p) addw(it_wd + (size_t)p * H * H, H, H);   // 8..11
    for (int p = 0; p < 4; ++p) {                  // 12..19
        const float* ew1 = eg_e_w1 + (size_t)p * EIN_D * EHID_D;
        addw(ew1, H, EHID_D);
        addw(ew1 + (size_t)H * EHID_D, H, EHID_D);
    }
    for (int p = 0; p < 4; ++p) addw(eg_n_w1 + (size_t)p * NIN_D * NHID_D, NIN_D, NHID_D);  // 20..23
    for (int p = 0; p < 4; ++p) addw(eg_n_w2 + (size_t)p * NHID_D * H, NHID_D, H);          // 24..27
    addw(aux_w1, 2 * H, H);                        // 28
    k_prep<<<dim3(29, 16), 256, 0, stream>>>(pa, Wt);
    k_prep_ew2<<<4, 256, 0, stream>>>(eg_e_w2, eg_c_w1, Wf);
    auto WH = [&](int i) { return (const unsigned short*)(Wt + woffs[i]); };
    auto WL = [&](int i) { return (const unsigned short*)(Wt + woffs[i] + wsz[i]); };

    // ---- CSRs + iota ----
    k_filli<<<(4 * N + 255) / 256, 256, 0, stream>>>(cnt4, 0, 4 * N);
    k_iota<<<(N + 255) / 256, 256, 0, stream>>>(iota, N);
    k_hist<<<gEA, 256, 0, stream>>>(ei_intra1 + EIA_D, EIA_D, cnt4);
    k_hist<<<gEA, 256, 0, stream>>>(ei_intra2 + EIA_D, EIA_D, cnt4 + N);
    k_hist<<<gEA, 256, 0, stream>>>(ei_12 + EIR_D, EIR_D, cnt4 + 2 * N);
    k_hist<<<gEA, 256, 0, stream>>>(ei_21 + EIR_D, EIR_D, cnt4 + 3 * N);
    k_scan4<<<4, 256, 0, stream>>>(cnt4, N, rp4);
    k_filli<<<(4 * N + 255) / 256, 256, 0, stream>>>(cnt4, 0, 4 * N);
    const int* rpI1 = rp4;
    const int* rpI2 = rp4 + (N + 1);
    const int* rp12 = rp4 + 2 * (N + 1);
    const int* rp21 = rp4 + 3 * (N + 1);
    k_scatter<<<gEA, 256, 0, stream>>>(ei_intra1, ei_intra1 + EIA_D, EIA_D, rpI1, cnt4, cjI1, dstI1);
    k_scatter<<<gEA, 256, 0, stream>>>(ei_intra2, ei_intra2 + EIA_D, EIA_D, rpI2, cnt4 + N, cjI2, dstI2);
    k_scatter<<<gEA, 256, 0, stream>>>(ei_12, ei_12 + EIR_D, EIR_D, rp12, cnt4 + 2 * N, cj12, nullptr);
    k_scatter<<<gEA, 256, 0, stream>>>(ei_21, ei_21 + EIR_D, EIR_D, rp21, cnt4 + 3 * N, cj21, nullptr);

    const int MB = (N + 127) / 128;   // 157
    MMJobs js{};

    // ---- GAT intra layers ----
    auto intraL = [&](auto kt_tag, const float* xa, const float* xb, int wa, int wb,
                      const float* as_a, const float* ad_a, const float* as_b, const float* ad_b,
                      const float* b_a, const float* b_b, float* oa, float* ob) {
        constexpr int KT = decltype(kt_tag)::value;
        js.j[0] = {xa, nullptr, nullptr, nullptr, WH(wa), WL(wa), nullptr, nullptr,
                   nullptr, (unsigned short*)h16a, as_a, ad_a, es1, ed1};
        js.j[1] = {xb, nullptr, nullptr, nullptr, WH(wb), WL(wb), nullptr, nullptr,
                   nullptr, (unsigned short*)h16b, as_b, ad_b, es2, ed2};
        k_mmf<0, false, 2, true, KT><<<dim3(MB, 1, 2), 256, 0, stream>>>(js, N, H, H, 2);
        GatJob g0{rpI1, cjI1, 1, es1, ed1, h16a, b_a, oa};
        GatJob g1{rpI2, cjI2, 1, es2, ed2, h16b, b_b, ob};
        k_gat2<<<dim3(gNW, 2), 256, 0, stream>>>(g0, g1, N);
    };

    intraL(std::integral_constant<int, 2>{}, x1_in, x2_in, 0, 1,
           g0_as, g0_ad, g0_as + H, g0_ad + H, g0_b, g0_b + H, x1a, x2a);
    const float* cx1 = x1a;
    const float* cx2 = x2a;
    intraL(std::integral_constant<int, 4>{}, cx1, cx2, 2, 3,
           g1_as, g1_ad, g1_as + H, g1_ad + H, g1_b, g1_b + H, x1b, x2b);
    cx1 = x1b; cx2 = x2b;

    // ---- GAT cross layers: hs+hd in ONE z=4 launch ----
    {
        float* outs1[2] = {x1a, x1b};
        float* outs2[2] = {x2a, x2b};
        for (int l = 0; l < 2; ++l) {
            int p0 = l * 2 + 0, p1 = l * 2 + 1;
            float* o2 = outs2[l];
            float* o1 = outs1[l];
            js.j[0] = {cx1, nullptr, nullptr, nullptr, WH(4 + p0), WL(4 + p0), nullptr, nullptr,
                       nullptr, (unsigned short*)h16a, it_as + p0 * H, nullptr, es1, nullptr};
            js.j[1] = {cx2, nullptr, nullptr, nullptr, WH(4 + p1), WL(4 + p1), nullptr, nullptr,
                       nullptr, (unsigned short*)h16b, it_as + p1 * H, nullptr, es2, nullptr};
            js.j[2] = {cx2, nullptr, nullptr, nullptr, WH(8 + p0), WL(8 + p0), nullptr, nullptr,
                       nullptr, nullptr, it_ad + p0 * H, nullptr, ed1, nullptr};
            js.j[3] = {cx1, nullptr, nullptr, nullptr, WH(8 + p1), WL(8 + p1), nullptr, nullptr,
                       nullptr, nullptr, it_ad + p1 * H, nullptr, ed2, nullptr};
            k_mmf<0, false, 1, true, 4><<<dim3(MB, 1, 4), 256, 0, stream>>>(js, N, H, H, 2);
            GatJob g0{rp12, cj12, 0, es1, ed1, h16a, it_b + p0 * H, o2};
            GatJob g1{rp21, cj21, 0, es2, ed2, h16b, it_b + p1 * H, o1};
            k_gat2<<<dim3(gNW, 2), 256, 0, stream>>>(g0, g1, N);
            cx1 = o1; cx2 = o2;
        }
    }

    // ---- EGNN layers ----
    auto egnn_pair = [&](const float* f1, const float* f2, const float* c1, const float* c2,
                         int l, float* fo1, float* fo2, float* co1, float* co2) {
        int p0 = 2 * l, p1 = 2 * l + 1;
        js.j[0] = {f1, nullptr, nullptr, nullptr, WH(12 + 2 * p0), WL(12 + 2 * p0),
                   eg_e_b1 + p0 * EHID_D, nullptr, (float*)A16a, nullptr, nullptr, nullptr, nullptr, nullptr};
        js.j[1] = {f1, nullptr, nullptr, nullptr, WH(13 + 2 * p0), WL(13 + 2 * p0),
                   nullptr, nullptr, (float*)B16a, nullptr, nullptr, nullptr, nullptr, nullptr};
        js.j[2] = {f2, nullptr, nullptr, nullptr, WH(12 + 2 * p1), WL(12 + 2 * p1),
                   eg_e_b1 + p1 * EHID_D, nullptr, (float*)A16b, nullptr, nullptr, nullptr, nullptr, nullptr};
        js.j[3] = {f2, nullptr, nullptr, nullptr, WH(13 + 2 * p1), WL(13 + 2 * p1),
                   nullptr, nullptr, (float*)B16b, nullptr, nullptr, nullptr, nullptr, nullptr};
        k_mmf<0, true, 0, false, 4><<<dim3(MB, 1, 4), 256, 0, stream>>>(js, N, EHID_D, APAD, 9);
        const float* ew1a = eg_e_w1 + (size_t)p0 * EIN_D * EHID_D;
        const float* ew1b = eg_e_w1 + (size_t)p1 * EIN_D * EHID_D;
        EJob e0{dstI1, cjI1, A16a, B16a, c1, ew1a + (size_t)256 * EHID_D,
                Wf + (size_t)p0 * 8704, Wf + 4 * 8704 + (size_t)p0 * 8704,
                Wf + 69632 + (size_t)p0 * 4096, Wf + 69632 + (size_t)p0 * 4096 + 2048,
                eg_e_b2 + p0 * M_D, eg_c_b1 + p0 * 64,
                eg_c_w2 + p0 * 64, eg_c_b2 + p0, me16a, cveca};
        EJob e1{dstI2, cjI2, A16b, B16b, c2, ew1b + (size_t)256 * EHID_D,
                Wf + (size_t)p1 * 8704, Wf + 4 * 8704 + (size_t)p1 * 8704,
                Wf + 69632 + (size_t)p1 * 4096, Wf + 69632 + (size_t)p1 * 4096 + 2048,
                eg_e_b2 + p1 * M_D, eg_c_b1 + p1 * 64,
                eg_c_w2 + p1 * 64, eg_c_b2 + p1, me16b, cvecb};
        k_edge2<<<dim3((EIA_D + 63) / 64, 2), 256, 0, stream>>>(e0, e1, EIA_D);
        SJob s0{rpI1, me16a, cveca, c1, co1, macc1};
        SJob s1{rpI2, me16b, cvecb, c2, co2, macc2};
        k_seg2<<<dim3(gNW, 2), 256, 0, stream>>>(s0, s1, N);
        js.j[0] = {f1, macc1, iota, iota, WH(20 + p0), WL(20 + p0),
                   eg_n_b1 + p0 * NHID_D, nullptr, nh1, nullptr, nullptr, nullptr, nullptr, nullptr};
        js.j[1] = {f2, macc2, iota, iota, WH(20 + p1), WL(20 + p1),
                   eg_n_b1 + p1 * NHID_D, nullptr, nh2, nullptr, nullptr, nullptr, nullptr, nullptr};
        k_mm<2, false, true><<<dim3(MB, 4, 2), 256, 0, stream>>>(js, N, NHID_D, NIN_D, 160, NHID_D, M_D);
        js.j[0] = {nh1, nullptr, nullptr, nullptr, WH(24 + p0), WL(24 + p0),
                   eg_n_b2 + p0 * H, f1, fo1, nullptr, nullptr, nullptr, nullptr, nullptr};
        js.j[1] = {nh2, nullptr, nullptr, nullptr, WH(24 + p1), WL(24 + p1),
                   eg_n_b2 + p1 * H, f2, fo2, nullptr, nullptr, nullptr, nullptr, nullptr};
        k_mm<0, true, false><<<dim3(MB, 2, 2), 256, 0, stream>>>(js, N, H, NHID_D, NHID_D, H, 0);
    };
    egnn_pair(cx1, cx2, pos1, pos2, 0, x1a, x2a, co1a, co2a);
    cx1 = x1a; cx2 = x2a;
    egnn_pair(cx1, cx2, co1a, co2a, 1, x1b, x2b, co1b, co2b);
    cx1 = x1b; cx2 = x2b;

    // ---- heads ----
    k_nodescore<<<gNW, 256, 0, stream>>>(cx1, lin_w, lin_b, dout, N);
    k_nodescore<<<gNW, 256, 0, stream>>>(cx2, lin_w, lin_b, dout + N, N);
    js.j[0] = {cx1, cx2, ei_int, ei_int + EIT_D, WH(28), WL(28),
               aux_b1, nullptr, Hb, nullptr, nullptr, nullptr, nullptr, nullptr};
    k_mm<1, false, true><<<dim3((EIT_D + 127) / 128, 2, 1), 256, 0, stream>>>(
        js, EIT_D, H, 2 * H, 2 * H, H, H_D);
    k_dist<<<(EIT_D + 3) / 4, 256, 0, stream>>>(Hb, aux_w2, aux_b2, dout + 2 * N, EIT_D);
}